// Round 9
// baseline (448.542 us; speedup 1.0000x reference)
//
#include <hip/hip_runtime.h>
#include <math.h>

typedef __attribute__((ext_vector_type(8))) short short8;
typedef __attribute__((ext_vector_type(4))) float f32x4;
typedef __attribute__((ext_vector_type(16))) float f32x16;
typedef unsigned short u16;
typedef unsigned int u32;
typedef __attribute__((ext_vector_type(2))) u32 u32x2;
typedef __attribute__((ext_vector_type(4))) u32 u32x4;
typedef unsigned long long u64;

static constexpr int E = 1024, H = 16, LQ = 1024, LC = 512, Bn = 4, FF = 4096;
static constexpr int NTOK = Bn * LQ;   // 4096
static constexpr int NCTX = Bn * LC;   // 2048

// Q pre-scale: 1/sqrt(64) * log2(e)  (softmax runs in exp2 domain)
#define QSCALE 0.1803368801111244f
#define DEFER_THR 11.5f

// ---------------- workspace layout (bytes) ----------------
static constexpr size_t OFF_TCOS   = 0;                                    // 1024*32 f32
static constexpr size_t OFF_TSIN   = OFF_TCOS + (size_t)LQ*32*4;
static constexpr size_t OFF_BSAQKV = OFF_TSIN + (size_t)LQ*32*4;           // 3072 f32 (+ca_k/v bias after)
static constexpr size_t OFF_BCAKV  = OFF_BSAQKV + 16384;                   // 2048 f32
// contiguous bf16 weight region (order matters for cvt_all):
static constexpr size_t OFF_WSAQKV = OFF_BCAKV + 16384;                    // [3072][1024] bf16
static constexpr size_t OFF_WSAP   = OFF_WSAQKV + (size_t)3072*1024*2;     // [1024][1024]
static constexpr size_t OFF_WCAQ   = OFF_WSAP   + (size_t)1024*1024*2;
static constexpr size_t OFF_WCAKV  = OFF_WCAQ   + (size_t)1024*1024*2;     // [2048][1024]
static constexpr size_t OFF_WCAP   = OFF_WCAKV  + (size_t)2048*1024*2;
static constexpr size_t OFF_WFC1   = OFF_WCAP   + (size_t)1024*1024*2;     // [4096][1024]
static constexpr size_t OFF_WFC2   = OFF_WFC1   + (size_t)4096*1024*2;     // [1024][4096]
static constexpr size_t OFF_CTXB   = OFF_WFC2   + (size_t)1024*4096*2;     // [2048][1024] bf16
static constexpr size_t OFF_H      = OFF_CTXB   + (size_t)2048*1024*2;     // [4096][1024] bf16 (LN out)
static constexpr size_t OFF_QKV    = OFF_H      + (size_t)4096*1024*2;     // [4096][3072] bf16
static constexpr size_t OFF_CAQ    = OFF_QKV;                              // [4096][1024]
static constexpr size_t OFF_CAKV   = OFF_QKV + (size_t)4096*1024*2;        // [2048][2048]
static constexpr size_t OFF_QR     = OFF_QKV + (size_t)4096*3072*2;        // [B,H,LQ,64]
static constexpr size_t OFF_KR     = OFF_QR  + (size_t)4096*1024*2;        // [B,H,Lk,64]
static constexpr size_t OFF_VT     = OFF_KR  + (size_t)4096*1024*2;        // [B,H,64,Lk]
static constexpr size_t OFF_AO     = OFF_VT  + (size_t)4096*1024*2;        // [4096][1024] bf16
static constexpr size_t OFF_U      = OFF_QKV;                              // fc1 out [4096][4096] bf16 reuses QKV+QR
static constexpr size_t WS_NEED    = OFF_AO + (size_t)4096*1024*2;         // ~105 MB

// ---------------- helpers ----------------
static __device__ __forceinline__ float bf2f(u16 u) {
  union { u32 i; float f; } un; un.i = ((u32)u) << 16; return un.f;
}
static __device__ __forceinline__ u16 f2bf(float f) {  // RNE
  union { float f; u32 u; } un; un.f = f;
  u32 u = un.u;
  return (u16)((u + 0x7FFFu + ((u >> 16) & 1u)) >> 16);
}
static __device__ __forceinline__ u64 pack4(u16 a, u16 b, u16 c, u16 d) {
  return (u64)a | ((u64)b << 16) | ((u64)c << 32) | ((u64)d << 48);
}
static __device__ __forceinline__ f32x4 mfma16(short8 a, short8 b, f32x4 c) {
  return __builtin_amdgcn_mfma_f32_16x16x32_bf16(a, b, c, 0, 0, 0);
}
static __device__ __forceinline__ f32x16 mfma32(short8 a, short8 b, f32x16 c) {
  return __builtin_amdgcn_mfma_f32_32x32x16_bf16(a, b, c, 0, 0, 0);
}
static __device__ __forceinline__ void gload_lds16(void* lds, const void* g) {
  __builtin_amdgcn_global_load_lds(
      (const __attribute__((address_space(1))) void*)g,
      (__attribute__((address_space(3))) void*)lds, 16, 0, 0);
}
// gelu(x) = 0.5x(1+tanh(z)) = x*e/(e+1), e=exp(2*0.79788456(x+0.044715x^3)).
static __device__ __forceinline__ float gelu_tanh(float x) {
  float z2 = 1.5957691216057308f * (x + 0.044715f * x * x * x);
  float e = __expf(z2);
  float r = __builtin_amdgcn_rcpf(e + 1.0f);
  return x - x * r;   // x*(1 - 1/(e+1)) = x*e/(e+1)
}
static __device__ __forceinline__ u32 cvtpk_bf16(float lo, float hi) {
  u32 r;
  asm("v_cvt_pk_bf16_f32 %0, %1, %2" : "=v"(r) : "v"(lo), "v"(hi));
  return r;
}

// ---------------- small kernels ----------------
__global__ __launch_bounds__(256) void build_tab(float* __restrict__ ct, float* __restrict__ st) {
  int idx = blockIdx.x * 256 + threadIdx.x;           // 1024*32 entries
  int pos = idx >> 5, i = idx & 31;
  float inv = powf(10000.f, -(float)i * (1.f / 32.f));
  float a = (float)pos * inv;
  ct[idx] = cosf(a);
  st[idx] = sinf(a);
}

// fused fp32->bf16 conversion of all weights + context into the contiguous
// bf16 ws region. 11 segments, sizes (in 4-elem units): 8 x 262144, 2 x 1048576, 524288.
struct Cvt11 { const float* s[11]; };
__global__ __launch_bounds__(256) void cvt_all(Cvt11 a, u16* __restrict__ dst) {
  u32 gid = blockIdx.x * 256 + threadIdx.x;   // 0 .. 4718591
  u32 s, off;
  if (gid < 2097152u)      { s = gid >> 18;                        off = gid & 262143u; }
  else if (gid < 4194304u) { u32 t = gid - 2097152u; s = 8 + (t >> 20); off = t & 1048575u; }
  else                     { s = 10;                               off = gid - 4194304u; }
  float4 v = *(const float4*)(a.s[s] + (size_t)off * 4);
  *(u64*)(dst + (size_t)gid * 4) = pack4(f2bf(v.x), f2bf(v.y), f2bf(v.z), f2bf(v.w));
}

// fused bias copies: sa_q,sa_k,sa_v -> BSAQKV(+0,+1024,+2048); ca_k,ca_v -> BCAKV(+0,+1024)
struct Cp5 { const float* s[5]; };
__global__ __launch_bounds__(256) void copy5(Cp5 a, float* __restrict__ dst) {
  int gid = blockIdx.x * 256 + threadIdx.x;   // 0..5119
  int s = gid >> 10, off = gid & 1023;
  int doff = (s < 3) ? s * 1024 : 4096 + (s - 3) * 1024;
  dst[doff + off] = a.s[s][off];
}

// out[row][c] += gate[c]*bias[c]  (init pass for split-K atomic GEMM)
__global__ __launch_bounds__(256) void init_bias_gate(float* __restrict__ out, const float* __restrict__ bias,
                                                      const float* __restrict__ gate) {
  int i = (blockIdx.x * 256 + threadIdx.x) * 4;
  int c = i & 1023;
  float4 o = *(float4*)(out + i);
  o.x += gate[c] * bias[c];
  o.y += gate[c + 1] * bias[c + 1];
  o.z += gate[c + 2] * bias[c + 2];
  o.w += gate[c + 3] * bias[c + 3];
  *(float4*)(out + i) = o;
}

// LN over last dim 1024, one row per block (256 threads, 4 f32 each), bf16 out.
__global__ __launch_bounds__(256) void ln_bf16(const float* __restrict__ x, const float* __restrict__ w,
                                               const float* __restrict__ b, u16* __restrict__ out) {
  __shared__ float red[4];
  int row = blockIdx.x, tid = threadIdx.x;
  const float* xr = x + (size_t)row * 1024;
  float4 v = ((const float4*)xr)[tid];
  float s = v.x + v.y + v.z + v.w;
#pragma unroll
  for (int off = 32; off; off >>= 1) s += __shfl_xor(s, off);
  if ((tid & 63) == 0) red[tid >> 6] = s;
  __syncthreads();
  float mean = (red[0] + red[1] + red[2] + red[3]) * (1.f / 1024.f);
  float dx = v.x - mean, dy = v.y - mean, dz = v.z - mean, dw = v.w - mean;
  float sq = dx * dx + dy * dy + dz * dz + dw * dw;
#pragma unroll
  for (int off = 32; off; off >>= 1) sq += __shfl_xor(sq, off);
  __syncthreads();
  if ((tid & 63) == 0) red[tid >> 6] = sq;
  __syncthreads();
  float var = (red[0] + red[1] + red[2] + red[3]) * (1.f / 1024.f);
  float rstd = rsqrtf(var + 1e-6f);
  float4 wv = ((const float4*)w)[tid];
  float4 bv = ((const float4*)b)[tid];
  u64 o = pack4(f2bf(dx * rstd * wv.x + bv.x), f2bf(dy * rstd * wv.y + bv.y),
                f2bf(dz * rstd * wv.z + bv.z), f2bf(dw * rstd * wv.w + bv.w));
  *(u64*)(out + (size_t)row * 1024 + tid * 4) = o;
}

// Fused RoPE/scatter: 3 jobs in one dispatch (blockIdx.y selects job).
// mode 0: rotate pairs (x scale), dst [B,H,Lper,64]. mode 1: transpose, dst [B,H,64,Lper].
struct RopeJob { const u16* src; u16* dst; int ld, col0, Lper, T, mode; float scale; };
struct Rope3 { RopeJob j[3]; };
__global__ __launch_bounds__(128) void rope3(Rope3 a, const float* __restrict__ cosT,
                                             const float* __restrict__ sinT) {
  RopeJob jb = a.j[blockIdx.y];
  int t = blockIdx.x;
  if (t >= jb.T) return;
  int b = t / jb.Lper, l = t - b * jb.Lper;
  int tid = threadIdx.x;
  int e0 = tid * 8;
  int h = e0 >> 6, d0 = e0 & 63;
  short8 vv = *(const short8*)(jb.src + (size_t)t * jb.ld + jb.col0 + e0);
  if (jb.mode == 0) {
    short8 ov;
#pragma unroll
    for (int j = 0; j < 4; ++j) {
      float x1 = bf2f((u16)vv[2 * j]);
      float x2 = bf2f((u16)vv[2 * j + 1]);
      int i = (d0 >> 1) + j;
      float c = cosT[l * 32 + i], s = sinT[l * 32 + i];
      ov[2 * j]     = (short)f2bf((x1 * c - x2 * s) * jb.scale);
      ov[2 * j + 1] = (short)f2bf((x1 * s + x2 * c) * jb.scale);
    }
    *(short8*)(jb.dst + (((size_t)b * H + h) * jb.Lper + l) * 64 + d0) = ov;
  } else {
#pragma unroll
    for (int m = 0; m < 8; ++m)
      jb.dst[(((size_t)b * H + h) * 64 + d0 + m) * jb.Lper + l] = (u16)vv[m];
  }
}

// ---------------- GEMM: C[M,N] = A[M,K] @ W[N,K]^T + bias ----------------
enum { EPI_BF16 = 0, EPI_GELU = 1, EPI_RESID = 2, EPI_ATOMIC = 3 };

// gemm6: 128x128 tile, 256 threads (2x2 waves of 64x64, acc 4x4 = 0.5
// fragment-reads/MFMA — HALF of gemm2's 64x32 wave tile), double-buffered
// 64 KiB LDS with gemm2's proven pipeline, 2 blocks/CU co-resident.
// LDS-BW arithmetic: 0.031 B/FLOP -> ~70% MfmaUtil ceiling (vs gemm2's 17.5%).
template <int EPI>
__global__ __launch_bounds__(256, 2) void gemm6(const u16* __restrict__ A, const u16* __restrict__ W,
                                                const float* __restrict__ bias, u16* outb, float* outf,
                                                const float* res, const float* __restrict__ gate,
                                                int M, int N, int K, int kchunks) {
  __shared__ u16 As[2][128 * 64];
  __shared__ u16 Bs[2][128 * 64];

  int nwg = gridDim.x * gridDim.y;
  int bid = blockIdx.y * gridDim.x + blockIdx.x;
  int cpx = nwg >> 3;
  int swz = (bid & 7) * cpx + (bid >> 3);
  int bx = swz % gridDim.x;
  int by = swz / gridDim.x;
  int row0 = by * 128, col0 = bx * 128;

  const int Kc = K / kchunks;
  const int kbase = blockIdx.z * Kc;

  int tid = threadIdx.x;
  int lane = tid & 63, wid = tid >> 6;
  int wr = wid >> 1, wc = wid & 1;      // 2x2 waves, each owns 64x64
  int lr = lane & 15, lg = lane >> 4;

  // staging: 1024 16B chunks per matrix per K-tile; 4 chunks/thread each.
  u32 aoff[4], boff[4];
  int ldso[4];
#pragma unroll
  for (int j = 0; j < 4; ++j) {
    int q = tid + j * 256;
    int r = q >> 3, p = q & 7, sp = p ^ (r & 7);
    aoff[j] = (u32)(row0 + r) * (u32)K + sp * 8;
    boff[j] = (u32)(col0 + r) * (u32)K + sp * 8;
    ldso[j] = q * 8;
  }

  f32x4 acc[4][4] = {};
  const int nkt = Kc >> 6;

  // prologue: stage tile 0 into buf 0
#pragma unroll
  for (int j = 0; j < 4; ++j) {
    gload_lds16(&As[0][ldso[j]], A + aoff[j] + kbase);
    gload_lds16(&Bs[0][ldso[j]], W + boff[j] + kbase);
  }
  __syncthreads();

  for (int kt = 0; kt < nkt; ++kt) {
    int cur = kt & 1;
    if (kt + 1 < nkt) {       // prefetch next tile into the other buffer
      int k0 = kbase + ((kt + 1) << 6);
#pragma unroll
      for (int j = 0; j < 4; ++j) {
        gload_lds16(&As[cur ^ 1][ldso[j]], A + aoff[j] + k0);
        gload_lds16(&Bs[cur ^ 1][ldso[j]], W + boff[j] + k0);
      }
    }
#pragma unroll
    for (int kk = 0; kk < 2; ++kk) {
      short8 af[4], bf[4];
#pragma unroll
      for (int m = 0; m < 4; ++m) {
        int r = wr * 64 + m * 16 + lr;
        int sc = (kk * 4 + lg) ^ (r & 7);
        af[m] = *(const short8*)(&As[cur][r * 64 + sc * 8]);
      }
#pragma unroll
      for (int n = 0; n < 4; ++n) {
        int r = wc * 64 + n * 16 + lr;
        int sc = (kk * 4 + lg) ^ (r & 7);
        bf[n] = *(const short8*)(&Bs[cur][r * 64 + sc * 8]);
      }
      __builtin_amdgcn_s_setprio(1);
#pragma unroll
      for (int m = 0; m < 4; ++m)
#pragma unroll
        for (int n = 0; n < 4; ++n)
          acc[m][n] = mfma16(af[m], bf[n], acc[m][n]);
      __builtin_amdgcn_s_setprio(0);
    }
    __syncthreads();   // drains vmcnt(0): prefetched tile landed; buffers swap
  }

  if (EPI == EPI_BF16 || EPI == EPI_GELU) {
    // LDS-staged coalesced stores; As (32 KiB) = [128][128] u16 C-tile.
    u16* Ct = &As[0][0];
#pragma unroll
    for (int n = 0; n < 4; ++n) {
      int c = wc * 64 + n * 16 + lr;
      float bv = bias[col0 + c];
#pragma unroll
      for (int m = 0; m < 4; ++m) {
#pragma unroll
        for (int i = 0; i < 4; ++i) {
          int r = wr * 64 + m * 16 + lg * 4 + i;
          float v = acc[m][n][i] + bv;
          Ct[r * 128 + c] = f2bf(EPI == EPI_GELU ? gelu_tanh(v) : v);
        }
      }
    }
    __syncthreads();
    // 2048 16-B chunks; consecutive lanes cover complete 256-B rows.
#pragma unroll
    for (int j = 0; j < 8; ++j) {
      u32 q = (u32)tid + j * 256;
      u32 r = q >> 4, ck = q & 15;
      short8 v = *(const short8*)(Ct + r * 128 + ck * 8);
      *(short8*)(outb + (size_t)(row0 + r) * N + col0 + ck * 8) = v;
    }
  } else {
#pragma unroll
    for (int n = 0; n < 4; ++n) {
      int cg = col0 + wc * 64 + n * 16 + lr;
      float bv = (EPI == EPI_ATOMIC) ? 0.f : bias[cg];
#pragma unroll
      for (int m = 0; m < 4; ++m) {
#pragma unroll
        for (int i = 0; i < 4; ++i) {
          int rg = row0 + wr * 64 + m * 16 + lg * 4 + i;
          float v = acc[m][n][i] + bv;
          if (EPI == EPI_RESID) {
            float r = res[(size_t)rg * N + cg];
            outf[(size_t)rg * N + cg] = r + gate[cg] * v;
          } else {
            atomicAdd(&outf[(size_t)rg * N + cg], gate[cg] * v);
          }
        }
      }
    }
  }
}

// ---------------- flash attention, swapped-QK^T 32x32 structure ----------------
template <int MASKED>
static __device__ __forceinline__ void attn_tile(const u16* Kt, const u16* Vp0, const u16* Vp1,
                                                 const short8* qf, int kb, int q0, int l31, int hi,
                                                 float& m, float& lsum, f32x16& o0, f32x16& o1) {
  f32x16 s0 = {}, s1 = {};
  const u16* kp0 = Kt + (size_t)l31 * 64 + hi * 8;
  const u16* kp1 = Kt + (size_t)(32 + l31) * 64 + hi * 8;
  __builtin_amdgcn_s_setprio(1);
#pragma unroll
  for (int s = 0; s < 4; ++s) {
    short8 kf0 = *(const short8*)(kp0 + s * 16);
    short8 kf1 = *(const short8*)(kp1 + s * 16);
    s0 = mfma32(kf0, qf[s], s0);   // S^T[k][q]
    s1 = mfma32(kf1, qf[s], s1);
  }
  __builtin_amdgcn_s_setprio(0);
  if (MASKED) {
    int qg = q0 + l31;
#pragma unroll
    for (int r = 0; r < 16; ++r) {
      int kk = kb + (r & 3) + 8 * (r >> 2) + 4 * hi;
      if (kk > qg) s0[r] = -INFINITY;
      if (kk + 32 > qg) s1[r] = -INFINITY;
    }
  }
  float pm = -INFINITY;
#pragma unroll
  for (int r = 0; r < 16; ++r) pm = fmaxf(pm, fmaxf(s0[r], s1[r]));
  pm = fmaxf(pm, __shfl_xor(pm, 32));
  if (!__all(pm <= m + DEFER_THR)) {
    float mn = fmaxf(m, pm);
    float al = exp2f(m - mn);
    m = mn;
    lsum *= al;
#pragma unroll
    for (int r = 0; r < 16; ++r) {
      float alr = __shfl(al, (r & 3) + 8 * (r >> 2) + 4 * hi);
      o0[r] *= alr;
      o1[r] *= alr;
    }
  }
  float ts = 0.f;
#pragma unroll
  for (int r = 0; r < 16; ++r) {
    float p0 = exp2f(s0[r] - m);
    float p1 = exp2f(s1[r] - m);
    s0[r] = p0; s1[r] = p1;
    ts += p0 + p1;
  }
  ts += __shfl_xor(ts, 32);
  lsum += ts;
  auto pack8 = [&](float a0, float a1, float a2, float a3,
                   float a4, float a5, float a6, float a7) -> short8 {
    u32 c0 = cvtpk_bf16(a0, a1), c1 = cvtpk_bf16(a2, a3);
    u32 c2 = cvtpk_bf16(a4, a5), c3 = cvtpk_bf16(a6, a7);
    u32x2 r02 = __builtin_amdgcn_permlane32_swap(c0, c2, false, false);
    u32x2 r13 = __builtin_amdgcn_permlane32_swap(c1, c3, false, false);
    u32x4 w;
    w[0] = r02[0]; w[1] = r13[0]; w[2] = r02[1]; w[3] = r13[1];
    return __builtin_bit_cast(short8, w);
  };
  short8 pa0 = pack8(s0[0], s0[1], s0[2], s0[3], s0[4], s0[5], s0[6], s0[7]);
  short8 pa1 = pack8(s0[8], s0[9], s0[10], s0[11], s0[12], s0[13], s0[14], s0[15]);
  short8 pa2 = pack8(s1[0], s1[1], s1[2], s1[3], s1[4], s1[5], s1[6], s1[7]);
  short8 pa3 = pack8(s1[8], s1[9], s1[10], s1[11], s1[12], s1[13], s1[14], s1[15]);
  short8 pa[4] = {pa0, pa1, pa2, pa3};
  __builtin_amdgcn_s_setprio(1);
#pragma unroll
  for (int ks = 0; ks < 4; ++ks) {
    short8 bv0 = *(const short8*)(Vp0 + ks * 16 + hi * 8);
    short8 bv1 = *(const short8*)(Vp1 + ks * 16 + hi * 8);
    o0 = mfma32(pa[ks], bv0, o0);
    o1 = mfma32(pa[ks], bv1, o1);
  }
  __builtin_amdgcn_s_setprio(0);
}

template <int CAUSAL>
__global__ __launch_bounds__(256) void flash_attn2(const u16* __restrict__ Q, const u16* __restrict__ K,
                                                   const u16* __restrict__ Vt, u16* __restrict__ O,
                                                   int Lq, int Lk) {
  const int wid = threadIdx.x >> 6, lane = threadIdx.x & 63;
  const int l31 = lane & 31, hi = lane >> 5;
  int wg = blockIdx.x * 4 + wid;     // 4 independent waves per block, no barriers
  int bh = wg & 63;
  int qc = wg >> 6;
  if (CAUSAL) qc = (Lq >> 5) - 1 - qc;   // heavy q-chunks dispatch first
  int q0 = qc << 5;

  const u16* Qb = Q + ((size_t)bh * Lq + q0) * 64;
  const u16* Kb = K + (size_t)bh * Lk * 64;
  const u16* Vb = Vt + (size_t)bh * 64 * Lk;

  short8 qf[4];
#pragma unroll
  for (int s = 0; s < 4; ++s) qf[s] = *(const short8*)(Qb + (size_t)l31 * 64 + s * 16 + hi * 8);

  f32x16 o0 = {}, o1 = {};
  float m = -INFINITY, lsum = 0.f;

  const u16* Kt = Kb;
  const u16* Vp0 = Vb + (size_t)l31 * Lk;
  const u16* Vp1 = Vb + (size_t)(32 + l31) * Lk;

  int nt = CAUSAL ? ((q0 >> 6) + 1) : (Lk >> 6);
  for (int t = 0; t < nt - 1; ++t) {
    attn_tile<0>(Kt, Vp0, Vp1, qf, t * 64, q0, l31, hi, m, lsum, o0, o1);
    Kt += 64 * 64; Vp0 += 64; Vp1 += 64;
  }
  if (CAUSAL)
    attn_tile<1>(Kt, Vp0, Vp1, qf, (nt - 1) * 64, q0, l31, hi, m, lsum, o0, o1);
  else
    attn_tile<0>(Kt, Vp0, Vp1, qf, (nt - 1) * 64, q0, l31, hi, m, lsum, o0, o1);

  float myinv = 1.f / lsum;
  int b = bh >> 4, h = bh & 15;
#pragma unroll
  for (int r = 0; r < 16; ++r) {
    int cr = (r & 3) + 8 * (r >> 2) + 4 * hi;
    float li = __shfl(myinv, cr);
    u16* op = O + ((size_t)b * Lq + q0 + cr) * 1024 + h * 64;
    op[l31] = f2bf(o0[r] * li);
    op[32 + l31] = f2bf(o1[r] * li);
  }
}

// ---------------- launch ----------------
extern "C" void kernel_launch(void* const* d_in, const int* in_sizes, int n_in,
                              void* d_out, int out_size, void* d_ws, size_t ws_size,
                              hipStream_t stream) {
  (void)in_sizes; (void)n_in; (void)out_size;
  if (ws_size < WS_NEED) return;  // need ~105 MB scratch

  const float* x     = (const float*)d_in[0];
  const float* ctx   = (const float*)d_in[1];
  const float* g_msa = (const float*)d_in[3];
  const float* g_ca  = (const float*)d_in[4];
  const float* g_mlp = (const float*)d_in[5];
  const float* n1w = (const float*)d_in[6],  *n1b = (const float*)d_in[7];
  const float* n2w = (const float*)d_in[8],  *n2b = (const float*)d_in[9];
  const float* n3w = (const float*)d_in[10], *n3b = (const float*)d_in[11];
  const float* sa_qw = (const float*)d_in[12], *sa_kw = (const float*)d_in[14];
  const float* sa_vw = (const float*)d_in[16], *sa_pw = (const float*)d_in[18];
  const float* sa_qb = (const float*)d_in[13], *sa_kb = (const float*)d_in[15];
  const float* sa_vb = (const float*)d_in[17], *sa_pb = (const float*)d_in[19];
  const float* ca_qw = (const float*)d_in[20], *ca_qb = (const float*)d_in[21];
  const float* ca_kw = (const float*)d_in[22], *ca_kb = (const float*)d_in[23];
  const float* ca_vw = (const float*)d_in[24], *ca_vb = (const float*)d_in[25];
  const float* ca_pw = (const float*)d_in[26], *ca_pb = (const float*)d_in[27];
  const float* fc1w = (const float*)d_in[28], *fc1b = (const float*)d_in[29];
  const float* fc2w = (const float*)d_in[30], *fc2b = (const float*)d_in[31];

  char* ws = (char*)d_ws;
  float* out = (float*)d_out;
  float* tcos = (float*)(ws + OFF_TCOS);
  float* tsin = (float*)(ws + OFF_TSIN);
  u16* Hb   = (u16*)(ws + OFF_H);
  u16* QKV  = (u16*)(ws + OFF_QKV);
  u16* QR   = (u16*)(ws + OFF_QR);
  u16* KR   = (u16*)(ws + OFF_KR);
  u16* VT   = (u16*)(ws + OFF_VT);
  u16* AO   = (u16*)(ws + OFF_AO);

  // RoPE tables
  build_tab<<<dim3(128), dim3(256), 0, stream>>>(tcos, tsin);

  // fused weight/context conversion (fp32 -> bf16) into contiguous ws region
  Cvt11 ca;
  ca.s[0] = sa_qw; ca.s[1] = sa_kw; ca.s[2] = sa_vw; ca.s[3] = sa_pw;
  ca.s[4] = ca_qw; ca.s[5] = ca_kw; ca.s[6] = ca_vw; ca.s[7] = ca_pw;
  ca.s[8] = fc1w;  ca.s[9] = fc2w;  ca.s[10] = ctx;
  cvt_all<<<dim3(18432), dim3(256), 0, stream>>>(ca, (u16*)(ws + OFF_WSAQKV));
  Cp5 cp;
  cp.s[0] = sa_qb; cp.s[1] = sa_kb; cp.s[2] = sa_vb; cp.s[3] = ca_kb; cp.s[4] = ca_vb;
  copy5<<<dim3(20), dim3(256), 0, stream>>>(cp, (float*)(ws + OFF_BSAQKV));

  // ---- self-attention ----
  ln_bf16<<<dim3(NTOK), dim3(256), 0, stream>>>(x, n1w, n1b, Hb);
  gemm6<EPI_BF16><<<dim3(3072 / 128, NTOK / 128), dim3(256), 0, stream>>>(
      Hb, (u16*)(ws + OFF_WSAQKV), (float*)(ws + OFF_BSAQKV), QKV, nullptr, nullptr, nullptr,
      NTOK, 3072, 1024, 1);
  {
    Rope3 r;
    r.j[0] = {QKV, QR, 3072, 0,    LQ, NTOK, 0, QSCALE};
    r.j[1] = {QKV, KR, 3072, 1024, LQ, NTOK, 0, 1.0f};
    r.j[2] = {QKV, VT, 3072, 2048, LQ, NTOK, 1, 1.0f};
    rope3<<<dim3(NTOK, 3), dim3(128), 0, stream>>>(r, tcos, tsin);
  }
  flash_attn2<1><<<dim3(512), dim3(256), 0, stream>>>(QR, KR, VT, AO, LQ, LQ);
  gemm6<EPI_RESID><<<dim3(1024 / 128, NTOK / 128), dim3(256), 0, stream>>>(
      AO, (u16*)(ws + OFF_WSAP), sa_pb, nullptr, out, x, g_msa, NTOK, 1024, 1024, 1);

  // ---- cross-attention ----
  ln_bf16<<<dim3(NTOK), dim3(256), 0, stream>>>(out, n2w, n2b, Hb);
  gemm6<EPI_BF16><<<dim3(1024 / 128, NTOK / 128), dim3(256), 0, stream>>>(
      Hb, (u16*)(ws + OFF_WCAQ), ca_qb, (u16*)(ws + OFF_CAQ), nullptr, nullptr, nullptr,
      NTOK, 1024, 1024, 1);
  gemm6<EPI_BF16><<<dim3(2048 / 128, NCTX / 128), dim3(256), 0, stream>>>(
      (u16*)(ws + OFF_CTXB), (u16*)(ws + OFF_WCAKV), (float*)(ws + OFF_BCAKV),
      (u16*)(ws + OFF_CAKV), nullptr, nullptr, nullptr, NCTX, 2048, 1024, 1);
  {
    Rope3 r;
    r.j[0] = {(u16*)(ws + OFF_CAQ),  QR, 1024, 0,    LQ, NTOK, 0, QSCALE};
    r.j[1] = {(u16*)(ws + OFF_CAKV), KR, 2048, 0,    LC, NCTX, 0, 1.0f};
    r.j[2] = {(u16*)(ws + OFF_CAKV), VT, 2048, 1024, LC, NCTX, 1, 1.0f};
    rope3<<<dim3(NTOK, 3), dim3(128), 0, stream>>>(r, tcos, tsin);
  }
  flash_attn2<0><<<dim3(512), dim3(256), 0, stream>>>(QR, KR, VT, AO, LQ, LC);
  gemm6<EPI_RESID><<<dim3(1024 / 128, NTOK / 128), dim3(256), 0, stream>>>(
      AO, (u16*)(ws + OFF_WCAP), ca_pb, nullptr, out, out, g_ca, NTOK, 1024, 1024, 1);

  // ---- MLP ----
  ln_bf16<<<dim3(NTOK), dim3(256), 0, stream>>>(out, n3w, n3b, Hb);
  gemm6<EPI_GELU><<<dim3(4096 / 128, NTOK / 128), dim3(256), 0, stream>>>(
      Hb, (u16*)(ws + OFF_WFC1), fc1b, (u16*)(ws + OFF_U), nullptr, nullptr, nullptr,
      NTOK, 4096, 1024, 1);
  // fc2: split-K x2, atomic accumulation; bias+gate pre-applied
  init_bias_gate<<<dim3(4096), dim3(256), 0, stream>>>(out, fc2b, g_mlp);
  gemm6<EPI_ATOMIC><<<dim3(1024 / 128, NTOK / 128, 2), dim3(256), 0, stream>>>(
      (u16*)(ws + OFF_U), (u16*)(ws + OFF_WFC2), nullptr, nullptr, out, nullptr, g_mlp,
      NTOK, 1024, 4096, 2);
}

// Round 10
// 406.449 us; speedup vs baseline: 1.1036x; 1.1036x over previous
//
#include <hip/hip_runtime.h>
#include <math.h>

#if !__has_builtin(__builtin_amdgcn_cvt_pk_fp8_f32)
#include <hip/hip_fp8.h>
#endif

typedef __attribute__((ext_vector_type(8))) short short8;
typedef __attribute__((ext_vector_type(4))) float f32x4;
typedef __attribute__((ext_vector_type(16))) float f32x16;
typedef unsigned char u8;
typedef unsigned short u16;
typedef unsigned int u32;
typedef __attribute__((ext_vector_type(2))) u32 u32x2;
typedef __attribute__((ext_vector_type(4))) u32 u32x4;
typedef __attribute__((ext_vector_type(8))) int i32x8;
typedef unsigned long long u64;

static constexpr int E = 1024, H = 16, LQ = 1024, LC = 512, Bn = 4, FF = 4096;
static constexpr int NTOK = Bn * LQ;   // 4096
static constexpr int NCTX = Bn * LC;   // 2048

// Q pre-scale: 1/sqrt(64) * log2(e)  (softmax runs in exp2 domain)
#define QSCALE 0.1803368801111244f
#define DEFER_THR 11.5f

// ---------------- workspace layout (bytes) ----------------
static constexpr size_t OFF_TCOS   = 0;                                    // 1024*32 f32
static constexpr size_t OFF_TSIN   = OFF_TCOS + (size_t)LQ*32*4;
static constexpr size_t OFF_BSAQKV = OFF_TSIN + (size_t)LQ*32*4;           // 3072 f32 (+ca_k/v bias after)
static constexpr size_t OFF_BCAKV  = OFF_BSAQKV + 16384;                   // 2048 f32
// contiguous bf16 weight region (order matters for cvt_all):
static constexpr size_t OFF_WSAQKV = OFF_BCAKV + 16384;                    // [3072][1024] bf16
static constexpr size_t OFF_WSAP   = OFF_WSAQKV + (size_t)3072*1024*2;     // [1024][1024]
static constexpr size_t OFF_WCAQ   = OFF_WSAP   + (size_t)1024*1024*2;
static constexpr size_t OFF_WCAKV  = OFF_WCAQ   + (size_t)1024*1024*2;     // [2048][1024]
static constexpr size_t OFF_WCAP   = OFF_WCAKV  + (size_t)2048*1024*2;
static constexpr size_t OFF_WFC1   = OFF_WCAP   + (size_t)1024*1024*2;     // [4096][1024] (bf16, unused now)
static constexpr size_t OFF_WFC2   = OFF_WFC1   + (size_t)4096*1024*2;     // [1024][4096] (bf16, unused now)
static constexpr size_t OFF_CTXB   = OFF_WFC2   + (size_t)1024*4096*2;     // [2048][1024] bf16
static constexpr size_t OFF_H      = OFF_CTXB   + (size_t)2048*1024*2;     // [4096][1024] bf16 (LN out) / fp8 for ln3
static constexpr size_t OFF_QKV    = OFF_H      + (size_t)4096*1024*2;     // [4096][3072] bf16
static constexpr size_t OFF_CAQ    = OFF_QKV;                              // [4096][1024]
static constexpr size_t OFF_CAKV   = OFF_QKV + (size_t)4096*1024*2;        // [2048][2048]
static constexpr size_t OFF_QR     = OFF_QKV + (size_t)4096*3072*2;        // [B,H,LQ,64] / fp8 fc1w after CA
static constexpr size_t OFF_KR     = OFF_QR  + (size_t)4096*1024*2;        // [B,H,Lk,64] / fp8 fc2w after CA
static constexpr size_t OFF_VT     = OFF_KR  + (size_t)4096*1024*2;        // [B,H,64,Lk]
static constexpr size_t OFF_AO     = OFF_VT  + (size_t)4096*1024*2;        // [4096][1024] bf16
static constexpr size_t OFF_U      = OFF_QKV;                              // fc1 out [4096][4096] fp8 reuses QKV
static constexpr size_t WS_NEED    = OFF_AO + (size_t)4096*1024*2;         // ~105 MB

// ---------------- helpers ----------------
static __device__ __forceinline__ float bf2f(u16 u) {
  union { u32 i; float f; } un; un.i = ((u32)u) << 16; return un.f;
}
static __device__ __forceinline__ u16 f2bf(float f) {  // RNE
  union { float f; u32 u; } un; un.f = f;
  u32 u = un.u;
  return (u16)((u + 0x7FFFu + ((u >> 16) & 1u)) >> 16);
}
static __device__ __forceinline__ u64 pack4(u16 a, u16 b, u16 c, u16 d) {
  return (u64)a | ((u64)b << 16) | ((u64)c << 32) | ((u64)d << 48);
}
static __device__ __forceinline__ f32x4 mfma16(short8 a, short8 b, f32x4 c) {
  return __builtin_amdgcn_mfma_f32_16x16x32_bf16(a, b, c, 0, 0, 0);
}
static __device__ __forceinline__ f32x16 mfma32(short8 a, short8 b, f32x16 c) {
  return __builtin_amdgcn_mfma_f32_32x32x16_bf16(a, b, c, 0, 0, 0);
}
static __device__ __forceinline__ void gload_lds16(void* lds, const void* g) {
  __builtin_amdgcn_global_load_lds(
      (const __attribute__((address_space(1))) void*)g,
      (__attribute__((address_space(3))) void*)lds, 16, 0, 0);
}
// gelu(x) = 0.5x(1+tanh(z)) = x*e/(e+1), e=exp(2*0.79788456(x+0.044715x^3)).
static __device__ __forceinline__ float gelu_tanh(float x) {
  float z2 = 1.5957691216057308f * (x + 0.044715f * x * x * x);
  float e = __expf(z2);
  float r = __builtin_amdgcn_rcpf(e + 1.0f);
  return x - x * r;   // x*(1 - 1/(e+1)) = x*e/(e+1)
}
static __device__ __forceinline__ u32 cvtpk_bf16(float lo, float hi) {
  u32 r;
  asm("v_cvt_pk_bf16_f32 %0, %1, %2" : "=v"(r) : "v"(lo), "v"(hi));
  return r;
}
// fp32 -> OCP e4m3 (saturating)
static __device__ __forceinline__ u32 pack_fp8x4(float a, float b, float c, float d) {
#if __has_builtin(__builtin_amdgcn_cvt_pk_fp8_f32)
  u32 r = (u32)__builtin_amdgcn_cvt_pk_fp8_f32(a, b, 0, false);
  r = (u32)__builtin_amdgcn_cvt_pk_fp8_f32(c, d, (int)r, true);
  return r;
#else
  __hip_fp8_e4m3 qa(a), qb(b), qc(c), qd(d);
  return (u32)qa.__x | ((u32)qb.__x << 8) | ((u32)qc.__x << 16) | ((u32)qd.__x << 24);
#endif
}
static __device__ __forceinline__ u8 fp8b(float f) {
#if __has_builtin(__builtin_amdgcn_cvt_pk_fp8_f32)
  return (u8)((u32)__builtin_amdgcn_cvt_pk_fp8_f32(f, f, 0, false) & 0xFFu);
#else
  __hip_fp8_e4m3 t(f); return t.__x;
#endif
}

// ---------------- small kernels ----------------
__global__ __launch_bounds__(256) void build_tab(float* __restrict__ ct, float* __restrict__ st) {
  int idx = blockIdx.x * 256 + threadIdx.x;           // 1024*32 entries
  int pos = idx >> 5, i = idx & 31;
  float inv = powf(10000.f, -(float)i * (1.f / 32.f));
  float a = (float)pos * inv;
  ct[idx] = cosf(a);
  st[idx] = sinf(a);
}

// fused fp32->bf16 conversion of weights + context (segments 8,9 = fc1w/fc2w
// now go through cvt_fp8 instead -> early-exit).
struct Cvt11 { const float* s[11]; };
__global__ __launch_bounds__(256) void cvt_all(Cvt11 a, u16* __restrict__ dst) {
  u32 gid = blockIdx.x * 256 + threadIdx.x;   // 0 .. 4718591
  u32 s, off;
  if (gid < 2097152u)      { s = gid >> 18;                        off = gid & 262143u; }
  else if (gid < 4194304u) { return; }        // fc1w/fc2w handled in fp8
  else                     { s = 10;                               off = gid - 4194304u; }
  float4 v = *(const float4*)(a.s[s] + (size_t)off * 4);
  *(u64*)(dst + (size_t)gid * 4) = pack4(f2bf(v.x), f2bf(v.y), f2bf(v.z), f2bf(v.w));
}

// fc1w/fc2w -> fp8 e4m3 scaled x256 (weights ~N(0,0.02) -> ~N(0,5): clear of subnormals)
__global__ __launch_bounds__(256) void cvt_fp8(const float* __restrict__ s0, const float* __restrict__ s1,
                                               u8* __restrict__ d0, u8* __restrict__ d1) {
  u32 gid = blockIdx.x * 256 + threadIdx.x;   // 0..2097151, 4 elems each
  const float* s; u8* d; u32 off;
  if (gid < 1048576u) { s = s0; d = d0; off = gid; }
  else                { s = s1; d = d1; off = gid - 1048576u; }
  float4 v = *(const float4*)(s + (size_t)off * 4);
  *(u32*)(d + (size_t)off * 4) =
      pack_fp8x4(v.x * 256.f, v.y * 256.f, v.z * 256.f, v.w * 256.f);
}

// fused bias copies: sa_q,sa_k,sa_v -> BSAQKV(+0,+1024,+2048); ca_k,ca_v -> BCAKV(+0,+1024)
struct Cp5 { const float* s[5]; };
__global__ __launch_bounds__(256) void copy5(Cp5 a, float* __restrict__ dst) {
  int gid = blockIdx.x * 256 + threadIdx.x;   // 0..5119
  int s = gid >> 10, off = gid & 1023;
  int doff = (s < 3) ? s * 1024 : 4096 + (s - 3) * 1024;
  dst[doff + off] = a.s[s][off];
}

// out[row][c] += gate[c]*bias[c]  (init pass for split-K atomic GEMM)
__global__ __launch_bounds__(256) void init_bias_gate(float* __restrict__ out, const float* __restrict__ bias,
                                                      const float* __restrict__ gate) {
  int i = (blockIdx.x * 256 + threadIdx.x) * 4;
  int c = i & 1023;
  float4 o = *(float4*)(out + i);
  o.x += gate[c] * bias[c];
  o.y += gate[c + 1] * bias[c + 1];
  o.z += gate[c + 2] * bias[c + 2];
  o.w += gate[c + 3] * bias[c + 3];
  *(float4*)(out + i) = o;
}

// LN over last dim 1024, one row per block, bf16 out.
__global__ __launch_bounds__(256) void ln_bf16(const float* __restrict__ x, const float* __restrict__ w,
                                               const float* __restrict__ b, u16* __restrict__ out) {
  __shared__ float red[4];
  int row = blockIdx.x, tid = threadIdx.x;
  const float* xr = x + (size_t)row * 1024;
  float4 v = ((const float4*)xr)[tid];
  float s = v.x + v.y + v.z + v.w;
#pragma unroll
  for (int off = 32; off; off >>= 1) s += __shfl_xor(s, off);
  if ((tid & 63) == 0) red[tid >> 6] = s;
  __syncthreads();
  float mean = (red[0] + red[1] + red[2] + red[3]) * (1.f / 1024.f);
  float dx = v.x - mean, dy = v.y - mean, dz = v.z - mean, dw = v.w - mean;
  float sq = dx * dx + dy * dy + dz * dz + dw * dw;
#pragma unroll
  for (int off = 32; off; off >>= 1) sq += __shfl_xor(sq, off);
  __syncthreads();
  if ((tid & 63) == 0) red[tid >> 6] = sq;
  __syncthreads();
  float var = (red[0] + red[1] + red[2] + red[3]) * (1.f / 1024.f);
  float rstd = rsqrtf(var + 1e-6f);
  float4 wv = ((const float4*)w)[tid];
  float4 bv = ((const float4*)b)[tid];
  u64 o = pack4(f2bf(dx * rstd * wv.x + bv.x), f2bf(dy * rstd * wv.y + bv.y),
                f2bf(dz * rstd * wv.z + bv.z), f2bf(dw * rstd * wv.w + bv.w));
  *(u64*)(out + (size_t)row * 1024 + tid * 4) = o;
}

// LN -> fp8 e4m3 scaled x16 (for the fp8 MLP path)
__global__ __launch_bounds__(256) void ln_fp8(const float* __restrict__ x, const float* __restrict__ w,
                                              const float* __restrict__ b, u8* __restrict__ out) {
  __shared__ float red[4];
  int row = blockIdx.x, tid = threadIdx.x;
  const float* xr = x + (size_t)row * 1024;
  float4 v = ((const float4*)xr)[tid];
  float s = v.x + v.y + v.z + v.w;
#pragma unroll
  for (int off = 32; off; off >>= 1) s += __shfl_xor(s, off);
  if ((tid & 63) == 0) red[tid >> 6] = s;
  __syncthreads();
  float mean = (red[0] + red[1] + red[2] + red[3]) * (1.f / 1024.f);
  float dx = v.x - mean, dy = v.y - mean, dz = v.z - mean, dw = v.w - mean;
  float sq = dx * dx + dy * dy + dz * dz + dw * dw;
#pragma unroll
  for (int off = 32; off; off >>= 1) sq += __shfl_xor(sq, off);
  __syncthreads();
  if ((tid & 63) == 0) red[tid >> 6] = sq;
  __syncthreads();
  float var = (red[0] + red[1] + red[2] + red[3]) * (1.f / 1024.f);
  float rstd = rsqrtf(var + 1e-6f);
  float4 wv = ((const float4*)w)[tid];
  float4 bv = ((const float4*)b)[tid];
  u32 pk = pack_fp8x4((dx * rstd * wv.x + bv.x) * 16.f, (dy * rstd * wv.y + bv.y) * 16.f,
                      (dz * rstd * wv.z + bv.z) * 16.f, (dw * rstd * wv.w + bv.w) * 16.f);
  *(u32*)(out + (size_t)row * 1024 + tid * 4) = pk;
}

// Fused RoPE/scatter: 3 jobs in one dispatch (blockIdx.y selects job).
struct RopeJob { const u16* src; u16* dst; int ld, col0, Lper, T, mode; float scale; };
struct Rope3 { RopeJob j[3]; };
__global__ __launch_bounds__(128) void rope3(Rope3 a, const float* __restrict__ cosT,
                                             const float* __restrict__ sinT) {
  RopeJob jb = a.j[blockIdx.y];
  int t = blockIdx.x;
  if (t >= jb.T) return;
  int b = t / jb.Lper, l = t - b * jb.Lper;
  int tid = threadIdx.x;
  int e0 = tid * 8;
  int h = e0 >> 6, d0 = e0 & 63;
  short8 vv = *(const short8*)(jb.src + (size_t)t * jb.ld + jb.col0 + e0);
  if (jb.mode == 0) {
    short8 ov;
#pragma unroll
    for (int j = 0; j < 4; ++j) {
      float x1 = bf2f((u16)vv[2 * j]);
      float x2 = bf2f((u16)vv[2 * j + 1]);
      int i = (d0 >> 1) + j;
      float c = cosT[l * 32 + i], s = sinT[l * 32 + i];
      ov[2 * j]     = (short)f2bf((x1 * c - x2 * s) * jb.scale);
      ov[2 * j + 1] = (short)f2bf((x1 * s + x2 * c) * jb.scale);
    }
    *(short8*)(jb.dst + (((size_t)b * H + h) * jb.Lper + l) * 64 + d0) = ov;
  } else {
#pragma unroll
    for (int m = 0; m < 8; ++m)
      jb.dst[(((size_t)b * H + h) * 64 + d0 + m) * jb.Lper + l] = (u16)vv[m];
  }
}

// ---------------- bf16 GEMM (proven R8 config): C = A @ W^T + bias ----------------
enum { EPI_BF16 = 0, EPI_GELU = 1, EPI_RESID = 2, EPI_ATOMIC = 3 };

template <int EPI>
__global__ __launch_bounds__(512, 4) void gemm2(const u16* __restrict__ A, const u16* __restrict__ W,
                                                const float* __restrict__ bias, u16* outb, float* outf,
                                                const float* res, const float* __restrict__ gate,
                                                int M, int N, int K, int kchunks) {
  __shared__ u16 As[2][128 * 64];
  __shared__ u16 Bs[2][128 * 64];

  int nwg = gridDim.x * gridDim.y;
  int bid = blockIdx.y * gridDim.x + blockIdx.x;
  int cpx = nwg >> 3;
  int swz = (bid & 7) * cpx + (bid >> 3);
  int bx = swz % gridDim.x;
  int by = swz / gridDim.x;
  int row0 = by * 128, col0 = bx * 128;

  const int Kc = K / kchunks;
  const int kbase = blockIdx.z * Kc;

  int tid = threadIdx.x;
  int lane = tid & 63, wid = tid >> 6;
  int wr = wid >> 2, wc = wid & 3;  // 2x4 waves, each owns 64x32
  int lr = lane & 15, lg = lane >> 4;

  size_t a_off0, a_off1, b_off0, b_off1;
  int l_off0 = tid * 8, l_off1 = (512 + tid) * 8;
  {
    int q = tid, r = q >> 3, p = q & 7, sp = p ^ (r & 7);
    a_off0 = (size_t)(row0 + r) * K + sp * 8;
    b_off0 = (size_t)(col0 + r) * K + sp * 8;
    q = 512 + tid; r = q >> 3; p = q & 7; sp = p ^ (r & 7);
    a_off1 = (size_t)(row0 + r) * K + sp * 8;
    b_off1 = (size_t)(col0 + r) * K + sp * 8;
  }

  f32x4 acc[4][2] = {};

  const int nkt = Kc >> 6;
  {
    gload_lds16(&As[0][l_off0], A + a_off0 + kbase);
    gload_lds16(&Bs[0][l_off0], W + b_off0 + kbase);
    gload_lds16(&As[0][l_off1], A + a_off1 + kbase);
    gload_lds16(&Bs[0][l_off1], W + b_off1 + kbase);
  }
  __syncthreads();

  for (int kt = 0; kt < nkt; ++kt) {
    int cur = kt & 1;
    if (kt + 1 < nkt) {
      int k0 = kbase + ((kt + 1) << 6);
      gload_lds16(&As[cur ^ 1][l_off0], A + a_off0 + k0);
      gload_lds16(&Bs[cur ^ 1][l_off0], W + b_off0 + k0);
      gload_lds16(&As[cur ^ 1][l_off1], A + a_off1 + k0);
      gload_lds16(&Bs[cur ^ 1][l_off1], W + b_off1 + k0);
    }
#pragma unroll
    for (int kk = 0; kk < 2; ++kk) {
      short8 af[4], bfr[2];
#pragma unroll
      for (int m = 0; m < 4; ++m) {
        int r = wr * 64 + m * 16 + lr;
        int sc = (kk * 4 + lg) ^ (r & 7);
        af[m] = *(const short8*)(&As[cur][r * 64 + sc * 8]);
      }
#pragma unroll
      for (int n = 0; n < 2; ++n) {
        int r = wc * 32 + n * 16 + lr;
        int sc = (kk * 4 + lg) ^ (r & 7);
        bfr[n] = *(const short8*)(&Bs[cur][r * 64 + sc * 8]);
      }
#pragma unroll
      for (int m = 0; m < 4; ++m)
#pragma unroll
        for (int n = 0; n < 2; ++n)
          acc[m][n] = mfma16(af[m], bfr[n], acc[m][n]);
    }
    __syncthreads();
  }

  if (EPI == EPI_BF16 || EPI == EPI_GELU) {
    u16* Ct = &As[0][0];
#pragma unroll
    for (int n = 0; n < 2; ++n) {
      int c = wc * 32 + n * 16 + lr;
      float bv = bias[col0 + c];
#pragma unroll
      for (int m = 0; m < 4; ++m) {
#pragma unroll
        for (int i = 0; i < 4; ++i) {
          int r = wr * 64 + m * 16 + lg * 4 + i;
          float v = acc[m][n][i] + bv;
          Ct[r * 128 + c] = f2bf(EPI == EPI_GELU ? gelu_tanh(v) : v);
        }
      }
    }
    __syncthreads();
#pragma unroll
    for (int j = 0; j < 4; ++j) {
      u32 q = (u32)tid + j * 512;
      u32 r = q >> 4, ck = q & 15;
      short8 v = *(const short8*)(Ct + r * 128 + ck * 8);
      *(short8*)(outb + (size_t)(row0 + r) * N + col0 + ck * 8) = v;
    }
  } else {
#pragma unroll
    for (int n = 0; n < 2; ++n) {
      int cg = col0 + wc * 32 + n * 16 + lr;
      float bv = (EPI == EPI_ATOMIC) ? 0.f : bias[cg];
#pragma unroll
      for (int m = 0; m < 4; ++m) {
#pragma unroll
        for (int i = 0; i < 4; ++i) {
          int rg = row0 + wr * 64 + m * 16 + lg * 4 + i;
          float v = acc[m][n][i] + bv;
          if (EPI == EPI_RESID) {
            float r = res[(size_t)rg * N + cg];
            outf[(size_t)rg * N + cg] = r + gate[cg] * v;
          } else {
            atomicAdd(&outf[(size_t)rg * N + cg], gate[cg] * v);
          }
        }
      }
    }
  }
}

// ---------------- fp8 MX GEMM: C = (A/16) @ (W/256)^T -> acc/4096 ----------------
// 128x128 tile, BK=128, 256 threads (2x2 waves of 64x64 = 2x2 32x32-frags),
// dbuf 64 KiB LDS, gemm2 pipeline. mfma_scale_f32_32x32x64_f8f6f4 with unity
// E8M0 scales (0x7F). LDS bytes/FLOP = half of bf16 + 2x MFMA rate -> ~70% ceiling.
enum { E8_GELU = 0, E8_ATOMIC = 1 };

template <int EPI>
__global__ __launch_bounds__(256, 2) void gemm8(const u8* __restrict__ A, const u8* __restrict__ W,
                                                const float* __restrict__ bias, u8* outb, float* outf,
                                                const float* __restrict__ gate,
                                                int M, int N, int K, int kchunks) {
  __shared__ u8 As[2][128 * 128];
  __shared__ u8 Bs[2][128 * 128];

  int nwg = gridDim.x * gridDim.y;
  int bid = blockIdx.y * gridDim.x + blockIdx.x;
  int cpx = nwg >> 3;
  int swz = (bid & 7) * cpx + (bid >> 3);
  int bx = swz % gridDim.x, by = swz / gridDim.x;
  int row0 = by * 128, col0 = bx * 128;

  const int Kc = K / kchunks;
  const int kbase = blockIdx.z * Kc;

  int tid = threadIdx.x;
  int lane = tid & 63, wid = tid >> 6;
  int wr = wid >> 1, wc = wid & 1;      // 2x2 waves, each owns 64x64
  int l31 = lane & 31, hi = lane >> 5;

  // staging: tile = 128 rows x 128 B = 1024 chunks of 16 B; 4 per thread per matrix.
  u32 aoff[4], boff[4];
  int ldso[4];
#pragma unroll
  for (int j = 0; j < 4; ++j) {
    int q = tid + j * 256;
    int r = q >> 3, p = q & 7, sp = p ^ (r & 7);
    aoff[j] = (u32)(row0 + r) * (u32)K + sp * 16;
    boff[j] = (u32)(col0 + r) * (u32)K + sp * 16;
    ldso[j] = q * 16;
  }

  f32x16 acc[2][2] = {};
  const int nkt = Kc >> 7;              // BK = 128

  // fragment read: lane row = base+blk*32+l31; k = ks*64 + hi*32 + [0..31]
  auto rdfrag = [&](const u8* base, int wbase, int ks, i32x8* f) {
#pragma unroll
    for (int blk = 0; blk < 2; ++blk) {
      int r = wbase + blk * 32 + l31;
      const u8* rp = base + r * 128;
      int ck = ks * 4 + hi * 2;
      u32x4 lo = *(const u32x4*)(rp + ((ck) ^ (r & 7)) * 16);
      u32x4 hh = *(const u32x4*)(rp + ((ck + 1) ^ (r & 7)) * 16);
      i32x8 v;
      v[0] = (int)lo[0]; v[1] = (int)lo[1]; v[2] = (int)lo[2]; v[3] = (int)lo[3];
      v[4] = (int)hh[0]; v[5] = (int)hh[1]; v[6] = (int)hh[2]; v[7] = (int)hh[3];
      f[blk] = v;
    }
  };

  // prologue
#pragma unroll
  for (int j = 0; j < 4; ++j) {
    gload_lds16(&As[0][ldso[j]], A + aoff[j] + kbase);
    gload_lds16(&Bs[0][ldso[j]], W + boff[j] + kbase);
  }
  __syncthreads();

  for (int kt = 0; kt < nkt; ++kt) {
    int cur = kt & 1;
    if (kt + 1 < nkt) {
      int k0 = kbase + ((kt + 1) << 7);
#pragma unroll
      for (int j = 0; j < 4; ++j) {
        gload_lds16(&As[cur ^ 1][ldso[j]], A + aoff[j] + k0);
        gload_lds16(&Bs[cur ^ 1][ldso[j]], W + boff[j] + k0);
      }
    }
#pragma unroll
    for (int ks = 0; ks < 2; ++ks) {
      i32x8 a[2], b[2];
      rdfrag(&As[cur][0], wr * 64, ks, a);
      rdfrag(&Bs[cur][0], wc * 64, ks, b);
      __builtin_amdgcn_s_setprio(1);
#pragma unroll
      for (int mi = 0; mi < 2; ++mi)
#pragma unroll
        for (int ni = 0; ni < 2; ++ni)
          acc[mi][ni] = __builtin_amdgcn_mfma_scale_f32_32x32x64_f8f6f4(
              a[mi], b[ni], acc[mi][ni], 0, 0, 0, 0x7F7F7F7F, 0, 0x7F7F7F7F);
      __builtin_amdgcn_s_setprio(0);
    }
    __syncthreads();
  }

  // epilogue: C layout col=lane&31, row=(g&3)+8*(g>>2)+4*hi (shape-determined)
  constexpr float SCL = 1.f / 4096.f;   // undo x16 (act) * x256 (weights)
  if (EPI == E8_GELU) {
    u8* Ct = &As[0][0];                 // [128][128] u8 = 16 KiB
#pragma unroll
    for (int ni = 0; ni < 2; ++ni) {
      int cl = wc * 64 + ni * 32 + l31;
      float bv = bias[col0 + cl];
#pragma unroll
      for (int mi = 0; mi < 2; ++mi) {
#pragma unroll
        for (int g = 0; g < 16; ++g) {
          int rl = wr * 64 + mi * 32 + (g & 3) + 8 * (g >> 2) + 4 * hi;
          float v = acc[mi][ni][g] * SCL + bv;
          Ct[rl * 128 + cl] = fp8b(gelu_tanh(v) * 16.f);
        }
      }
    }
    __syncthreads();
#pragma unroll
    for (int j = 0; j < 4; ++j) {
      int q = tid + j * 256;
      int r = q >> 3, ck = q & 7;
      *(u32x4*)(outb + (size_t)(row0 + r) * N + col0 + ck * 16) =
          *(const u32x4*)(Ct + r * 128 + ck * 16);
    }
  } else {
#pragma unroll
    for (int ni = 0; ni < 2; ++ni) {
      int cg = col0 + wc * 64 + ni * 32 + l31;
      float gv = gate[cg];
#pragma unroll
      for (int mi = 0; mi < 2; ++mi) {
#pragma unroll
        for (int g = 0; g < 16; ++g) {
          int rg = row0 + wr * 64 + mi * 32 + (g & 3) + 8 * (g >> 2) + 4 * hi;
          atomicAdd(&outf[(size_t)rg * N + cg], gv * (acc[mi][ni][g] * SCL));
        }
      }
    }
  }
}

// ---------------- flash attention, swapped-QK^T 32x32 structure ----------------
template <int MASKED>
static __device__ __forceinline__ void attn_tile(const u16* Kt, const u16* Vp0, const u16* Vp1,
                                                 const short8* qf, int kb, int q0, int l31, int hi,
                                                 float& m, float& lsum, f32x16& o0, f32x16& o1) {
  f32x16 s0 = {}, s1 = {};
  const u16* kp0 = Kt + (size_t)l31 * 64 + hi * 8;
  const u16* kp1 = Kt + (size_t)(32 + l31) * 64 + hi * 8;
  __builtin_amdgcn_s_setprio(1);
#pragma unroll
  for (int s = 0; s < 4; ++s) {
    short8 kf0 = *(const short8*)(kp0 + s * 16);
    short8 kf1 = *(const short8*)(kp1 + s * 16);
    s0 = mfma32(kf0, qf[s], s0);   // S^T[k][q]
    s1 = mfma32(kf1, qf[s], s1);
  }
  __builtin_amdgcn_s_setprio(0);
  if (MASKED) {
    int qg = q0 + l31;
#pragma unroll
    for (int r = 0; r < 16; ++r) {
      int kk = kb + (r & 3) + 8 * (r >> 2) + 4 * hi;
      if (kk > qg) s0[r] = -INFINITY;
      if (kk + 32 > qg) s1[r] = -INFINITY;
    }
  }
  float pm = -INFINITY;
#pragma unroll
  for (int r = 0; r < 16; ++r) pm = fmaxf(pm, fmaxf(s0[r], s1[r]));
  pm = fmaxf(pm, __shfl_xor(pm, 32));
  if (!__all(pm <= m + DEFER_THR)) {
    float mn = fmaxf(m, pm);
    float al = exp2f(m - mn);
    m = mn;
    lsum *= al;
#pragma unroll
    for (int r = 0; r < 16; ++r) {
      float alr = __shfl(al, (r & 3) + 8 * (r >> 2) + 4 * hi);
      o0[r] *= alr;
      o1[r] *= alr;
    }
  }
  float ts = 0.f;
#pragma unroll
  for (int r = 0; r < 16; ++r) {
    float p0 = exp2f(s0[r] - m);
    float p1 = exp2f(s1[r] - m);
    s0[r] = p0; s1[r] = p1;
    ts += p0 + p1;
  }
  ts += __shfl_xor(ts, 32);
  lsum += ts;
  auto pack8 = [&](float a0, float a1, float a2, float a3,
                   float a4, float a5, float a6, float a7) -> short8 {
    u32 c0 = cvtpk_bf16(a0, a1), c1 = cvtpk_bf16(a2, a3);
    u32 c2 = cvtpk_bf16(a4, a5), c3 = cvtpk_bf16(a6, a7);
    u32x2 r02 = __builtin_amdgcn_permlane32_swap(c0, c2, false, false);
    u32x2 r13 = __builtin_amdgcn_permlane32_swap(c1, c3, false, false);
    u32x4 w;
    w[0] = r02[0]; w[1] = r13[0]; w[2] = r02[1]; w[3] = r13[1];
    return __builtin_bit_cast(short8, w);
  };
  short8 pa0 = pack8(s0[0], s0[1], s0[2], s0[3], s0[4], s0[5], s0[6], s0[7]);
  short8 pa1 = pack8(s0[8], s0[9], s0[10], s0[11], s0[12], s0[13], s0[14], s0[15]);
  short8 pa2 = pack8(s1[0], s1[1], s1[2], s1[3], s1[4], s1[5], s1[6], s1[7]);
  short8 pa3 = pack8(s1[8], s1[9], s1[10], s1[11], s1[12], s1[13], s1[14], s1[15]);
  short8 pa[4] = {pa0, pa1, pa2, pa3};
  __builtin_amdgcn_s_setprio(1);
#pragma unroll
  for (int ks = 0; ks < 4; ++ks) {
    short8 bv0 = *(const short8*)(Vp0 + ks * 16 + hi * 8);
    short8 bv1 = *(const short8*)(Vp1 + ks * 16 + hi * 8);
    o0 = mfma32(pa[ks], bv0, o0);
    o1 = mfma32(pa[ks], bv1, o1);
  }
  __builtin_amdgcn_s_setprio(0);
}

template <int CAUSAL>
__global__ __launch_bounds__(256) void flash_attn2(const u16* __restrict__ Q, const u16* __restrict__ K,
                                                   const u16* __restrict__ Vt, u16* __restrict__ O,
                                                   int Lq, int Lk) {
  const int wid = threadIdx.x >> 6, lane = threadIdx.x & 63;
  const int l31 = lane & 31, hi = lane >> 5;
  int wg = blockIdx.x * 4 + wid;     // 4 independent waves per block, no barriers
  int bh = wg & 63;
  int qc = wg >> 6;
  if (CAUSAL) qc = (Lq >> 5) - 1 - qc;   // heavy q-chunks dispatch first
  int q0 = qc << 5;

  const u16* Qb = Q + ((size_t)bh * Lq + q0) * 64;
  const u16* Kb = K + (size_t)bh * Lk * 64;
  const u16* Vb = Vt + (size_t)bh * 64 * Lk;

  short8 qf[4];
#pragma unroll
  for (int s = 0; s < 4; ++s) qf[s] = *(const short8*)(Qb + (size_t)l31 * 64 + s * 16 + hi * 8);

  f32x16 o0 = {}, o1 = {};
  float m = -INFINITY, lsum = 0.f;

  const u16* Kt = Kb;
  const u16* Vp0 = Vb + (size_t)l31 * Lk;
  const u16* Vp1 = Vb + (size_t)(32 + l31) * Lk;

  int nt = CAUSAL ? ((q0 >> 6) + 1) : (Lk >> 6);
  for (int t = 0; t < nt - 1; ++t) {
    attn_tile<0>(Kt, Vp0, Vp1, qf, t * 64, q0, l31, hi, m, lsum, o0, o1);
    Kt += 64 * 64; Vp0 += 64; Vp1 += 64;
  }
  if (CAUSAL)
    attn_tile<1>(Kt, Vp0, Vp1, qf, (nt - 1) * 64, q0, l31, hi, m, lsum, o0, o1);
  else
    attn_tile<0>(Kt, Vp0, Vp1, qf, (nt - 1) * 64, q0, l31, hi, m, lsum, o0, o1);

  float myinv = 1.f / lsum;
  int b = bh >> 4, h = bh & 15;
#pragma unroll
  for (int r = 0; r < 16; ++r) {
    int cr = (r & 3) + 8 * (r >> 2) + 4 * hi;
    float li = __shfl(myinv, cr);
    u16* op = O + ((size_t)b * Lq + q0 + cr) * 1024 + h * 64;
    op[l31] = f2bf(o0[r] * li);
    op[32 + l31] = f2bf(o1[r] * li);
  }
}

// ---------------- launch ----------------
extern "C" void kernel_launch(void* const* d_in, const int* in_sizes, int n_in,
                              void* d_out, int out_size, void* d_ws, size_t ws_size,
                              hipStream_t stream) {
  (void)in_sizes; (void)n_in; (void)out_size;
  if (ws_size < WS_NEED) return;  // need ~105 MB scratch

  const float* x     = (const float*)d_in[0];
  const float* ctx   = (const float*)d_in[1];
  const float* g_msa = (const float*)d_in[3];
  const float* g_ca  = (const float*)d_in[4];
  const float* g_mlp = (const float*)d_in[5];
  const float* n1w = (const float*)d_in[6],  *n1b = (const float*)d_in[7];
  const float* n2w = (const float*)d_in[8],  *n2b = (const float*)d_in[9];
  const float* n3w = (const float*)d_in[10], *n3b = (const float*)d_in[11];
  const float* sa_qw = (const float*)d_in[12], *sa_kw = (const float*)d_in[14];
  const float* sa_vw = (const float*)d_in[16], *sa_pw = (const float*)d_in[18];
  const float* sa_qb = (const float*)d_in[13], *sa_kb = (const float*)d_in[15];
  const float* sa_vb = (const float*)d_in[17], *sa_pb = (const float*)d_in[19];
  const float* ca_qw = (const float*)d_in[20], *ca_qb = (const float*)d_in[21];
  const float* ca_kw = (const float*)d_in[22], *ca_kb = (const float*)d_in[23];
  const float* ca_vw = (const float*)d_in[24], *ca_vb = (const float*)d_in[25];
  const float* ca_pw = (const float*)d_in[26], *ca_pb = (const float*)d_in[27];
  const float* fc1w = (const float*)d_in[28], *fc1b = (const float*)d_in[29];
  const float* fc2w = (const float*)d_in[30], *fc2b = (const float*)d_in[31];

  char* ws = (char*)d_ws;
  float* out = (float*)d_out;
  float* tcos = (float*)(ws + OFF_TCOS);
  float* tsin = (float*)(ws + OFF_TSIN);
  u16* Hb   = (u16*)(ws + OFF_H);
  u16* QKV  = (u16*)(ws + OFF_QKV);
  u16* QR   = (u16*)(ws + OFF_QR);
  u16* KR   = (u16*)(ws + OFF_KR);
  u16* VT   = (u16*)(ws + OFF_VT);
  u16* AO   = (u16*)(ws + OFF_AO);
  u8*  H8   = (u8*)(ws + OFF_H);        // ln3 fp8 output (H bf16 dead by then)
  u8*  U8   = (u8*)(ws + OFF_U);        // fc1 out fp8 (QKV region dead by then)
  u8*  W8FC1 = (u8*)(ws + OFF_QR);      // fp8 fc1w (QR dead after cross-attn)
  u8*  W8FC2 = (u8*)(ws + OFF_KR);      // fp8 fc2w (KR dead after cross-attn)

  // RoPE tables
  build_tab<<<dim3(128), dim3(256), 0, stream>>>(tcos, tsin);

  // fused weight/context conversion (fp32 -> bf16) into contiguous ws region
  Cvt11 ca;
  ca.s[0] = sa_qw; ca.s[1] = sa_kw; ca.s[2] = sa_vw; ca.s[3] = sa_pw;
  ca.s[4] = ca_qw; ca.s[5] = ca_kw; ca.s[6] = ca_vw; ca.s[7] = ca_pw;
  ca.s[8] = fc1w;  ca.s[9] = fc2w;  ca.s[10] = ctx;
  cvt_all<<<dim3(18432), dim3(256), 0, stream>>>(ca, (u16*)(ws + OFF_WSAQKV));
  Cp5 cp;
  cp.s[0] = sa_qb; cp.s[1] = sa_kb; cp.s[2] = sa_vb; cp.s[3] = ca_kb; cp.s[4] = ca_vb;
  copy5<<<dim3(20), dim3(256), 0, stream>>>(cp, (float*)(ws + OFF_BSAQKV));

  // ---- self-attention ----
  ln_bf16<<<dim3(NTOK), dim3(256), 0, stream>>>(x, n1w, n1b, Hb);
  gemm2<EPI_BF16><<<dim3(3072 / 128, NTOK / 128), dim3(512), 0, stream>>>(
      Hb, (u16*)(ws + OFF_WSAQKV), (float*)(ws + OFF_BSAQKV), QKV, nullptr, nullptr, nullptr,
      NTOK, 3072, 1024, 1);
  {
    Rope3 r;
    r.j[0] = {QKV, QR, 3072, 0,    LQ, NTOK, 0, QSCALE};
    r.j[1] = {QKV, KR, 3072, 1024, LQ, NTOK, 0, 1.0f};
    r.j[2] = {QKV, VT, 3072, 2048, LQ, NTOK, 1, 1.0f};
    rope3<<<dim3(NTOK, 3), dim3(128), 0, stream>>>(r, tcos, tsin);
  }
  flash_attn2<1><<<dim3(512), dim3(256), 0, stream>>>(QR, KR, VT, AO, LQ, LQ);
  gemm2<EPI_RESID><<<dim3(1024 / 128, NTOK / 128), dim3(512), 0, stream>>>(
      AO, (u16*)(ws + OFF_WSAP), sa_pb, nullptr, out, x, g_msa, NTOK, 1024, 1024, 1);

  // ---- cross-attention ----
  ln_bf16<<<dim3(NTOK), dim3(256), 0, stream>>>(out, n2w, n2b, Hb);
  gemm2<EPI_BF16><<<dim3(1024 / 128, NTOK / 128), dim3(512), 0, stream>>>(
      Hb, (u16*)(ws + OFF_WCAQ), ca_qb, (u16*)(ws + OFF_CAQ), nullptr, nullptr, nullptr,
      NTOK, 1024, 1024, 1);
  gemm2<EPI_BF16><<<dim3(2048 / 128, NCTX / 128), dim3(512), 0, stream>>>(
      (u16*)(ws + OFF_CTXB), (u16*)(ws + OFF_WCAKV), (float*)(ws + OFF_BCAKV),
      (u16*)(ws + OFF_CAKV), nullptr, nullptr, nullptr, NCTX, 2048, 1024, 1);
  {
    Rope3 r;
    r.j[0] = {(u16*)(ws + OFF_CAQ),  QR, 1024, 0,    LQ, NTOK, 0, QSCALE};
    r.j[1] = {(u16*)(ws + OFF_CAKV), KR, 2048, 0,    LC, NCTX, 0, 1.0f};
    r.j[2] = {(u16*)(ws + OFF_CAKV), VT, 2048, 1024, LC, NCTX, 1, 1.0f};
    rope3<<<dim3(NTOK, 3), dim3(128), 0, stream>>>(r, tcos, tsin);
  }
  flash_attn2<0><<<dim3(512), dim3(256), 0, stream>>>(QR, KR, VT, AO, LQ, LC);
  gemm2<EPI_RESID><<<dim3(1024 / 128, NTOK / 128), dim3(512), 0, stream>>>(
      AO, (u16*)(ws + OFF_WCAP), ca_pb, nullptr, out, out, g_ca, NTOK, 1024, 1024, 1);

  // ---- MLP (fp8 MX path) ----
  // QR/KR are dead now; convert fc1w/fc2w -> fp8 x256 into their space.
  cvt_fp8<<<dim3(8192), dim3(256), 0, stream>>>(fc1w, fc2w, W8FC1, W8FC2);
  ln_fp8<<<dim3(NTOK), dim3(256), 0, stream>>>(out, n3w, n3b, H8);
  gemm8<E8_GELU><<<dim3(4096 / 128, NTOK / 128), dim3(256), 0, stream>>>(
      H8, W8FC1, fc1b, U8, nullptr, nullptr, NTOK, 4096, 1024, 1);
  // fc2: split-K x2, atomic accumulation; bias+gate pre-applied
  init_bias_gate<<<dim3(4096), dim3(256), 0, stream>>>(out, fc2b, g_mlp);
  gemm8<E8_ATOMIC><<<dim3(1024 / 128, NTOK / 128, 2), dim3(256), 0, stream>>>(
      U8, W8FC2, nullptr, nullptr, out, g_mlp, NTOK, 1024, 4096, 2);
}

// Round 11
// 389.518 us; speedup vs baseline: 1.1515x; 1.0435x over previous
//
#include <hip/hip_runtime.h>
#include <math.h>

#if !__has_builtin(__builtin_amdgcn_cvt_pk_fp8_f32)
#include <hip/hip_fp8.h>
#endif

typedef __attribute__((ext_vector_type(8))) short short8;
typedef __attribute__((ext_vector_type(4))) float f32x4;
typedef __attribute__((ext_vector_type(16))) float f32x16;
typedef unsigned char u8;
typedef unsigned short u16;
typedef unsigned int u32;
typedef __attribute__((ext_vector_type(2))) u32 u32x2;
typedef __attribute__((ext_vector_type(4))) u32 u32x4;
typedef __attribute__((ext_vector_type(8))) int i32x8;
typedef unsigned long long u64;

static constexpr int E = 1024, H = 16, LQ = 1024, LC = 512, Bn = 4, FF = 4096;
static constexpr int NTOK = Bn * LQ;   // 4096
static constexpr int NCTX = Bn * LC;   // 2048

// Q pre-scale: 1/sqrt(64) * log2(e)  (softmax runs in exp2 domain)
#define QSCALE 0.1803368801111244f
#define DEFER_THR 11.5f

// ---------------- workspace layout (bytes) ----------------
static constexpr size_t OFF_TCOS   = 0;                                    // 1024*32 f32
static constexpr size_t OFF_TSIN   = OFF_TCOS + (size_t)LQ*32*4;
static constexpr size_t OFF_BSAQKV = OFF_TSIN + (size_t)LQ*32*4;           // 3072 f32 (+ca_k/v bias after)
static constexpr size_t OFF_BCAKV  = OFF_BSAQKV + 16384;                   // 2048 f32
// contiguous bf16 weight region (order matters for cvt_all):
static constexpr size_t OFF_WSAQKV = OFF_BCAKV + 16384;                    // [3072][1024] bf16
static constexpr size_t OFF_WSAP   = OFF_WSAQKV + (size_t)3072*1024*2;     // [1024][1024]
static constexpr size_t OFF_WCAQ   = OFF_WSAP   + (size_t)1024*1024*2;
static constexpr size_t OFF_WCAKV  = OFF_WCAQ   + (size_t)1024*1024*2;     // [2048][1024]
static constexpr size_t OFF_WCAP   = OFF_WCAKV  + (size_t)2048*1024*2;
static constexpr size_t OFF_WFC1   = OFF_WCAP   + (size_t)1024*1024*2;     // [4096][1024] (bf16, unused now)
static constexpr size_t OFF_WFC2   = OFF_WFC1   + (size_t)4096*1024*2;     // [1024][4096] (bf16, unused now)
static constexpr size_t OFF_CTXB   = OFF_WFC2   + (size_t)1024*4096*2;     // [2048][1024] bf16
static constexpr size_t OFF_H      = OFF_CTXB   + (size_t)2048*1024*2;     // [4096][1024] bf16 (LN out) / fp8 for ln3
static constexpr size_t OFF_QKV    = OFF_H      + (size_t)4096*1024*2;     // [4096][3072] bf16
static constexpr size_t OFF_CAQ    = OFF_QKV;                              // [4096][1024]
static constexpr size_t OFF_CAKV   = OFF_QKV + (size_t)4096*1024*2;        // [2048][2048]
static constexpr size_t OFF_QR     = OFF_QKV + (size_t)4096*3072*2;        // [B,H,LQ,64] / fp8 fc1w after CA
static constexpr size_t OFF_KR     = OFF_QR  + (size_t)4096*1024*2;        // [B,H,Lk,64] / fp8 fc2w after CA
static constexpr size_t OFF_VT     = OFF_KR  + (size_t)4096*1024*2;        // [B,H,64,Lk]
static constexpr size_t OFF_AO     = OFF_VT  + (size_t)4096*1024*2;        // [4096][1024] bf16
static constexpr size_t OFF_U      = OFF_QKV;                              // fc1 out [4096][4096] fp8 reuses QKV
static constexpr size_t WS_NEED    = OFF_AO + (size_t)4096*1024*2;         // ~105 MB

// ---------------- helpers ----------------
static __device__ __forceinline__ float bf2f(u16 u) {
  union { u32 i; float f; } un; un.i = ((u32)u) << 16; return un.f;
}
static __device__ __forceinline__ u16 f2bf(float f) {  // RNE
  union { float f; u32 u; } un; un.f = f;
  u32 u = un.u;
  return (u16)((u + 0x7FFFu + ((u >> 16) & 1u)) >> 16);
}
static __device__ __forceinline__ u64 pack4(u16 a, u16 b, u16 c, u16 d) {
  return (u64)a | ((u64)b << 16) | ((u64)c << 32) | ((u64)d << 48);
}
static __device__ __forceinline__ f32x4 mfma16(short8 a, short8 b, f32x4 c) {
  return __builtin_amdgcn_mfma_f32_16x16x32_bf16(a, b, c, 0, 0, 0);
}
static __device__ __forceinline__ f32x16 mfma32(short8 a, short8 b, f32x16 c) {
  return __builtin_amdgcn_mfma_f32_32x32x16_bf16(a, b, c, 0, 0, 0);
}
static __device__ __forceinline__ void gload_lds16(void* lds, const void* g) {
  __builtin_amdgcn_global_load_lds(
      (const __attribute__((address_space(1))) void*)g,
      (__attribute__((address_space(3))) void*)lds, 16, 0, 0);
}
// gelu(x) = 0.5x(1+tanh(z)) = x*e/(e+1), e=exp(2*0.79788456(x+0.044715x^3)).
static __device__ __forceinline__ float gelu_tanh(float x) {
  float z2 = 1.5957691216057308f * (x + 0.044715f * x * x * x);
  float e = __expf(z2);
  float r = __builtin_amdgcn_rcpf(e + 1.0f);
  return x - x * r;   // x*(1 - 1/(e+1)) = x*e/(e+1)
}
static __device__ __forceinline__ u32 cvtpk_bf16(float lo, float hi) {
  u32 r;
  asm("v_cvt_pk_bf16_f32 %0, %1, %2" : "=v"(r) : "v"(lo), "v"(hi));
  return r;
}
// fp32 -> OCP e4m3 (saturating)
static __device__ __forceinline__ u32 pack_fp8x4(float a, float b, float c, float d) {
#if __has_builtin(__builtin_amdgcn_cvt_pk_fp8_f32)
  u32 r = (u32)__builtin_amdgcn_cvt_pk_fp8_f32(a, b, 0, false);
  r = (u32)__builtin_amdgcn_cvt_pk_fp8_f32(c, d, (int)r, true);
  return r;
#else
  __hip_fp8_e4m3 qa(a), qb(b), qc(c), qd(d);
  return (u32)qa.__x | ((u32)qb.__x << 8) | ((u32)qc.__x << 16) | ((u32)qd.__x << 24);
#endif
}
static __device__ __forceinline__ u8 fp8b(float f) {
#if __has_builtin(__builtin_amdgcn_cvt_pk_fp8_f32)
  return (u8)((u32)__builtin_amdgcn_cvt_pk_fp8_f32(f, f, 0, false) & 0xFFu);
#else
  __hip_fp8_e4m3 t(f); return t.__x;
#endif
}

// ---------------- small kernels ----------------
__global__ __launch_bounds__(256) void build_tab(float* __restrict__ ct, float* __restrict__ st) {
  int idx = blockIdx.x * 256 + threadIdx.x;           // 1024*32 entries
  int pos = idx >> 5, i = idx & 31;
  float inv = powf(10000.f, -(float)i * (1.f / 32.f));
  float a = (float)pos * inv;
  ct[idx] = cosf(a);
  st[idx] = sinf(a);
}

// fused fp32->bf16 conversion of weights + context (segments 8,9 = fc1w/fc2w
// now go through cvt_fp8 instead -> early-exit).
struct Cvt11 { const float* s[11]; };
__global__ __launch_bounds__(256) void cvt_all(Cvt11 a, u16* __restrict__ dst) {
  u32 gid = blockIdx.x * 256 + threadIdx.x;   // 0 .. 4718591
  u32 s, off;
  if (gid < 2097152u)      { s = gid >> 18;                        off = gid & 262143u; }
  else if (gid < 4194304u) { return; }        // fc1w/fc2w handled in fp8
  else                     { s = 10;                               off = gid - 4194304u; }
  float4 v = *(const float4*)(a.s[s] + (size_t)off * 4);
  *(u64*)(dst + (size_t)gid * 4) = pack4(f2bf(v.x), f2bf(v.y), f2bf(v.z), f2bf(v.w));
}

// fc1w/fc2w -> fp8 e4m3 scaled x256
__global__ __launch_bounds__(256) void cvt_fp8(const float* __restrict__ s0, const float* __restrict__ s1,
                                               u8* __restrict__ d0, u8* __restrict__ d1) {
  u32 gid = blockIdx.x * 256 + threadIdx.x;   // 0..2097151, 4 elems each
  const float* s; u8* d; u32 off;
  if (gid < 1048576u) { s = s0; d = d0; off = gid; }
  else                { s = s1; d = d1; off = gid - 1048576u; }
  float4 v = *(const float4*)(s + (size_t)off * 4);
  *(u32*)(d + (size_t)off * 4) =
      pack_fp8x4(v.x * 256.f, v.y * 256.f, v.z * 256.f, v.w * 256.f);
}

// fused bias copies: sa_q,sa_k,sa_v -> BSAQKV(+0,+1024,+2048); ca_k,ca_v -> BCAKV(+0,+1024)
struct Cp5 { const float* s[5]; };
__global__ __launch_bounds__(256) void copy5(Cp5 a, float* __restrict__ dst) {
  int gid = blockIdx.x * 256 + threadIdx.x;   // 0..5119
  int s = gid >> 10, off = gid & 1023;
  int doff = (s < 3) ? s * 1024 : 4096 + (s - 3) * 1024;
  dst[doff + off] = a.s[s][off];
}

// out[row][c] += gate[c]*bias[c]  (init pass for split-K atomic GEMM)
__global__ __launch_bounds__(256) void init_bias_gate(float* __restrict__ out, const float* __restrict__ bias,
                                                      const float* __restrict__ gate) {
  int i = (blockIdx.x * 256 + threadIdx.x) * 4;
  int c = i & 1023;
  float4 o = *(float4*)(out + i);
  o.x += gate[c] * bias[c];
  o.y += gate[c + 1] * bias[c + 1];
  o.z += gate[c + 2] * bias[c + 2];
  o.w += gate[c + 3] * bias[c + 3];
  *(float4*)(out + i) = o;
}

// LN over last dim 1024, one row per block, bf16 out.
__global__ __launch_bounds__(256) void ln_bf16(const float* __restrict__ x, const float* __restrict__ w,
                                               const float* __restrict__ b, u16* __restrict__ out) {
  __shared__ float red[4];
  int row = blockIdx.x, tid = threadIdx.x;
  const float* xr = x + (size_t)row * 1024;
  float4 v = ((const float4*)xr)[tid];
  float s = v.x + v.y + v.z + v.w;
#pragma unroll
  for (int off = 32; off; off >>= 1) s += __shfl_xor(s, off);
  if ((tid & 63) == 0) red[tid >> 6] = s;
  __syncthreads();
  float mean = (red[0] + red[1] + red[2] + red[3]) * (1.f / 1024.f);
  float dx = v.x - mean, dy = v.y - mean, dz = v.z - mean, dw = v.w - mean;
  float sq = dx * dx + dy * dy + dz * dz + dw * dw;
#pragma unroll
  for (int off = 32; off; off >>= 1) sq += __shfl_xor(sq, off);
  __syncthreads();
  if ((tid & 63) == 0) red[tid >> 6] = sq;
  __syncthreads();
  float var = (red[0] + red[1] + red[2] + red[3]) * (1.f / 1024.f);
  float rstd = rsqrtf(var + 1e-6f);
  float4 wv = ((const float4*)w)[tid];
  float4 bv = ((const float4*)b)[tid];
  u64 o = pack4(f2bf(dx * rstd * wv.x + bv.x), f2bf(dy * rstd * wv.y + bv.y),
                f2bf(dz * rstd * wv.z + bv.z), f2bf(dw * rstd * wv.w + bv.w));
  *(u64*)(out + (size_t)row * 1024 + tid * 4) = o;
}

// LN -> fp8 e4m3 scaled x16 (for the fp8 MLP path)
__global__ __launch_bounds__(256) void ln_fp8(const float* __restrict__ x, const float* __restrict__ w,
                                              const float* __restrict__ b, u8* __restrict__ out) {
  __shared__ float red[4];
  int row = blockIdx.x, tid = threadIdx.x;
  const float* xr = x + (size_t)row * 1024;
  float4 v = ((const float4*)xr)[tid];
  float s = v.x + v.y + v.z + v.w;
#pragma unroll
  for (int off = 32; off; off >>= 1) s += __shfl_xor(s, off);
  if ((tid & 63) == 0) red[tid >> 6] = s;
  __syncthreads();
  float mean = (red[0] + red[1] + red[2] + red[3]) * (1.f / 1024.f);
  float dx = v.x - mean, dy = v.y - mean, dz = v.z - mean, dw = v.w - mean;
  float sq = dx * dx + dy * dy + dz * dz + dw * dw;
#pragma unroll
  for (int off = 32; off; off >>= 1) sq += __shfl_xor(sq, off);
  __syncthreads();
  if ((tid & 63) == 0) red[tid >> 6] = sq;
  __syncthreads();
  float var = (red[0] + red[1] + red[2] + red[3]) * (1.f / 1024.f);
  float rstd = rsqrtf(var + 1e-6f);
  float4 wv = ((const float4*)w)[tid];
  float4 bv = ((const float4*)b)[tid];
  u32 pk = pack_fp8x4((dx * rstd * wv.x + bv.x) * 16.f, (dy * rstd * wv.y + bv.y) * 16.f,
                      (dz * rstd * wv.z + bv.z) * 16.f, (dw * rstd * wv.w + bv.w) * 16.f);
  *(u32*)(out + (size_t)row * 1024 + tid * 4) = pk;
}

// Fused RoPE/scatter: 3 jobs in one dispatch (blockIdx.y selects job).
struct RopeJob { const u16* src; u16* dst; int ld, col0, Lper, T, mode; float scale; };
struct Rope3 { RopeJob j[3]; };
__global__ __launch_bounds__(128) void rope3(Rope3 a, const float* __restrict__ cosT,
                                             const float* __restrict__ sinT) {
  RopeJob jb = a.j[blockIdx.y];
  int t = blockIdx.x;
  if (t >= jb.T) return;
  int b = t / jb.Lper, l = t - b * jb.Lper;
  int tid = threadIdx.x;
  int e0 = tid * 8;
  int h = e0 >> 6, d0 = e0 & 63;
  short8 vv = *(const short8*)(jb.src + (size_t)t * jb.ld + jb.col0 + e0);
  if (jb.mode == 0) {
    short8 ov;
#pragma unroll
    for (int j = 0; j < 4; ++j) {
      float x1 = bf2f((u16)vv[2 * j]);
      float x2 = bf2f((u16)vv[2 * j + 1]);
      int i = (d0 >> 1) + j;
      float c = cosT[l * 32 + i], s = sinT[l * 32 + i];
      ov[2 * j]     = (short)f2bf((x1 * c - x2 * s) * jb.scale);
      ov[2 * j + 1] = (short)f2bf((x1 * s + x2 * c) * jb.scale);
    }
    *(short8*)(jb.dst + (((size_t)b * H + h) * jb.Lper + l) * 64 + d0) = ov;
  } else {
#pragma unroll
    for (int m = 0; m < 8; ++m)
      jb.dst[(((size_t)b * H + h) * 64 + d0 + m) * jb.Lper + l] = (u16)vv[m];
  }
}

// ---------------- bf16 GEMM (proven R8 config): C = A @ W^T + bias ----------------
enum { EPI_BF16 = 0, EPI_GELU = 1, EPI_RESID = 2, EPI_ATOMIC = 3 };

template <int EPI>
__global__ __launch_bounds__(512, 4) void gemm2(const u16* __restrict__ A, const u16* __restrict__ W,
                                                const float* __restrict__ bias, u16* outb, float* outf,
                                                const float* res, const float* __restrict__ gate,
                                                int M, int N, int K, int kchunks) {
  __shared__ u16 As[2][128 * 64];
  __shared__ u16 Bs[2][128 * 64];

  int nwg = gridDim.x * gridDim.y;
  int bid = blockIdx.y * gridDim.x + blockIdx.x;
  int cpx = nwg >> 3;
  int swz = (bid & 7) * cpx + (bid >> 3);
  int bx = swz % gridDim.x;
  int by = swz / gridDim.x;
  int row0 = by * 128, col0 = bx * 128;

  const int Kc = K / kchunks;
  const int kbase = blockIdx.z * Kc;

  int tid = threadIdx.x;
  int lane = tid & 63, wid = tid >> 6;
  int wr = wid >> 2, wc = wid & 3;  // 2x4 waves, each owns 64x32
  int lr = lane & 15, lg = lane >> 4;

  size_t a_off0, a_off1, b_off0, b_off1;
  int l_off0 = tid * 8, l_off1 = (512 + tid) * 8;
  {
    int q = tid, r = q >> 3, p = q & 7, sp = p ^ (r & 7);
    a_off0 = (size_t)(row0 + r) * K + sp * 8;
    b_off0 = (size_t)(col0 + r) * K + sp * 8;
    q = 512 + tid; r = q >> 3; p = q & 7; sp = p ^ (r & 7);
    a_off1 = (size_t)(row0 + r) * K + sp * 8;
    b_off1 = (size_t)(col0 + r) * K + sp * 8;
  }

  f32x4 acc[4][2] = {};

  const int nkt = Kc >> 6;
  {
    gload_lds16(&As[0][l_off0], A + a_off0 + kbase);
    gload_lds16(&Bs[0][l_off0], W + b_off0 + kbase);
    gload_lds16(&As[0][l_off1], A + a_off1 + kbase);
    gload_lds16(&Bs[0][l_off1], W + b_off1 + kbase);
  }
  __syncthreads();

  for (int kt = 0; kt < nkt; ++kt) {
    int cur = kt & 1;
    if (kt + 1 < nkt) {
      int k0 = kbase + ((kt + 1) << 6);
      gload_lds16(&As[cur ^ 1][l_off0], A + a_off0 + k0);
      gload_lds16(&Bs[cur ^ 1][l_off0], W + b_off0 + k0);
      gload_lds16(&As[cur ^ 1][l_off1], A + a_off1 + k0);
      gload_lds16(&Bs[cur ^ 1][l_off1], W + b_off1 + k0);
    }
#pragma unroll
    for (int kk = 0; kk < 2; ++kk) {
      short8 af[4], bfr[2];
#pragma unroll
      for (int m = 0; m < 4; ++m) {
        int r = wr * 64 + m * 16 + lr;
        int sc = (kk * 4 + lg) ^ (r & 7);
        af[m] = *(const short8*)(&As[cur][r * 64 + sc * 8]);
      }
#pragma unroll
      for (int n = 0; n < 2; ++n) {
        int r = wc * 32 + n * 16 + lr;
        int sc = (kk * 4 + lg) ^ (r & 7);
        bfr[n] = *(const short8*)(&Bs[cur][r * 64 + sc * 8]);
      }
#pragma unroll
      for (int m = 0; m < 4; ++m)
#pragma unroll
        for (int n = 0; n < 2; ++n)
          acc[m][n] = mfma16(af[m], bfr[n], acc[m][n]);
    }
    __syncthreads();
  }

  if (EPI == EPI_BF16 || EPI == EPI_GELU) {
    u16* Ct = &As[0][0];
#pragma unroll
    for (int n = 0; n < 2; ++n) {
      int c = wc * 32 + n * 16 + lr;
      float bv = bias[col0 + c];
#pragma unroll
      for (int m = 0; m < 4; ++m) {
#pragma unroll
        for (int i = 0; i < 4; ++i) {
          int r = wr * 64 + m * 16 + lg * 4 + i;
          float v = acc[m][n][i] + bv;
          Ct[r * 128 + c] = f2bf(EPI == EPI_GELU ? gelu_tanh(v) : v);
        }
      }
    }
    __syncthreads();
#pragma unroll
    for (int j = 0; j < 4; ++j) {
      u32 q = (u32)tid + j * 512;
      u32 r = q >> 4, ck = q & 15;
      short8 v = *(const short8*)(Ct + r * 128 + ck * 8);
      *(short8*)(outb + (size_t)(row0 + r) * N + col0 + ck * 8) = v;
    }
  } else {
#pragma unroll
    for (int n = 0; n < 2; ++n) {
      int cg = col0 + wc * 32 + n * 16 + lr;
      float bv = (EPI == EPI_ATOMIC) ? 0.f : bias[cg];
#pragma unroll
      for (int m = 0; m < 4; ++m) {
#pragma unroll
        for (int i = 0; i < 4; ++i) {
          int rg = row0 + wr * 64 + m * 16 + lg * 4 + i;
          float v = acc[m][n][i] + bv;
          if (EPI == EPI_RESID) {
            float r = res[(size_t)rg * N + cg];
            outf[(size_t)rg * N + cg] = r + gate[cg] * v;
          } else {
            atomicAdd(&outf[(size_t)rg * N + cg], gate[cg] * v);
          }
        }
      }
    }
  }
}

// ---------------- fp8 MX GEMM: C = (A/16) @ (W/256)^T -> acc/4096 ----------------
enum { E8_GELU = 0, E8_ATOMIC = 1 };

template <int EPI>
__global__ __launch_bounds__(256, 2) void gemm8(const u8* __restrict__ A, const u8* __restrict__ W,
                                                const float* __restrict__ bias, u8* outb, float* outf,
                                                const float* __restrict__ gate,
                                                int M, int N, int K, int kchunks) {
  __shared__ u8 As[2][128 * 128];
  __shared__ u8 Bs[2][128 * 128];

  int nwg = gridDim.x * gridDim.y;
  int bid = blockIdx.y * gridDim.x + blockIdx.x;
  int cpx = nwg >> 3;
  int swz = (bid & 7) * cpx + (bid >> 3);
  int bx = swz % gridDim.x, by = swz / gridDim.x;
  int row0 = by * 128, col0 = bx * 128;

  const int Kc = K / kchunks;
  const int kbase = blockIdx.z * Kc;

  int tid = threadIdx.x;
  int lane = tid & 63, wid = tid >> 6;
  int wr = wid >> 1, wc = wid & 1;      // 2x2 waves, each owns 64x64
  int l31 = lane & 31, hi = lane >> 5;

  u32 aoff[4], boff[4];
  int ldso[4];
#pragma unroll
  for (int j = 0; j < 4; ++j) {
    int q = tid + j * 256;
    int r = q >> 3, p = q & 7, sp = p ^ (r & 7);
    aoff[j] = (u32)(row0 + r) * (u32)K + sp * 16;
    boff[j] = (u32)(col0 + r) * (u32)K + sp * 16;
    ldso[j] = q * 16;
  }

  f32x16 acc[2][2] = {};
  const int nkt = Kc >> 7;              // BK = 128

  auto rdfrag = [&](const u8* base, int wbase, int ks, i32x8* f) {
#pragma unroll
    for (int blk = 0; blk < 2; ++blk) {
      int r = wbase + blk * 32 + l31;
      const u8* rp = base + r * 128;
      int ck = ks * 4 + hi * 2;
      u32x4 lo = *(const u32x4*)(rp + ((ck) ^ (r & 7)) * 16);
      u32x4 hh = *(const u32x4*)(rp + ((ck + 1) ^ (r & 7)) * 16);
      i32x8 v;
      v[0] = (int)lo[0]; v[1] = (int)lo[1]; v[2] = (int)lo[2]; v[3] = (int)lo[3];
      v[4] = (int)hh[0]; v[5] = (int)hh[1]; v[6] = (int)hh[2]; v[7] = (int)hh[3];
      f[blk] = v;
    }
  };

  // prologue
#pragma unroll
  for (int j = 0; j < 4; ++j) {
    gload_lds16(&As[0][ldso[j]], A + aoff[j] + kbase);
    gload_lds16(&Bs[0][ldso[j]], W + boff[j] + kbase);
  }
  __syncthreads();

  for (int kt = 0; kt < nkt; ++kt) {
    int cur = kt & 1;
    if (kt + 1 < nkt) {
      int k0 = kbase + ((kt + 1) << 7);
#pragma unroll
      for (int j = 0; j < 4; ++j) {
        gload_lds16(&As[cur ^ 1][ldso[j]], A + aoff[j] + k0);
        gload_lds16(&Bs[cur ^ 1][ldso[j]], W + boff[j] + k0);
      }
    }
#pragma unroll
    for (int ks = 0; ks < 2; ++ks) {
      i32x8 a[2], b[2];
      rdfrag(&As[cur][0], wr * 64, ks, a);
      rdfrag(&Bs[cur][0], wc * 64, ks, b);
      __builtin_amdgcn_s_setprio(1);
#pragma unroll
      for (int mi = 0; mi < 2; ++mi)
#pragma unroll
        for (int ni = 0; ni < 2; ++ni)
          acc[mi][ni] = __builtin_amdgcn_mfma_scale_f32_32x32x64_f8f6f4(
              a[mi], b[ni], acc[mi][ni], 0, 0, 0, 0x7F7F7F7F, 0, 0x7F7F7F7F);
      __builtin_amdgcn_s_setprio(0);
    }
    __syncthreads();
  }

  constexpr float SCL = 1.f / 4096.f;   // undo x16 (act) * x256 (weights)
  if (EPI == E8_GELU) {
    u8* Ct = &As[0][0];                 // [128][128] u8 = 16 KiB
#pragma unroll
    for (int ni = 0; ni < 2; ++ni) {
      int cl = wc * 64 + ni * 32 + l31;
      float bv = bias[col0 + cl];
#pragma unroll
      for (int mi = 0; mi < 2; ++mi) {
#pragma unroll
        for (int g = 0; g < 16; ++g) {
          int rl = wr * 64 + mi * 32 + (g & 3) + 8 * (g >> 2) + 4 * hi;
          float v = acc[mi][ni][g] * SCL + bv;
          Ct[rl * 128 + cl] = fp8b(gelu_tanh(v) * 16.f);
        }
      }
    }
    __syncthreads();
#pragma unroll
    for (int j = 0; j < 4; ++j) {
      int q = tid + j * 256;
      int r = q >> 3, ck = q & 7;
      *(u32x4*)(outb + (size_t)(row0 + r) * N + col0 + ck * 16) =
          *(const u32x4*)(Ct + r * 128 + ck * 16);
    }
  } else {
#pragma unroll
    for (int ni = 0; ni < 2; ++ni) {
      int cg = col0 + wc * 64 + ni * 32 + l31;
      float gv = gate[cg];
#pragma unroll
      for (int mi = 0; mi < 2; ++mi) {
#pragma unroll
        for (int g = 0; g < 16; ++g) {
          int rg = row0 + wr * 64 + mi * 32 + (g & 3) + 8 * (g >> 2) + 4 * hi;
          atomicAdd(&outf[(size_t)rg * N + cg], gv * (acc[mi][ni][g] * SCL));
        }
      }
    }
  }
}

// ---------------- flash attention, swapped-QK^T, register-pipelined K/V ----------------
// Per tile: issue V loads first (retire under QK^T+softmax); QK^T consumes kf
// regs; immediately re-load kf with NEXT tile's K (regs dead after QK^T, ~600cy
// of VALU+PV before next use). Breaks the load->MFMA latency serialization.
template <int MASKED, int PRE>
static __device__ __forceinline__ void attn_tile3(short8* kf, const u16* KtNext,
                                                  const u16* Vp0, const u16* Vp1,
                                                  const short8* qf, int kb, int q0, int l31, int hi,
                                                  float& m, float& lsum, f32x16& o0, f32x16& o1) {
  // 1) V loads for THIS tile — independent, issue first
  short8 vf0[4], vf1[4];
#pragma unroll
  for (int ks = 0; ks < 4; ++ks) {
    vf0[ks] = *(const short8*)(Vp0 + ks * 16 + hi * 8);
    vf1[ks] = *(const short8*)(Vp1 + ks * 16 + hi * 8);
  }
  // 2) QK^T from pre-loaded K registers
  f32x16 s0 = {}, s1 = {};
  __builtin_amdgcn_s_setprio(1);
#pragma unroll
  for (int s = 0; s < 4; ++s) {
    s0 = mfma32(kf[s], qf[s], s0);       // S^T[k][q]
    s1 = mfma32(kf[4 + s], qf[s], s1);
  }
  __builtin_amdgcn_s_setprio(0);
  // 3) prefetch next tile's K into kf (dead after QK^T)
  if (PRE) {
    const u16* kp0 = KtNext + (size_t)l31 * 64 + hi * 8;
    const u16* kp1 = KtNext + (size_t)(32 + l31) * 64 + hi * 8;
#pragma unroll
    for (int s = 0; s < 4; ++s) {
      kf[s] = *(const short8*)(kp0 + s * 16);
      kf[4 + s] = *(const short8*)(kp1 + s * 16);
    }
  }
  if (MASKED) {
    int qg = q0 + l31;
#pragma unroll
    for (int r = 0; r < 16; ++r) {
      int kk = kb + (r & 3) + 8 * (r >> 2) + 4 * hi;
      if (kk > qg) s0[r] = -INFINITY;
      if (kk + 32 > qg) s1[r] = -INFINITY;
    }
  }
  float pm = -INFINITY;
#pragma unroll
  for (int r = 0; r < 16; ++r) pm = fmaxf(pm, fmaxf(s0[r], s1[r]));
  pm = fmaxf(pm, __shfl_xor(pm, 32));
  if (!__all(pm <= m + DEFER_THR)) {
    float mn = fmaxf(m, pm);
    float al = exp2f(m - mn);
    m = mn;
    lsum *= al;
#pragma unroll
    for (int r = 0; r < 16; ++r) {
      float alr = __shfl(al, (r & 3) + 8 * (r >> 2) + 4 * hi);
      o0[r] *= alr;
      o1[r] *= alr;
    }
  }
  float ts = 0.f;
#pragma unroll
  for (int r = 0; r < 16; ++r) {
    float p0 = exp2f(s0[r] - m);
    float p1 = exp2f(s1[r] - m);
    s0[r] = p0; s1[r] = p1;
    ts += p0 + p1;
  }
  ts += __shfl_xor(ts, 32);
  lsum += ts;
  auto pack8 = [&](float a0, float a1, float a2, float a3,
                   float a4, float a5, float a6, float a7) -> short8 {
    u32 c0 = cvtpk_bf16(a0, a1), c1 = cvtpk_bf16(a2, a3);
    u32 c2 = cvtpk_bf16(a4, a5), c3 = cvtpk_bf16(a6, a7);
    u32x2 r02 = __builtin_amdgcn_permlane32_swap(c0, c2, false, false);
    u32x2 r13 = __builtin_amdgcn_permlane32_swap(c1, c3, false, false);
    u32x4 w;
    w[0] = r02[0]; w[1] = r13[0]; w[2] = r02[1]; w[3] = r13[1];
    return __builtin_bit_cast(short8, w);
  };
  short8 pa0 = pack8(s0[0], s0[1], s0[2], s0[3], s0[4], s0[5], s0[6], s0[7]);
  short8 pa1 = pack8(s0[8], s0[9], s0[10], s0[11], s0[12], s0[13], s0[14], s0[15]);
  short8 pa2 = pack8(s1[0], s1[1], s1[2], s1[3], s1[4], s1[5], s1[6], s1[7]);
  short8 pa3 = pack8(s1[8], s1[9], s1[10], s1[11], s1[12], s1[13], s1[14], s1[15]);
  short8 pa[4] = {pa0, pa1, pa2, pa3};
  __builtin_amdgcn_s_setprio(1);
#pragma unroll
  for (int ks = 0; ks < 4; ++ks) {
    o0 = mfma32(pa[ks], vf0[ks], o0);
    o1 = mfma32(pa[ks], vf1[ks], o1);
  }
  __builtin_amdgcn_s_setprio(0);
}

template <int CAUSAL>
__global__ __launch_bounds__(256) void flash_attn2(const u16* __restrict__ Q, const u16* __restrict__ K,
                                                   const u16* __restrict__ Vt, u16* __restrict__ O,
                                                   int Lq, int Lk) {
  const int wid = threadIdx.x >> 6, lane = threadIdx.x & 63;
  const int l31 = lane & 31, hi = lane >> 5;
  int wg = blockIdx.x * 4 + wid;     // 4 independent waves per block, no barriers
  int bh = wg & 63;
  int qc = wg >> 6;
  if (CAUSAL) qc = (Lq >> 5) - 1 - qc;   // heavy q-chunks dispatch first
  int q0 = qc << 5;

  const u16* Qb = Q + ((size_t)bh * Lq + q0) * 64;
  const u16* Kb = K + (size_t)bh * Lk * 64;
  const u16* Vb = Vt + (size_t)bh * 64 * Lk;

  short8 qf[4];
#pragma unroll
  for (int s = 0; s < 4; ++s) qf[s] = *(const short8*)(Qb + (size_t)l31 * 64 + s * 16 + hi * 8);

  f32x16 o0 = {}, o1 = {};
  float m = -INFINITY, lsum = 0.f;

  const u16* Kt = Kb;
  const u16* Vp0 = Vb + (size_t)l31 * Lk;
  const u16* Vp1 = Vb + (size_t)(32 + l31) * Lk;

  // preload K tile 0 into registers
  short8 kf[8];
  {
    const u16* kp0 = Kt + (size_t)l31 * 64 + hi * 8;
    const u16* kp1 = Kt + (size_t)(32 + l31) * 64 + hi * 8;
#pragma unroll
    for (int s = 0; s < 4; ++s) {
      kf[s] = *(const short8*)(kp0 + s * 16);
      kf[4 + s] = *(const short8*)(kp1 + s * 16);
    }
  }

  int nt = CAUSAL ? ((q0 >> 6) + 1) : (Lk >> 6);
  for (int t = 0; t < nt - 1; ++t) {
    attn_tile3<0, 1>(kf, Kt + 64 * 64, Vp0, Vp1, qf, t * 64, q0, l31, hi, m, lsum, o0, o1);
    Kt += 64 * 64; Vp0 += 64; Vp1 += 64;
  }
  if (CAUSAL)
    attn_tile3<1, 0>(kf, nullptr, Vp0, Vp1, qf, (nt - 1) * 64, q0, l31, hi, m, lsum, o0, o1);
  else
    attn_tile3<0, 0>(kf, nullptr, Vp0, Vp1, qf, (nt - 1) * 64, q0, l31, hi, m, lsum, o0, o1);

  float myinv = 1.f / lsum;
  int b = bh >> 4, h = bh & 15;
#pragma unroll
  for (int r = 0; r < 16; ++r) {
    int cr = (r & 3) + 8 * (r >> 2) + 4 * hi;
    float li = __shfl(myinv, cr);
    u16* op = O + ((size_t)b * Lq + q0 + cr) * 1024 + h * 64;
    op[l31] = f2bf(o0[r] * li);
    op[32 + l31] = f2bf(o1[r] * li);
  }
}

// ---------------- launch ----------------
extern "C" void kernel_launch(void* const* d_in, const int* in_sizes, int n_in,
                              void* d_out, int out_size, void* d_ws, size_t ws_size,
                              hipStream_t stream) {
  (void)in_sizes; (void)n_in; (void)out_size;
  if (ws_size < WS_NEED) return;  // need ~105 MB scratch

  const float* x     = (const float*)d_in[0];
  const float* ctx   = (const float*)d_in[1];
  const float* g_msa = (const float*)d_in[3];
  const float* g_ca  = (const float*)d_in[4];
  const float* g_mlp = (const float*)d_in[5];
  const float* n1w = (const float*)d_in[6],  *n1b = (const float*)d_in[7];
  const float* n2w = (const float*)d_in[8],  *n2b = (const float*)d_in[9];
  const float* n3w = (const float*)d_in[10], *n3b = (const float*)d_in[11];
  const float* sa_qw = (const float*)d_in[12], *sa_kw = (const float*)d_in[14];
  const float* sa_vw = (const float*)d_in[16], *sa_pw = (const float*)d_in[18];
  const float* sa_qb = (const float*)d_in[13], *sa_kb = (const float*)d_in[15];
  const float* sa_vb = (const float*)d_in[17], *sa_pb = (const float*)d_in[19];
  const float* ca_qw = (const float*)d_in[20], *ca_qb = (const float*)d_in[21];
  const float* ca_kw = (const float*)d_in[22], *ca_kb = (const float*)d_in[23];
  const float* ca_vw = (const float*)d_in[24], *ca_vb = (const float*)d_in[25];
  const float* ca_pw = (const float*)d_in[26], *ca_pb = (const float*)d_in[27];
  const float* fc1w = (const float*)d_in[28], *fc1b = (const float*)d_in[29];
  const float* fc2w = (const float*)d_in[30], *fc2b = (const float*)d_in[31];

  char* ws = (char*)d_ws;
  float* out = (float*)d_out;
  float* tcos = (float*)(ws + OFF_TCOS);
  float* tsin = (float*)(ws + OFF_TSIN);
  u16* Hb   = (u16*)(ws + OFF_H);
  u16* QKV  = (u16*)(ws + OFF_QKV);
  u16* QR   = (u16*)(ws + OFF_QR);
  u16* KR   = (u16*)(ws + OFF_KR);
  u16* VT   = (u16*)(ws + OFF_VT);
  u16* AO   = (u16*)(ws + OFF_AO);
  u8*  H8   = (u8*)(ws + OFF_H);        // ln3 fp8 output
  u8*  U8   = (u8*)(ws + OFF_U);        // fc1 out fp8
  u8*  W8FC1 = (u8*)(ws + OFF_QR);      // fp8 fc1w (QR dead after cross-attn)
  u8*  W8FC2 = (u8*)(ws + OFF_KR);      // fp8 fc2w (KR dead after cross-attn)

  // RoPE tables
  build_tab<<<dim3(128), dim3(256), 0, stream>>>(tcos, tsin);

  // fused weight/context conversion (fp32 -> bf16) into contiguous ws region
  Cvt11 ca;
  ca.s[0] = sa_qw; ca.s[1] = sa_kw; ca.s[2] = sa_vw; ca.s[3] = sa_pw;
  ca.s[4] = ca_qw; ca.s[5] = ca_kw; ca.s[6] = ca_vw; ca.s[7] = ca_pw;
  ca.s[8] = fc1w;  ca.s[9] = fc2w;  ca.s[10] = ctx;
  cvt_all<<<dim3(18432), dim3(256), 0, stream>>>(ca, (u16*)(ws + OFF_WSAQKV));
  Cp5 cp;
  cp.s[0] = sa_qb; cp.s[1] = sa_kb; cp.s[2] = sa_vb; cp.s[3] = ca_kb; cp.s[4] = ca_vb;
  copy5<<<dim3(20), dim3(256), 0, stream>>>(cp, (float*)(ws + OFF_BSAQKV));

  // ---- self-attention ----
  ln_bf16<<<dim3(NTOK), dim3(256), 0, stream>>>(x, n1w, n1b, Hb);
  gemm2<EPI_BF16><<<dim3(3072 / 128, NTOK / 128), dim3(512), 0, stream>>>(
      Hb, (u16*)(ws + OFF_WSAQKV), (float*)(ws + OFF_BSAQKV), QKV, nullptr, nullptr, nullptr,
      NTOK, 3072, 1024, 1);
  {
    Rope3 r;
    r.j[0] = {QKV, QR, 3072, 0,    LQ, NTOK, 0, QSCALE};
    r.j[1] = {QKV, KR, 3072, 1024, LQ, NTOK, 0, 1.0f};
    r.j[2] = {QKV, VT, 3072, 2048, LQ, NTOK, 1, 1.0f};
    rope3<<<dim3(NTOK, 3), dim3(128), 0, stream>>>(r, tcos, tsin);
  }
  flash_attn2<1><<<dim3(512), dim3(256), 0, stream>>>(QR, KR, VT, AO, LQ, LQ);
  gemm2<EPI_RESID><<<dim3(1024 / 128, NTOK / 128), dim3(512), 0, stream>>>(
      AO, (u16*)(ws + OFF_WSAP), sa_pb, nullptr, out, x, g_msa, NTOK, 1024, 1024, 1);

  // ---- cross-attention ----
  ln_bf16<<<dim3(NTOK), dim3(256), 0, stream>>>(out, n2w, n2b, Hb);
  gemm2<EPI_BF16><<<dim3(1024 / 128, NTOK / 128), dim3(512), 0, stream>>>(
      Hb, (u16*)(ws + OFF_WCAQ), ca_qb, (u16*)(ws + OFF_CAQ), nullptr, nullptr, nullptr,
      NTOK, 1024, 1024, 1);
  gemm2<EPI_BF16><<<dim3(2048 / 128, NCTX / 128), dim3(512), 0, stream>>>(
      (u16*)(ws + OFF_CTXB), (u16*)(ws + OFF_WCAKV), (float*)(ws + OFF_BCAKV),
      (u16*)(ws + OFF_CAKV), nullptr, nullptr, nullptr, NCTX, 2048, 1024, 1);
  {
    Rope3 r;
    r.j[0] = {(u16*)(ws + OFF_CAQ),  QR, 1024, 0,    LQ, NTOK, 0, QSCALE};
    r.j[1] = {(u16*)(ws + OFF_CAKV), KR, 2048, 0,    LC, NCTX, 0, 1.0f};
    r.j[2] = {(u16*)(ws + OFF_CAKV), VT, 2048, 1024, LC, NCTX, 1, 1.0f};
    rope3<<<dim3(NTOK, 3), dim3(128), 0, stream>>>(r, tcos, tsin);
  }
  flash_attn2<0><<<dim3(512), dim3(256), 0, stream>>>(QR, KR, VT, AO, LQ, LC);
  gemm2<EPI_RESID><<<dim3(1024 / 128, NTOK / 128), dim3(512), 0, stream>>>(
      AO, (u16*)(ws + OFF_WCAP), ca_pb, nullptr, out, out, g_ca, NTOK, 1024, 1024, 1);

  // ---- MLP (fp8 MX path) ----
  cvt_fp8<<<dim3(8192), dim3(256), 0, stream>>>(fc1w, fc2w, W8FC1, W8FC2);
  ln_fp8<<<dim3(NTOK), dim3(256), 0, stream>>>(out, n3w, n3b, H8);
  gemm8<E8_GELU><<<dim3(4096 / 128, NTOK / 128), dim3(256), 0, stream>>>(
      H8, W8FC1, fc1b, U8, nullptr, nullptr, NTOK, 4096, 1024, 1);
  init_bias_gate<<<dim3(4096), dim3(256), 0, stream>>>(out, fc2b, g_mlp);
  gemm8<E8_ATOMIC><<<dim3(1024 / 128, NTOK / 128, 2), dim3(256), 0, stream>>>(
      U8, W8FC2, nullptr, nullptr, out, g_mlp, NTOK, 1024, 4096, 2);
}

// Round 12
// 380.055 us; speedup vs baseline: 1.1802x; 1.0249x over previous
//
#include <hip/hip_runtime.h>
#include <math.h>

#if !__has_builtin(__builtin_amdgcn_cvt_pk_fp8_f32)
#include <hip/hip_fp8.h>
#endif

typedef __attribute__((ext_vector_type(8))) short short8;
typedef __attribute__((ext_vector_type(4))) float f32x4;
typedef __attribute__((ext_vector_type(16))) float f32x16;
typedef unsigned char u8;
typedef unsigned short u16;
typedef unsigned int u32;
typedef __attribute__((ext_vector_type(2))) u32 u32x2;
typedef __attribute__((ext_vector_type(4))) u32 u32x4;
typedef __attribute__((ext_vector_type(8))) int i32x8;
typedef unsigned long long u64;

static constexpr int E = 1024, H = 16, LQ = 1024, LC = 512, Bn = 4, FF = 4096;
static constexpr int NTOK = Bn * LQ;   // 4096
static constexpr int NCTX = Bn * LC;   // 2048

// Q pre-scale: 1/sqrt(64) * log2(e)  (softmax runs in exp2 domain)
#define QSCALE 0.1803368801111244f
#define DEFER_THR 11.5f

// ---------------- workspace layout (bytes) ----------------
static constexpr size_t OFF_TCOS   = 0;                                    // 1024*32 f32
static constexpr size_t OFF_TSIN   = OFF_TCOS + (size_t)LQ*32*4;
static constexpr size_t OFF_BSAQKV = OFF_TSIN + (size_t)LQ*32*4;           // 3072 f32 (+ca_k/v bias after)
static constexpr size_t OFF_BCAKV  = OFF_BSAQKV + 16384;                   // 2048 f32
// contiguous bf16 weight region (order matters for cvt_all):
static constexpr size_t OFF_WSAQKV = OFF_BCAKV + 16384;                    // [3072][1024] bf16
static constexpr size_t OFF_WSAP   = OFF_WSAQKV + (size_t)3072*1024*2;     // [1024][1024]
static constexpr size_t OFF_WCAQ   = OFF_WSAP   + (size_t)1024*1024*2;
static constexpr size_t OFF_WCAKV  = OFF_WCAQ   + (size_t)1024*1024*2;     // [2048][1024]
static constexpr size_t OFF_WCAP   = OFF_WCAKV  + (size_t)2048*1024*2;
static constexpr size_t OFF_WFC1   = OFF_WCAP   + (size_t)1024*1024*2;     // [4096][1024] (bf16, unused now)
static constexpr size_t OFF_WFC2   = OFF_WFC1   + (size_t)4096*1024*2;     // [1024][4096] (bf16, unused now)
static constexpr size_t OFF_CTXB   = OFF_WFC2   + (size_t)1024*4096*2;     // [2048][1024] bf16
static constexpr size_t OFF_H      = OFF_CTXB   + (size_t)2048*1024*2;     // [4096][1024] bf16 (LN out) / fp8 for ln3
static constexpr size_t OFF_QKV    = OFF_H      + (size_t)4096*1024*2;     // [4096][3072] bf16
static constexpr size_t OFF_CAQ    = OFF_QKV;                              // [4096][1024]
static constexpr size_t OFF_CAKV   = OFF_QKV + (size_t)4096*1024*2;        // [2048][2048]
static constexpr size_t OFF_QR     = OFF_QKV + (size_t)4096*3072*2;        // [B,H,LQ,64] / fp8 fc1w after CA
static constexpr size_t OFF_KR     = OFF_QR  + (size_t)4096*1024*2;        // [B,H,Lk,64] / fp8 fc2w after CA
static constexpr size_t OFF_VT     = OFF_KR  + (size_t)4096*1024*2;        // [B,H,64,Lk]
static constexpr size_t OFF_AO     = OFF_VT  + (size_t)4096*1024*2;        // [4096][1024] bf16
static constexpr size_t OFF_U      = OFF_QKV;                              // fc1 out [4096][4096] fp8 reuses QKV
static constexpr size_t WS_NEED    = OFF_AO + (size_t)4096*1024*2;         // ~105 MB

// ---------------- helpers ----------------
static __device__ __forceinline__ float bf2f(u16 u) {
  union { u32 i; float f; } un; un.i = ((u32)u) << 16; return un.f;
}
static __device__ __forceinline__ u16 f2bf(float f) {  // RNE
  union { float f; u32 u; } un; un.f = f;
  u32 u = un.u;
  return (u16)((u + 0x7FFFu + ((u >> 16) & 1u)) >> 16);
}
static __device__ __forceinline__ u64 pack4(u16 a, u16 b, u16 c, u16 d) {
  return (u64)a | ((u64)b << 16) | ((u64)c << 32) | ((u64)d << 48);
}
static __device__ __forceinline__ f32x4 mfma16(short8 a, short8 b, f32x4 c) {
  return __builtin_amdgcn_mfma_f32_16x16x32_bf16(a, b, c, 0, 0, 0);
}
static __device__ __forceinline__ f32x16 mfma32(short8 a, short8 b, f32x16 c) {
  return __builtin_amdgcn_mfma_f32_32x32x16_bf16(a, b, c, 0, 0, 0);
}
static __device__ __forceinline__ void gload_lds16(void* lds, const void* g) {
  __builtin_amdgcn_global_load_lds(
      (const __attribute__((address_space(1))) void*)g,
      (__attribute__((address_space(3))) void*)lds, 16, 0, 0);
}
// gelu(x) = 0.5x(1+tanh(z)) = x*e/(e+1), e=exp(2*0.79788456(x+0.044715x^3)).
static __device__ __forceinline__ float gelu_tanh(float x) {
  float z2 = 1.5957691216057308f * (x + 0.044715f * x * x * x);
  float e = __expf(z2);
  float r = __builtin_amdgcn_rcpf(e + 1.0f);
  return x - x * r;   // x*(1 - 1/(e+1)) = x*e/(e+1)
}
static __device__ __forceinline__ u32 cvtpk_bf16(float lo, float hi) {
  u32 r;
  asm("v_cvt_pk_bf16_f32 %0, %1, %2" : "=v"(r) : "v"(lo), "v"(hi));
  return r;
}
// fp32 -> OCP e4m3 (saturating)
static __device__ __forceinline__ u32 pack_fp8x4(float a, float b, float c, float d) {
#if __has_builtin(__builtin_amdgcn_cvt_pk_fp8_f32)
  u32 r = (u32)__builtin_amdgcn_cvt_pk_fp8_f32(a, b, 0, false);
  r = (u32)__builtin_amdgcn_cvt_pk_fp8_f32(c, d, (int)r, true);
  return r;
#else
  __hip_fp8_e4m3 qa(a), qb(b), qc(c), qd(d);
  return (u32)qa.__x | ((u32)qb.__x << 8) | ((u32)qc.__x << 16) | ((u32)qd.__x << 24);
#endif
}
static __device__ __forceinline__ u8 fp8b(float f) {
#if __has_builtin(__builtin_amdgcn_cvt_pk_fp8_f32)
  return (u8)((u32)__builtin_amdgcn_cvt_pk_fp8_f32(f, f, 0, false) & 0xFFu);
#else
  __hip_fp8_e4m3 t(f); return t.__x;
#endif
}

// ---------------- small kernels ----------------
__global__ __launch_bounds__(256) void build_tab(float* __restrict__ ct, float* __restrict__ st) {
  int idx = blockIdx.x * 256 + threadIdx.x;           // 1024*32 entries
  int pos = idx >> 5, i = idx & 31;
  float inv = powf(10000.f, -(float)i * (1.f / 32.f));
  float a = (float)pos * inv;
  ct[idx] = cosf(a);
  st[idx] = sinf(a);
}

// fused fp32->bf16 conversion of weights + context (segments 8,9 = fc1w/fc2w
// handled by cvt_fp8 -> early-exit).
struct Cvt11 { const float* s[11]; };
__global__ __launch_bounds__(256) void cvt_all(Cvt11 a, u16* __restrict__ dst) {
  u32 gid = blockIdx.x * 256 + threadIdx.x;   // 0 .. 4718591
  u32 s, off;
  if (gid < 2097152u)      { s = gid >> 18;                        off = gid & 262143u; }
  else if (gid < 4194304u) { return; }        // fc1w/fc2w handled in fp8
  else                     { s = 10;                               off = gid - 4194304u; }
  float4 v = *(const float4*)(a.s[s] + (size_t)off * 4);
  *(u64*)(dst + (size_t)gid * 4) = pack4(f2bf(v.x), f2bf(v.y), f2bf(v.z), f2bf(v.w));
}

// fc1w/fc2w -> fp8 e4m3 scaled x256
__global__ __launch_bounds__(256) void cvt_fp8(const float* __restrict__ s0, const float* __restrict__ s1,
                                               u8* __restrict__ d0, u8* __restrict__ d1) {
  u32 gid = blockIdx.x * 256 + threadIdx.x;   // 0..2097151, 4 elems each
  const float* s; u8* d; u32 off;
  if (gid < 1048576u) { s = s0; d = d0; off = gid; }
  else                { s = s1; d = d1; off = gid - 1048576u; }
  float4 v = *(const float4*)(s + (size_t)off * 4);
  *(u32*)(d + (size_t)off * 4) =
      pack_fp8x4(v.x * 256.f, v.y * 256.f, v.z * 256.f, v.w * 256.f);
}

// fused bias copies: sa_q,sa_k,sa_v -> BSAQKV(+0,+1024,+2048); ca_k,ca_v -> BCAKV(+0,+1024)
struct Cp5 { const float* s[5]; };
__global__ __launch_bounds__(256) void copy5(Cp5 a, float* __restrict__ dst) {
  int gid = blockIdx.x * 256 + threadIdx.x;   // 0..5119
  int s = gid >> 10, off = gid & 1023;
  int doff = (s < 3) ? s * 1024 : 4096 + (s - 3) * 1024;
  dst[doff + off] = a.s[s][off];
}

// LN over last dim 1024, one row per block, bf16 out.
__global__ __launch_bounds__(256) void ln_bf16(const float* __restrict__ x, const float* __restrict__ w,
                                               const float* __restrict__ b, u16* __restrict__ out) {
  __shared__ float red[4];
  int row = blockIdx.x, tid = threadIdx.x;
  const float* xr = x + (size_t)row * 1024;
  float4 v = ((const float4*)xr)[tid];
  float s = v.x + v.y + v.z + v.w;
#pragma unroll
  for (int off = 32; off; off >>= 1) s += __shfl_xor(s, off);
  if ((tid & 63) == 0) red[tid >> 6] = s;
  __syncthreads();
  float mean = (red[0] + red[1] + red[2] + red[3]) * (1.f / 1024.f);
  float dx = v.x - mean, dy = v.y - mean, dz = v.z - mean, dw = v.w - mean;
  float sq = dx * dx + dy * dy + dz * dz + dw * dw;
#pragma unroll
  for (int off = 32; off; off >>= 1) sq += __shfl_xor(sq, off);
  __syncthreads();
  if ((tid & 63) == 0) red[tid >> 6] = sq;
  __syncthreads();
  float var = (red[0] + red[1] + red[2] + red[3]) * (1.f / 1024.f);
  float rstd = rsqrtf(var + 1e-6f);
  float4 wv = ((const float4*)w)[tid];
  float4 bv = ((const float4*)b)[tid];
  u64 o = pack4(f2bf(dx * rstd * wv.x + bv.x), f2bf(dy * rstd * wv.y + bv.y),
                f2bf(dz * rstd * wv.z + bv.z), f2bf(dw * rstd * wv.w + bv.w));
  *(u64*)(out + (size_t)row * 1024 + tid * 4) = o;
}

// LN -> fp8 e4m3 scaled x16 (for the fp8 MLP path)
__global__ __launch_bounds__(256) void ln_fp8(const float* __restrict__ x, const float* __restrict__ w,
                                              const float* __restrict__ b, u8* __restrict__ out) {
  __shared__ float red[4];
  int row = blockIdx.x, tid = threadIdx.x;
  const float* xr = x + (size_t)row * 1024;
  float4 v = ((const float4*)xr)[tid];
  float s = v.x + v.y + v.z + v.w;
#pragma unroll
  for (int off = 32; off; off >>= 1) s += __shfl_xor(s, off);
  if ((tid & 63) == 0) red[tid >> 6] = s;
  __syncthreads();
  float mean = (red[0] + red[1] + red[2] + red[3]) * (1.f / 1024.f);
  float dx = v.x - mean, dy = v.y - mean, dz = v.z - mean, dw = v.w - mean;
  float sq = dx * dx + dy * dy + dz * dz + dw * dw;
#pragma unroll
  for (int off = 32; off; off >>= 1) sq += __shfl_xor(sq, off);
  __syncthreads();
  if ((tid & 63) == 0) red[tid >> 6] = sq;
  __syncthreads();
  float var = (red[0] + red[1] + red[2] + red[3]) * (1.f / 1024.f);
  float rstd = rsqrtf(var + 1e-6f);
  float4 wv = ((const float4*)w)[tid];
  float4 bv = ((const float4*)b)[tid];
  u32 pk = pack_fp8x4((dx * rstd * wv.x + bv.x) * 16.f, (dy * rstd * wv.y + bv.y) * 16.f,
                      (dz * rstd * wv.z + bv.z) * 16.f, (dw * rstd * wv.w + bv.w) * 16.f);
  *(u32*)(out + (size_t)row * 1024 + tid * 4) = pk;
}

// Fused RoPE/scatter: 3 jobs in one dispatch (blockIdx.y selects job).
struct RopeJob { const u16* src; u16* dst; int ld, col0, Lper, T, mode; float scale; };
struct Rope3 { RopeJob j[3]; };
__global__ __launch_bounds__(128) void rope3(Rope3 a, const float* __restrict__ cosT,
                                             const float* __restrict__ sinT) {
  RopeJob jb = a.j[blockIdx.y];
  int t = blockIdx.x;
  if (t >= jb.T) return;
  int b = t / jb.Lper, l = t - b * jb.Lper;
  int tid = threadIdx.x;
  int e0 = tid * 8;
  int h = e0 >> 6, d0 = e0 & 63;
  short8 vv = *(const short8*)(jb.src + (size_t)t * jb.ld + jb.col0 + e0);
  if (jb.mode == 0) {
    short8 ov;
#pragma unroll
    for (int j = 0; j < 4; ++j) {
      float x1 = bf2f((u16)vv[2 * j]);
      float x2 = bf2f((u16)vv[2 * j + 1]);
      int i = (d0 >> 1) + j;
      float c = cosT[l * 32 + i], s = sinT[l * 32 + i];
      ov[2 * j]     = (short)f2bf((x1 * c - x2 * s) * jb.scale);
      ov[2 * j + 1] = (short)f2bf((x1 * s + x2 * c) * jb.scale);
    }
    *(short8*)(jb.dst + (((size_t)b * H + h) * jb.Lper + l) * 64 + d0) = ov;
  } else {
#pragma unroll
    for (int m = 0; m < 8; ++m)
      jb.dst[(((size_t)b * H + h) * 64 + d0 + m) * jb.Lper + l] = (u16)vv[m];
  }
}

// ---------------- bf16 GEMM (proven R8 config): C = A @ W^T + bias ----------------
enum { EPI_BF16 = 0, EPI_GELU = 1, EPI_RESID = 2 };

template <int EPI>
__global__ __launch_bounds__(512, 4) void gemm2(const u16* __restrict__ A, const u16* __restrict__ W,
                                                const float* __restrict__ bias, u16* outb, float* outf,
                                                const float* res, const float* __restrict__ gate,
                                                int M, int N, int K) {
  __shared__ u16 As[2][128 * 64];
  __shared__ u16 Bs[2][128 * 64];

  int nwg = gridDim.x * gridDim.y;
  int bid = blockIdx.y * gridDim.x + blockIdx.x;
  int cpx = nwg >> 3;
  int swz = (bid & 7) * cpx + (bid >> 3);
  int bx = swz % gridDim.x;
  int by = swz / gridDim.x;
  int row0 = by * 128, col0 = bx * 128;

  int tid = threadIdx.x;
  int lane = tid & 63, wid = tid >> 6;
  int wr = wid >> 2, wc = wid & 3;  // 2x4 waves, each owns 64x32
  int lr = lane & 15, lg = lane >> 4;

  size_t a_off0, a_off1, b_off0, b_off1;
  int l_off0 = tid * 8, l_off1 = (512 + tid) * 8;
  {
    int q = tid, r = q >> 3, p = q & 7, sp = p ^ (r & 7);
    a_off0 = (size_t)(row0 + r) * K + sp * 8;
    b_off0 = (size_t)(col0 + r) * K + sp * 8;
    q = 512 + tid; r = q >> 3; p = q & 7; sp = p ^ (r & 7);
    a_off1 = (size_t)(row0 + r) * K + sp * 8;
    b_off1 = (size_t)(col0 + r) * K + sp * 8;
  }

  f32x4 acc[4][2] = {};

  const int nkt = K >> 6;
  {
    gload_lds16(&As[0][l_off0], A + a_off0);
    gload_lds16(&Bs[0][l_off0], W + b_off0);
    gload_lds16(&As[0][l_off1], A + a_off1);
    gload_lds16(&Bs[0][l_off1], W + b_off1);
  }
  __syncthreads();

  for (int kt = 0; kt < nkt; ++kt) {
    int cur = kt & 1;
    if (kt + 1 < nkt) {
      int k0 = (kt + 1) << 6;
      gload_lds16(&As[cur ^ 1][l_off0], A + a_off0 + k0);
      gload_lds16(&Bs[cur ^ 1][l_off0], W + b_off0 + k0);
      gload_lds16(&As[cur ^ 1][l_off1], A + a_off1 + k0);
      gload_lds16(&Bs[cur ^ 1][l_off1], W + b_off1 + k0);
    }
#pragma unroll
    for (int kk = 0; kk < 2; ++kk) {
      short8 af[4], bfr[2];
#pragma unroll
      for (int m = 0; m < 4; ++m) {
        int r = wr * 64 + m * 16 + lr;
        int sc = (kk * 4 + lg) ^ (r & 7);
        af[m] = *(const short8*)(&As[cur][r * 64 + sc * 8]);
      }
#pragma unroll
      for (int n = 0; n < 2; ++n) {
        int r = wc * 32 + n * 16 + lr;
        int sc = (kk * 4 + lg) ^ (r & 7);
        bfr[n] = *(const short8*)(&Bs[cur][r * 64 + sc * 8]);
      }
#pragma unroll
      for (int m = 0; m < 4; ++m)
#pragma unroll
        for (int n = 0; n < 2; ++n)
          acc[m][n] = mfma16(af[m], bfr[n], acc[m][n]);
    }
    __syncthreads();
  }

  if (EPI == EPI_BF16 || EPI == EPI_GELU) {
    u16* Ct = &As[0][0];
#pragma unroll
    for (int n = 0; n < 2; ++n) {
      int c = wc * 32 + n * 16 + lr;
      float bv = bias[col0 + c];
#pragma unroll
      for (int m = 0; m < 4; ++m) {
#pragma unroll
        for (int i = 0; i < 4; ++i) {
          int r = wr * 64 + m * 16 + lg * 4 + i;
          float v = acc[m][n][i] + bv;
          Ct[r * 128 + c] = f2bf(EPI == EPI_GELU ? gelu_tanh(v) : v);
        }
      }
    }
    __syncthreads();
#pragma unroll
    for (int j = 0; j < 4; ++j) {
      u32 q = (u32)tid + j * 512;
      u32 r = q >> 4, ck = q & 15;
      short8 v = *(const short8*)(Ct + r * 128 + ck * 8);
      *(short8*)(outb + (size_t)(row0 + r) * N + col0 + ck * 8) = v;
    }
  } else {
#pragma unroll
    for (int n = 0; n < 2; ++n) {
      int cg = col0 + wc * 32 + n * 16 + lr;
      float bv = bias[cg];
#pragma unroll
      for (int m = 0; m < 4; ++m) {
#pragma unroll
        for (int i = 0; i < 4; ++i) {
          int rg = row0 + wr * 64 + m * 16 + lg * 4 + i;
          float v = acc[m][n][i] + bv;
          float r = res[(size_t)rg * N + cg];
          outf[(size_t)rg * N + cg] = r + gate[cg] * v;
        }
      }
    }
  }
}

// ---------------- fp8 MX GEMM: C = (A/16) @ (W/256)^T -> acc/4096 ----------------
// 128x128 tile, BK=128, 256 threads (2x2 waves of 64x64 = 4x4 16x16-frags),
// dbuf 32 KiB LDS, gemm2 pipeline. mfma_scale_f32_16x16x128_f8f6f4 with unity
// E8M0 scales. 16x16 fragment read = 16 rows (lane&15) x 4 slots (lane>>4):
// EXACTLY the measured-zero-conflict gemm2 LDS pattern (vs 32x32's 4 cyc/read).
enum { E8_GELU = 0, E8_RESID = 1 };

template <int EPI>
__global__ __launch_bounds__(256, 2) void gemm8(const u8* __restrict__ A, const u8* __restrict__ W,
                                                const float* __restrict__ bias, u8* outb, float* outf,
                                                const float* res, const float* __restrict__ gate,
                                                int M, int N, int K) {
  __shared__ u8 As[2][128 * 128];
  __shared__ u8 Bs[2][128 * 128];

  int nwg = gridDim.x * gridDim.y;
  int bid = blockIdx.y * gridDim.x + blockIdx.x;
  int cpx = nwg >> 3;
  int swz = (bid & 7) * cpx + (bid >> 3);
  int bx = swz % gridDim.x, by = swz / gridDim.x;
  int row0 = by * 128, col0 = bx * 128;

  int tid = threadIdx.x;
  int lane = tid & 63, wid = tid >> 6;
  int wr = wid >> 1, wc = wid & 1;      // 2x2 waves, each owns 64x64
  int lr = lane & 15, lg = lane >> 4;

  // staging: tile = 128 rows x 128 B = 1024 chunks of 16 B; 4 per thread per matrix.
  u32 aoff[4], boff[4];
  int ldso[4];
#pragma unroll
  for (int j = 0; j < 4; ++j) {
    int q = tid + j * 256;
    int r = q >> 3, p = q & 7, sp = p ^ (r & 7);
    aoff[j] = (u32)(row0 + r) * (u32)K + sp * 16;
    boff[j] = (u32)(col0 + r) * (u32)K + sp * 16;
    ldso[j] = q * 16;
  }

  f32x4 acc[4][4] = {};
  const int nkt = K >> 7;               // BK = 128

  // 16x16x128 fragment: lane (lr,lg) reads row r=base+frag*16+lr,
  // k-bytes lg*32..lg*32+31 = slots lg*2, lg*2+1 (XOR-swizzled).
  auto rdfrag = [&](const u8* base, int r, i32x8& f) {
    const u8* rp = base + r * 128;
    int ck = lg * 2;
    u32x4 lo = *(const u32x4*)(rp + ((ck) ^ (r & 7)) * 16);
    u32x4 hh = *(const u32x4*)(rp + ((ck + 1) ^ (r & 7)) * 16);
    i32x8 v;
    v[0] = (int)lo[0]; v[1] = (int)lo[1]; v[2] = (int)lo[2]; v[3] = (int)lo[3];
    v[4] = (int)hh[0]; v[5] = (int)hh[1]; v[6] = (int)hh[2]; v[7] = (int)hh[3];
    f = v;
  };

  // prologue
#pragma unroll
  for (int j = 0; j < 4; ++j) {
    gload_lds16(&As[0][ldso[j]], A + aoff[j]);
    gload_lds16(&Bs[0][ldso[j]], W + boff[j]);
  }
  __syncthreads();

  for (int kt = 0; kt < nkt; ++kt) {
    int cur = kt & 1;
    if (kt + 1 < nkt) {
      int k0 = (kt + 1) << 7;
#pragma unroll
      for (int j = 0; j < 4; ++j) {
        gload_lds16(&As[cur ^ 1][ldso[j]], A + aoff[j] + k0);
        gload_lds16(&Bs[cur ^ 1][ldso[j]], W + boff[j] + k0);
      }
    }
    i32x8 a[4], b[4];
#pragma unroll
    for (int m = 0; m < 4; ++m) rdfrag(&As[cur][0], wr * 64 + m * 16 + lr, a[m]);
#pragma unroll
    for (int n = 0; n < 4; ++n) rdfrag(&Bs[cur][0], wc * 64 + n * 16 + lr, b[n]);
    __builtin_amdgcn_s_setprio(1);
#pragma unroll
    for (int m = 0; m < 4; ++m)
#pragma unroll
      for (int n = 0; n < 4; ++n)
        acc[m][n] = __builtin_amdgcn_mfma_scale_f32_16x16x128_f8f6f4(
            a[m], b[n], acc[m][n], 0, 0, 0, 0x7F7F7F7F, 0, 0x7F7F7F7F);
    __builtin_amdgcn_s_setprio(0);
    __syncthreads();
  }

  // epilogue: C layout col=lane&15, row=(lane>>4)*4+i (dtype-independent)
  constexpr float SCL = 1.f / 4096.f;   // undo x16 (act) * x256 (weights)
  if (EPI == E8_GELU) {
    u8* Ct = &As[0][0];                 // [128][128] u8 = 16 KiB
#pragma unroll
    for (int n = 0; n < 4; ++n) {
      int cl = wc * 64 + n * 16 + lr;
      float bv = bias[col0 + cl];
#pragma unroll
      for (int m = 0; m < 4; ++m) {
#pragma unroll
        for (int i = 0; i < 4; ++i) {
          int rl = wr * 64 + m * 16 + lg * 4 + i;
          float v = acc[m][n][i] * SCL + bv;
          Ct[rl * 128 + cl] = fp8b(gelu_tanh(v) * 16.f);
        }
      }
    }
    __syncthreads();
#pragma unroll
    for (int j = 0; j < 4; ++j) {
      int q = tid + j * 256;
      int r = q >> 3, ck = q & 7;
      *(u32x4*)(outb + (size_t)(row0 + r) * N + col0 + ck * 16) =
          *(const u32x4*)(Ct + r * 128 + ck * 16);
    }
  } else {
#pragma unroll
    for (int n = 0; n < 4; ++n) {
      int cg = col0 + wc * 64 + n * 16 + lr;
      float bv = bias[cg], gv = gate[cg];
#pragma unroll
      for (int m = 0; m < 4; ++m) {
#pragma unroll
        for (int i = 0; i < 4; ++i) {
          int rg = row0 + wr * 64 + m * 16 + lg * 4 + i;
          float v = acc[m][n][i] * SCL + bv;
          float r = res[(size_t)rg * N + cg];
          outf[(size_t)rg * N + cg] = r + gv * v;
        }
      }
    }
  }
}

// ---------------- flash attention, swapped-QK^T, register-pipelined K/V ----------------
template <int MASKED, int PRE>
static __device__ __forceinline__ void attn_tile3(short8* kf, const u16* KtNext,
                                                  const u16* Vp0, const u16* Vp1,
                                                  const short8* qf, int kb, int q0, int l31, int hi,
                                                  float& m, float& lsum, f32x16& o0, f32x16& o1) {
  // 1) V loads for THIS tile — independent, issue first
  short8 vf0[4], vf1[4];
#pragma unroll
  for (int ks = 0; ks < 4; ++ks) {
    vf0[ks] = *(const short8*)(Vp0 + ks * 16 + hi * 8);
    vf1[ks] = *(const short8*)(Vp1 + ks * 16 + hi * 8);
  }
  // 2) QK^T from pre-loaded K registers
  f32x16 s0 = {}, s1 = {};
  __builtin_amdgcn_s_setprio(1);
#pragma unroll
  for (int s = 0; s < 4; ++s) {
    s0 = mfma32(kf[s], qf[s], s0);       // S^T[k][q]
    s1 = mfma32(kf[4 + s], qf[s], s1);
  }
  __builtin_amdgcn_s_setprio(0);
  // 3) prefetch next tile's K into kf (dead after QK^T)
  if (PRE) {
    const u16* kp0 = KtNext + (size_t)l31 * 64 + hi * 8;
    const u16* kp1 = KtNext + (size_t)(32 + l31) * 64 + hi * 8;
#pragma unroll
    for (int s = 0; s < 4; ++s) {
      kf[s] = *(const short8*)(kp0 + s * 16);
      kf[4 + s] = *(const short8*)(kp1 + s * 16);
    }
  }
  if (MASKED) {
    int qg = q0 + l31;
#pragma unroll
    for (int r = 0; r < 16; ++r) {
      int kk = kb + (r & 3) + 8 * (r >> 2) + 4 * hi;
      if (kk > qg) s0[r] = -INFINITY;
      if (kk + 32 > qg) s1[r] = -INFINITY;
    }
  }
  float pm = -INFINITY;
#pragma unroll
  for (int r = 0; r < 16; ++r) pm = fmaxf(pm, fmaxf(s0[r], s1[r]));
  pm = fmaxf(pm, __shfl_xor(pm, 32));
  if (!__all(pm <= m + DEFER_THR)) {
    float mn = fmaxf(m, pm);
    float al = exp2f(m - mn);
    m = mn;
    lsum *= al;
#pragma unroll
    for (int r = 0; r < 16; ++r) {
      float alr = __shfl(al, (r & 3) + 8 * (r >> 2) + 4 * hi);
      o0[r] *= alr;
      o1[r] *= alr;
    }
  }
  float ts = 0.f;
#pragma unroll
  for (int r = 0; r < 16; ++r) {
    float p0 = exp2f(s0[r] - m);
    float p1 = exp2f(s1[r] - m);
    s0[r] = p0; s1[r] = p1;
    ts += p0 + p1;
  }
  ts += __shfl_xor(ts, 32);
  lsum += ts;
  auto pack8 = [&](float a0, float a1, float a2, float a3,
                   float a4, float a5, float a6, float a7) -> short8 {
    u32 c0 = cvtpk_bf16(a0, a1), c1 = cvtpk_bf16(a2, a3);
    u32 c2 = cvtpk_bf16(a4, a5), c3 = cvtpk_bf16(a6, a7);
    u32x2 r02 = __builtin_amdgcn_permlane32_swap(c0, c2, false, false);
    u32x2 r13 = __builtin_amdgcn_permlane32_swap(c1, c3, false, false);
    u32x4 w;
    w[0] = r02[0]; w[1] = r13[0]; w[2] = r02[1]; w[3] = r13[1];
    return __builtin_bit_cast(short8, w);
  };
  short8 pa0 = pack8(s0[0], s0[1], s0[2], s0[3], s0[4], s0[5], s0[6], s0[7]);
  short8 pa1 = pack8(s0[8], s0[9], s0[10], s0[11], s0[12], s0[13], s0[14], s0[15]);
  short8 pa2 = pack8(s1[0], s1[1], s1[2], s1[3], s1[4], s1[5], s1[6], s1[7]);
  short8 pa3 = pack8(s1[8], s1[9], s1[10], s1[11], s1[12], s1[13], s1[14], s1[15]);
  short8 pa[4] = {pa0, pa1, pa2, pa3};
  __builtin_amdgcn_s_setprio(1);
#pragma unroll
  for (int ks = 0; ks < 4; ++ks) {
    o0 = mfma32(pa[ks], vf0[ks], o0);
    o1 = mfma32(pa[ks], vf1[ks], o1);
  }
  __builtin_amdgcn_s_setprio(0);
}

template <int CAUSAL>
__global__ __launch_bounds__(256) void flash_attn2(const u16* __restrict__ Q, const u16* __restrict__ K,
                                                   const u16* __restrict__ Vt, u16* __restrict__ O,
                                                   int Lq, int Lk) {
  const int wid = threadIdx.x >> 6, lane = threadIdx.x & 63;
  const int l31 = lane & 31, hi = lane >> 5;
  int wg = blockIdx.x * 4 + wid;     // 4 independent waves per block, no barriers
  int bh = wg & 63;
  int qc = wg >> 6;
  if (CAUSAL) qc = (Lq >> 5) - 1 - qc;   // heavy q-chunks dispatch first
  int q0 = qc << 5;

  const u16* Qb = Q + ((size_t)bh * Lq + q0) * 64;
  const u16* Kb = K + (size_t)bh * Lk * 64;
  const u16* Vb = Vt + (size_t)bh * 64 * Lk;

  short8 qf[4];
#pragma unroll
  for (int s = 0; s < 4; ++s) qf[s] = *(const short8*)(Qb + (size_t)l31 * 64 + s * 16 + hi * 8);

  f32x16 o0 = {}, o1 = {};
  float m = -INFINITY, lsum = 0.f;

  const u16* Kt = Kb;
  const u16* Vp0 = Vb + (size_t)l31 * Lk;
  const u16* Vp1 = Vb + (size_t)(32 + l31) * Lk;

  // preload K tile 0 into registers
  short8 kf[8];
  {
    const u16* kp0 = Kt + (size_t)l31 * 64 + hi * 8;
    const u16* kp1 = Kt + (size_t)(32 + l31) * 64 + hi * 8;
#pragma unroll
    for (int s = 0; s < 4; ++s) {
      kf[s] = *(const short8*)(kp0 + s * 16);
      kf[4 + s] = *(const short8*)(kp1 + s * 16);
    }
  }

  int nt = CAUSAL ? ((q0 >> 6) + 1) : (Lk >> 6);
  for (int t = 0; t < nt - 1; ++t) {
    attn_tile3<0, 1>(kf, Kt + 64 * 64, Vp0, Vp1, qf, t * 64, q0, l31, hi, m, lsum, o0, o1);
    Kt += 64 * 64; Vp0 += 64; Vp1 += 64;
  }
  if (CAUSAL)
    attn_tile3<1, 0>(kf, nullptr, Vp0, Vp1, qf, (nt - 1) * 64, q0, l31, hi, m, lsum, o0, o1);
  else
    attn_tile3<0, 0>(kf, nullptr, Vp0, Vp1, qf, (nt - 1) * 64, q0, l31, hi, m, lsum, o0, o1);

  float myinv = 1.f / lsum;
  int b = bh >> 4, h = bh & 15;
#pragma unroll
  for (int r = 0; r < 16; ++r) {
    int cr = (r & 3) + 8 * (r >> 2) + 4 * hi;
    float li = __shfl(myinv, cr);
    u16* op = O + ((size_t)b * Lq + q0 + cr) * 1024 + h * 64;
    op[l31] = f2bf(o0[r] * li);
    op[32 + l31] = f2bf(o1[r] * li);
  }
}

// ---------------- launch ----------------
extern "C" void kernel_launch(void* const* d_in, const int* in_sizes, int n_in,
                              void* d_out, int out_size, void* d_ws, size_t ws_size,
                              hipStream_t stream) {
  (void)in_sizes; (void)n_in; (void)out_size;
  if (ws_size < WS_NEED) return;  // need ~105 MB scratch

  const float* x     = (const float*)d_in[0];
  const float* ctx   = (const float*)d_in[1];
  const float* g_msa = (const float*)d_in[3];
  const float* g_ca  = (const float*)d_in[4];
  const float* g_mlp = (const float*)d_in[5];
  const float* n1w = (const float*)d_in[6],  *n1b = (const float*)d_in[7];
  const float* n2w = (const float*)d_in[8],  *n2b = (const float*)d_in[9];
  const float* n3w = (const float*)d_in[10], *n3b = (const float*)d_in[11];
  const float* sa_qw = (const float*)d_in[12], *sa_kw = (const float*)d_in[14];
  const float* sa_vw = (const float*)d_in[16], *sa_pw = (const float*)d_in[18];
  const float* sa_qb = (const float*)d_in[13], *sa_kb = (const float*)d_in[15];
  const float* sa_vb = (const float*)d_in[17], *sa_pb = (const float*)d_in[19];
  const float* ca_qw = (const float*)d_in[20], *ca_qb = (const float*)d_in[21];
  const float* ca_kw = (const float*)d_in[22], *ca_kb = (const float*)d_in[23];
  const float* ca_vw = (const float*)d_in[24], *ca_vb = (const float*)d_in[25];
  const float* ca_pw = (const float*)d_in[26], *ca_pb = (const float*)d_in[27];
  const float* fc1w = (const float*)d_in[28], *fc1b = (const float*)d_in[29];
  const float* fc2w = (const float*)d_in[30], *fc2b = (const float*)d_in[31];

  char* ws = (char*)d_ws;
  float* out = (float*)d_out;
  float* tcos = (float*)(ws + OFF_TCOS);
  float* tsin = (float*)(ws + OFF_TSIN);
  u16* Hb   = (u16*)(ws + OFF_H);
  u16* QKV  = (u16*)(ws + OFF_QKV);
  u16* QR   = (u16*)(ws + OFF_QR);
  u16* KR   = (u16*)(ws + OFF_KR);
  u16* VT   = (u16*)(ws + OFF_VT);
  u16* AO   = (u16*)(ws + OFF_AO);
  u8*  H8   = (u8*)(ws + OFF_H);        // ln3 fp8 output
  u8*  U8   = (u8*)(ws + OFF_U);        // fc1 out fp8
  u8*  W8FC1 = (u8*)(ws + OFF_QR);      // fp8 fc1w (QR dead after cross-attn)
  u8*  W8FC2 = (u8*)(ws + OFF_KR);      // fp8 fc2w (KR dead after cross-attn)

  // RoPE tables
  build_tab<<<dim3(128), dim3(256), 0, stream>>>(tcos, tsin);

  // fused weight/context conversion (fp32 -> bf16) into contiguous ws region
  Cvt11 ca;
  ca.s[0] = sa_qw; ca.s[1] = sa_kw; ca.s[2] = sa_vw; ca.s[3] = sa_pw;
  ca.s[4] = ca_qw; ca.s[5] = ca_kw; ca.s[6] = ca_vw; ca.s[7] = ca_pw;
  ca.s[8] = fc1w;  ca.s[9] = fc2w;  ca.s[10] = ctx;
  cvt_all<<<dim3(18432), dim3(256), 0, stream>>>(ca, (u16*)(ws + OFF_WSAQKV));
  Cp5 cp;
  cp.s[0] = sa_qb; cp.s[1] = sa_kb; cp.s[2] = sa_vb; cp.s[3] = ca_kb; cp.s[4] = ca_vb;
  copy5<<<dim3(20), dim3(256), 0, stream>>>(cp, (float*)(ws + OFF_BSAQKV));

  // ---- self-attention ----
  ln_bf16<<<dim3(NTOK), dim3(256), 0, stream>>>(x, n1w, n1b, Hb);
  gemm2<EPI_BF16><<<dim3(3072 / 128, NTOK / 128), dim3(512), 0, stream>>>(
      Hb, (u16*)(ws + OFF_WSAQKV), (float*)(ws + OFF_BSAQKV), QKV, nullptr, nullptr, nullptr,
      NTOK, 3072, 1024);
  {
    Rope3 r;
    r.j[0] = {QKV, QR, 3072, 0,    LQ, NTOK, 0, QSCALE};
    r.j[1] = {QKV, KR, 3072, 1024, LQ, NTOK, 0, 1.0f};
    r.j[2] = {QKV, VT, 3072, 2048, LQ, NTOK, 1, 1.0f};
    rope3<<<dim3(NTOK, 3), dim3(128), 0, stream>>>(r, tcos, tsin);
  }
  flash_attn2<1><<<dim3(512), dim3(256), 0, stream>>>(QR, KR, VT, AO, LQ, LQ);
  gemm2<EPI_RESID><<<dim3(1024 / 128, NTOK / 128), dim3(512), 0, stream>>>(
      AO, (u16*)(ws + OFF_WSAP), sa_pb, nullptr, out, x, g_msa, NTOK, 1024, 1024);

  // ---- cross-attention ----
  ln_bf16<<<dim3(NTOK), dim3(256), 0, stream>>>(out, n2w, n2b, Hb);
  gemm2<EPI_BF16><<<dim3(1024 / 128, NTOK / 128), dim3(512), 0, stream>>>(
      Hb, (u16*)(ws + OFF_WCAQ), ca_qb, (u16*)(ws + OFF_CAQ), nullptr, nullptr, nullptr,
      NTOK, 1024, 1024);
  gemm2<EPI_BF16><<<dim3(2048 / 128, NCTX / 128), dim3(512), 0, stream>>>(
      (u16*)(ws + OFF_CTXB), (u16*)(ws + OFF_WCAKV), (float*)(ws + OFF_BCAKV),
      (u16*)(ws + OFF_CAKV), nullptr, nullptr, nullptr, NCTX, 2048, 1024);
  {
    Rope3 r;
    r.j[0] = {(u16*)(ws + OFF_CAQ),  QR, 1024, 0,    LQ, NTOK, 0, QSCALE};
    r.j[1] = {(u16*)(ws + OFF_CAKV), KR, 2048, 0,    LC, NCTX, 0, 1.0f};
    r.j[2] = {(u16*)(ws + OFF_CAKV), VT, 2048, 1024, LC, NCTX, 1, 1.0f};
    rope3<<<dim3(NTOK, 3), dim3(128), 0, stream>>>(r, tcos, tsin);
  }
  flash_attn2<0><<<dim3(512), dim3(256), 0, stream>>>(QR, KR, VT, AO, LQ, LC);
  gemm2<EPI_RESID><<<dim3(1024 / 128, NTOK / 128), dim3(512), 0, stream>>>(
      AO, (u16*)(ws + OFF_WCAP), ca_pb, nullptr, out, out, g_ca, NTOK, 1024, 1024);

  // ---- MLP (fp8 MX path) ----
  cvt_fp8<<<dim3(8192), dim3(256), 0, stream>>>(fc1w, fc2w, W8FC1, W8FC2);
  ln_fp8<<<dim3(NTOK), dim3(256), 0, stream>>>(out, n3w, n3b, H8);
  gemm8<E8_GELU><<<dim3(4096 / 128, NTOK / 128), dim3(256), 0, stream>>>(
      H8, W8FC1, fc1b, U8, nullptr, nullptr, nullptr, NTOK, 4096, 1024);
  gemm8<E8_RESID><<<dim3(1024 / 128, NTOK / 128), dim3(256), 0, stream>>>(
      U8, W8FC2, fc2b, nullptr, out, out, g_mlp, NTOK, 1024, 4096);
}

// Round 13
// 369.205 us; speedup vs baseline: 1.2149x; 1.0294x over previous
//
#include <hip/hip_runtime.h>
#include <math.h>

#if !__has_builtin(__builtin_amdgcn_cvt_pk_fp8_f32)
#include <hip/hip_fp8.h>
#endif

typedef __attribute__((ext_vector_type(8))) short short8;
typedef __attribute__((ext_vector_type(4))) float f32x4;
typedef __attribute__((ext_vector_type(16))) float f32x16;
typedef unsigned char u8;
typedef unsigned short u16;
typedef unsigned int u32;
typedef __attribute__((ext_vector_type(2))) u32 u32x2;
typedef __attribute__((ext_vector_type(4))) u32 u32x4;
typedef __attribute__((ext_vector_type(8))) int i32x8;
typedef unsigned long long u64;

static constexpr int E = 1024, H = 16, LQ = 1024, LC = 512, Bn = 4, FF = 4096;
static constexpr int NTOK = Bn * LQ;   // 4096
static constexpr int NCTX = Bn * LC;   // 2048

// Q pre-scale: 1/sqrt(64) * log2(e)  (softmax runs in exp2 domain)
#define QSCALE 0.1803368801111244f
#define DEFER_THR 11.5f

// ---------------- workspace layout (bytes) ----------------
static constexpr size_t OFF_TCOS   = 0;                                    // 1024*32 f32
static constexpr size_t OFF_TSIN   = OFF_TCOS + (size_t)LQ*32*4;
static constexpr size_t OFF_BSAQKV = OFF_TSIN + (size_t)LQ*32*4;           // 3072 f32 (+ca_k/v bias after)
static constexpr size_t OFF_BCAKV  = OFF_BSAQKV + 16384;                   // 2048 f32
// contiguous bf16 weight region (order matters for cvt_all):
static constexpr size_t OFF_WSAQKV = OFF_BCAKV + 16384;                    // [3072][1024] bf16 (UNUSED now)
static constexpr size_t OFF_WSAP   = OFF_WSAQKV + (size_t)3072*1024*2;     // [1024][1024]
static constexpr size_t OFF_WCAQ   = OFF_WSAP   + (size_t)1024*1024*2;
static constexpr size_t OFF_WCAKV  = OFF_WCAQ   + (size_t)1024*1024*2;     // [2048][1024]
static constexpr size_t OFF_WCAP   = OFF_WCAKV  + (size_t)2048*1024*2;
static constexpr size_t OFF_WFC1   = OFF_WCAP   + (size_t)1024*1024*2;     // fp8 region: W8QKV(3M)+W8FC1(4M)+W8FC2(4M)
static constexpr size_t OFF_WFC2   = OFF_WFC1   + (size_t)4096*1024*2;
static constexpr size_t OFF_CTXB   = OFF_WFC2   + (size_t)1024*4096*2;     // [2048][1024] bf16
static constexpr size_t OFF_H      = OFF_CTXB   + (size_t)2048*1024*2;     // [4096][1024] bf16 (LN out) / fp8 ln1,ln3
static constexpr size_t OFF_QKV    = OFF_H      + (size_t)4096*1024*2;     // [4096][3072] bf16
static constexpr size_t OFF_CAQ    = OFF_QKV;                              // [4096][1024]
static constexpr size_t OFF_CAKV   = OFF_QKV + (size_t)4096*1024*2;        // [2048][2048]
static constexpr size_t OFF_QR     = OFF_QKV + (size_t)4096*3072*2;        // [B,H,LQ,64]
static constexpr size_t OFF_KR     = OFF_QR  + (size_t)4096*1024*2;        // [B,H,Lk,64]
static constexpr size_t OFF_VT     = OFF_KR  + (size_t)4096*1024*2;        // [B,H,64,Lk]
static constexpr size_t OFF_AO     = OFF_VT  + (size_t)4096*1024*2;        // [4096][1024] bf16
static constexpr size_t OFF_U      = OFF_QKV;                              // fc1 out [4096][4096] fp8 reuses QKV
static constexpr size_t WS_NEED    = OFF_AO + (size_t)4096*1024*2;         // ~105 MB

// fp8 weight sub-layout inside OFF_WFC1 (16 MB region)
static constexpr size_t OFF_W8QKV = OFF_WFC1;                              // [3072][1024] u8
static constexpr size_t OFF_W8FC1 = OFF_W8QKV + (size_t)3072*1024;         // [4096][1024] u8
static constexpr size_t OFF_W8FC2 = OFF_W8FC1 + (size_t)4096*1024;         // [1024][4096] u8

// ---------------- helpers ----------------
static __device__ __forceinline__ float bf2f(u16 u) {
  union { u32 i; float f; } un; un.i = ((u32)u) << 16; return un.f;
}
static __device__ __forceinline__ u16 f2bf(float f) {  // RNE
  union { float f; u32 u; } un; un.f = f;
  u32 u = un.u;
  return (u16)((u + 0x7FFFu + ((u >> 16) & 1u)) >> 16);
}
static __device__ __forceinline__ u64 pack4(u16 a, u16 b, u16 c, u16 d) {
  return (u64)a | ((u64)b << 16) | ((u64)c << 32) | ((u64)d << 48);
}
static __device__ __forceinline__ f32x4 mfma16(short8 a, short8 b, f32x4 c) {
  return __builtin_amdgcn_mfma_f32_16x16x32_bf16(a, b, c, 0, 0, 0);
}
static __device__ __forceinline__ f32x16 mfma32(short8 a, short8 b, f32x16 c) {
  return __builtin_amdgcn_mfma_f32_32x32x16_bf16(a, b, c, 0, 0, 0);
}
static __device__ __forceinline__ void gload_lds16(void* lds, const void* g) {
  __builtin_amdgcn_global_load_lds(
      (const __attribute__((address_space(1))) void*)g,
      (__attribute__((address_space(3))) void*)lds, 16, 0, 0);
}
// gelu(x) = 0.5x(1+tanh(z)) = x*e/(e+1), e=exp(2*0.79788456(x+0.044715x^3)).
static __device__ __forceinline__ float gelu_tanh(float x) {
  float z2 = 1.5957691216057308f * (x + 0.044715f * x * x * x);
  float e = __expf(z2);
  float r = __builtin_amdgcn_rcpf(e + 1.0f);
  return x - x * r;   // x*(1 - 1/(e+1)) = x*e/(e+1)
}
static __device__ __forceinline__ u32 cvtpk_bf16(float lo, float hi) {
  u32 r;
  asm("v_cvt_pk_bf16_f32 %0, %1, %2" : "=v"(r) : "v"(lo), "v"(hi));
  return r;
}
// fp32 -> OCP e4m3 (saturating)
static __device__ __forceinline__ u32 pack_fp8x4(float a, float b, float c, float d) {
#if __has_builtin(__builtin_amdgcn_cvt_pk_fp8_f32)
  u32 r = (u32)__builtin_amdgcn_cvt_pk_fp8_f32(a, b, 0, false);
  r = (u32)__builtin_amdgcn_cvt_pk_fp8_f32(c, d, (int)r, true);
  return r;
#else
  __hip_fp8_e4m3 qa(a), qb(b), qc(c), qd(d);
  return (u32)qa.__x | ((u32)qb.__x << 8) | ((u32)qc.__x << 16) | ((u32)qd.__x << 24);
#endif
}
static __device__ __forceinline__ u8 fp8b(float f) {
#if __has_builtin(__builtin_amdgcn_cvt_pk_fp8_f32)
  return (u8)((u32)__builtin_amdgcn_cvt_pk_fp8_f32(f, f, 0, false) & 0xFFu);
#else
  __hip_fp8_e4m3 t(f); return t.__x;
#endif
}

// ---------------- small kernels ----------------
__global__ __launch_bounds__(256) void build_tab(float* __restrict__ ct, float* __restrict__ st) {
  int idx = blockIdx.x * 256 + threadIdx.x;           // 1024*32 entries
  int pos = idx >> 5, i = idx & 31;
  float inv = powf(10000.f, -(float)i * (1.f / 32.f));
  float a = (float)pos * inv;
  ct[idx] = cosf(a);
  st[idx] = sinf(a);
}

// fused fp32->bf16 conversion of weights + context (segments 0-2 = sa_q/k/v
// and 8,9 = fc1w/fc2w now fp8 -> early-exit).
struct Cvt11 { const float* s[11]; };
__global__ __launch_bounds__(256) void cvt_all(Cvt11 a, u16* __restrict__ dst) {
  u32 gid = blockIdx.x * 256 + threadIdx.x;   // 0 .. 4718591
  u32 s, off;
  if (gid < 2097152u)      { s = gid >> 18; if (s < 3) return;     off = gid & 262143u; }
  else if (gid < 4194304u) { return; }        // fc1w/fc2w handled in fp8
  else                     { s = 10;                               off = gid - 4194304u; }
  float4 v = *(const float4*)(a.s[s] + (size_t)off * 4);
  *(u64*)(dst + (size_t)gid * 4) = pack4(f2bf(v.x), f2bf(v.y), f2bf(v.z), f2bf(v.w));
}

// sa_q/k/v + fc1w + fc2w -> fp8 e4m3 scaled x256. 11 segments of 1M elems.
__global__ __launch_bounds__(256) void cvt_fp8b(const float* __restrict__ qw, const float* __restrict__ kw,
                                                const float* __restrict__ vw, const float* __restrict__ f1,
                                                const float* __restrict__ f2,
                                                u8* __restrict__ d_qkv, u8* __restrict__ d_f1,
                                                u8* __restrict__ d_f2) {
  u32 gid = blockIdx.x * 256 + threadIdx.x;   // 0 .. 2883583 (11 * 262144), 4 elems each
  u32 seg = gid >> 18, off = gid & 262143u;
  const float* s; u8* d;
  if (seg < 3)      { s = seg == 0 ? qw : (seg == 1 ? kw : vw); d = d_qkv + (size_t)seg * 1048576; }
  else if (seg < 7) { s = f1 + (size_t)(seg - 3) * 1048576;     d = d_f1  + (size_t)(seg - 3) * 1048576; }
  else              { s = f2 + (size_t)(seg - 7) * 1048576;     d = d_f2  + (size_t)(seg - 7) * 1048576; }
  float4 v = *(const float4*)(s + (size_t)off * 4);
  *(u32*)(d + (size_t)off * 4) =
      pack_fp8x4(v.x * 256.f, v.y * 256.f, v.z * 256.f, v.w * 256.f);
}

// fused bias copies: sa_q,sa_k,sa_v -> BSAQKV(+0,+1024,+2048); ca_k,ca_v -> BCAKV(+0,+1024)
struct Cp5 { const float* s[5]; };
__global__ __launch_bounds__(256) void copy5(Cp5 a, float* __restrict__ dst) {
  int gid = blockIdx.x * 256 + threadIdx.x;   // 0..5119
  int s = gid >> 10, off = gid & 1023;
  int doff = (s < 3) ? s * 1024 : 4096 + (s - 3) * 1024;
  dst[doff + off] = a.s[s][off];
}

// out[row][c] += gate[c]*bias[c]  (init pass for split-K atomic GEMM)
__global__ __launch_bounds__(256) void init_bias_gate(float* __restrict__ out, const float* __restrict__ bias,
                                                      const float* __restrict__ gate) {
  int i = (blockIdx.x * 256 + threadIdx.x) * 4;
  int c = i & 1023;
  float4 o = *(float4*)(out + i);
  o.x += gate[c] * bias[c];
  o.y += gate[c + 1] * bias[c + 1];
  o.z += gate[c + 2] * bias[c + 2];
  o.w += gate[c + 3] * bias[c + 3];
  *(float4*)(out + i) = o;
}

// LN over last dim 1024, one row per block, bf16 out.
__global__ __launch_bounds__(256) void ln_bf16(const float* __restrict__ x, const float* __restrict__ w,
                                               const float* __restrict__ b, u16* __restrict__ out) {
  __shared__ float red[4];
  int row = blockIdx.x, tid = threadIdx.x;
  const float* xr = x + (size_t)row * 1024;
  float4 v = ((const float4*)xr)[tid];
  float s = v.x + v.y + v.z + v.w;
#pragma unroll
  for (int off = 32; off; off >>= 1) s += __shfl_xor(s, off);
  if ((tid & 63) == 0) red[tid >> 6] = s;
  __syncthreads();
  float mean = (red[0] + red[1] + red[2] + red[3]) * (1.f / 1024.f);
  float dx = v.x - mean, dy = v.y - mean, dz = v.z - mean, dw = v.w - mean;
  float sq = dx * dx + dy * dy + dz * dz + dw * dw;
#pragma unroll
  for (int off = 32; off; off >>= 1) sq += __shfl_xor(sq, off);
  __syncthreads();
  if ((tid & 63) == 0) red[tid >> 6] = sq;
  __syncthreads();
  float var = (red[0] + red[1] + red[2] + red[3]) * (1.f / 1024.f);
  float rstd = rsqrtf(var + 1e-6f);
  float4 wv = ((const float4*)w)[tid];
  float4 bv = ((const float4*)b)[tid];
  u64 o = pack4(f2bf(dx * rstd * wv.x + bv.x), f2bf(dy * rstd * wv.y + bv.y),
                f2bf(dz * rstd * wv.z + bv.z), f2bf(dw * rstd * wv.w + bv.w));
  *(u64*)(out + (size_t)row * 1024 + tid * 4) = o;
}

// LN -> fp8 e4m3 scaled x16 (for fp8 GEMM activations)
__global__ __launch_bounds__(256) void ln_fp8(const float* __restrict__ x, const float* __restrict__ w,
                                              const float* __restrict__ b, u8* __restrict__ out) {
  __shared__ float red[4];
  int row = blockIdx.x, tid = threadIdx.x;
  const float* xr = x + (size_t)row * 1024;
  float4 v = ((const float4*)xr)[tid];
  float s = v.x + v.y + v.z + v.w;
#pragma unroll
  for (int off = 32; off; off >>= 1) s += __shfl_xor(s, off);
  if ((tid & 63) == 0) red[tid >> 6] = s;
  __syncthreads();
  float mean = (red[0] + red[1] + red[2] + red[3]) * (1.f / 1024.f);
  float dx = v.x - mean, dy = v.y - mean, dz = v.z - mean, dw = v.w - mean;
  float sq = dx * dx + dy * dy + dz * dz + dw * dw;
#pragma unroll
  for (int off = 32; off; off >>= 1) sq += __shfl_xor(sq, off);
  __syncthreads();
  if ((tid & 63) == 0) red[tid >> 6] = sq;
  __syncthreads();
  float var = (red[0] + red[1] + red[2] + red[3]) * (1.f / 1024.f);
  float rstd = rsqrtf(var + 1e-6f);
  float4 wv = ((const float4*)w)[tid];
  float4 bv = ((const float4*)b)[tid];
  u32 pk = pack_fp8x4((dx * rstd * wv.x + bv.x) * 16.f, (dy * rstd * wv.y + bv.y) * 16.f,
                      (dz * rstd * wv.z + bv.z) * 16.f, (dw * rstd * wv.w + bv.w) * 16.f);
  *(u32*)(out + (size_t)row * 1024 + tid * 4) = pk;
}

// Fused RoPE/scatter: 3 jobs in one dispatch (blockIdx.y selects job).
struct RopeJob { const u16* src; u16* dst; int ld, col0, Lper, T, mode; float scale; };
struct Rope3 { RopeJob j[3]; };
__global__ __launch_bounds__(128) void rope3(Rope3 a, const float* __restrict__ cosT,
                                             const float* __restrict__ sinT) {
  RopeJob jb = a.j[blockIdx.y];
  int t = blockIdx.x;
  if (t >= jb.T) return;
  int b = t / jb.Lper, l = t - b * jb.Lper;
  int tid = threadIdx.x;
  int e0 = tid * 8;
  int h = e0 >> 6, d0 = e0 & 63;
  short8 vv = *(const short8*)(jb.src + (size_t)t * jb.ld + jb.col0 + e0);
  if (jb.mode == 0) {
    short8 ov;
#pragma unroll
    for (int j = 0; j < 4; ++j) {
      float x1 = bf2f((u16)vv[2 * j]);
      float x2 = bf2f((u16)vv[2 * j + 1]);
      int i = (d0 >> 1) + j;
      float c = cosT[l * 32 + i], s = sinT[l * 32 + i];
      ov[2 * j]     = (short)f2bf((x1 * c - x2 * s) * jb.scale);
      ov[2 * j + 1] = (short)f2bf((x1 * s + x2 * c) * jb.scale);
    }
    *(short8*)(jb.dst + (((size_t)b * H + h) * jb.Lper + l) * 64 + d0) = ov;
  } else {
#pragma unroll
    for (int m = 0; m < 8; ++m)
      jb.dst[(((size_t)b * H + h) * 64 + d0 + m) * jb.Lper + l] = (u16)vv[m];
  }
}

// ---------------- bf16 GEMM (proven R8 config): C = A @ W^T + bias ----------------
enum { EPI_BF16 = 0, EPI_GELU = 1, EPI_RESID = 2 };

template <int EPI>
__global__ __launch_bounds__(512, 4) void gemm2(const u16* __restrict__ A, const u16* __restrict__ W,
                                                const float* __restrict__ bias, u16* outb, float* outf,
                                                const float* res, const float* __restrict__ gate,
                                                int M, int N, int K) {
  __shared__ u16 As[2][128 * 64];
  __shared__ u16 Bs[2][128 * 64];

  int nwg = gridDim.x * gridDim.y;
  int bid = blockIdx.y * gridDim.x + blockIdx.x;
  int cpx = nwg >> 3;
  int swz = (bid & 7) * cpx + (bid >> 3);
  int bx = swz % gridDim.x;
  int by = swz / gridDim.x;
  int row0 = by * 128, col0 = bx * 128;

  int tid = threadIdx.x;
  int lane = tid & 63, wid = tid >> 6;
  int wr = wid >> 2, wc = wid & 3;  // 2x4 waves, each owns 64x32
  int lr = lane & 15, lg = lane >> 4;

  size_t a_off0, a_off1, b_off0, b_off1;
  int l_off0 = tid * 8, l_off1 = (512 + tid) * 8;
  {
    int q = tid, r = q >> 3, p = q & 7, sp = p ^ (r & 7);
    a_off0 = (size_t)(row0 + r) * K + sp * 8;
    b_off0 = (size_t)(col0 + r) * K + sp * 8;
    q = 512 + tid; r = q >> 3; p = q & 7; sp = p ^ (r & 7);
    a_off1 = (size_t)(row0 + r) * K + sp * 8;
    b_off1 = (size_t)(col0 + r) * K + sp * 8;
  }

  f32x4 acc[4][2] = {};

  const int nkt = K >> 6;
  {
    gload_lds16(&As[0][l_off0], A + a_off0);
    gload_lds16(&Bs[0][l_off0], W + b_off0);
    gload_lds16(&As[0][l_off1], A + a_off1);
    gload_lds16(&Bs[0][l_off1], W + b_off1);
  }
  __syncthreads();

  for (int kt = 0; kt < nkt; ++kt) {
    int cur = kt & 1;
    if (kt + 1 < nkt) {
      int k0 = (kt + 1) << 6;
      gload_lds16(&As[cur ^ 1][l_off0], A + a_off0 + k0);
      gload_lds16(&Bs[cur ^ 1][l_off0], W + b_off0 + k0);
      gload_lds16(&As[cur ^ 1][l_off1], A + a_off1 + k0);
      gload_lds16(&Bs[cur ^ 1][l_off1], W + b_off1 + k0);
    }
#pragma unroll
    for (int kk = 0; kk < 2; ++kk) {
      short8 af[4], bfr[2];
#pragma unroll
      for (int m = 0; m < 4; ++m) {
        int r = wr * 64 + m * 16 + lr;
        int sc = (kk * 4 + lg) ^ (r & 7);
        af[m] = *(const short8*)(&As[cur][r * 64 + sc * 8]);
      }
#pragma unroll
      for (int n = 0; n < 2; ++n) {
        int r = wc * 32 + n * 16 + lr;
        int sc = (kk * 4 + lg) ^ (r & 7);
        bfr[n] = *(const short8*)(&Bs[cur][r * 64 + sc * 8]);
      }
#pragma unroll
      for (int m = 0; m < 4; ++m)
#pragma unroll
        for (int n = 0; n < 2; ++n)
          acc[m][n] = mfma16(af[m], bfr[n], acc[m][n]);
    }
    __syncthreads();
  }

  if (EPI == EPI_BF16 || EPI == EPI_GELU) {
    u16* Ct = &As[0][0];
#pragma unroll
    for (int n = 0; n < 2; ++n) {
      int c = wc * 32 + n * 16 + lr;
      float bv = bias[col0 + c];
#pragma unroll
      for (int m = 0; m < 4; ++m) {
#pragma unroll
        for (int i = 0; i < 4; ++i) {
          int r = wr * 64 + m * 16 + lg * 4 + i;
          float v = acc[m][n][i] + bv;
          Ct[r * 128 + c] = f2bf(EPI == EPI_GELU ? gelu_tanh(v) : v);
        }
      }
    }
    __syncthreads();
#pragma unroll
    for (int j = 0; j < 4; ++j) {
      u32 q = (u32)tid + j * 512;
      u32 r = q >> 4, ck = q & 15;
      short8 v = *(const short8*)(Ct + r * 128 + ck * 8);
      *(short8*)(outb + (size_t)(row0 + r) * N + col0 + ck * 8) = v;
    }
  } else {
#pragma unroll
    for (int n = 0; n < 2; ++n) {
      int cg = col0 + wc * 32 + n * 16 + lr;
      float bv = bias[cg];
#pragma unroll
      for (int m = 0; m < 4; ++m) {
#pragma unroll
        for (int i = 0; i < 4; ++i) {
          int rg = row0 + wr * 64 + m * 16 + lg * 4 + i;
          float v = acc[m][n][i] + bv;
          float r = res[(size_t)rg * N + cg];
          outf[(size_t)rg * N + cg] = r + gate[cg] * v;
        }
      }
    }
  }
}

// ---------------- fp8 MX GEMM: C = (A/16) @ (W/256)^T -> acc/4096 ----------------
// 128x128 tile, BK=128, 256 threads (2x2 waves of 64x64 = 4x4 16x16-frags),
// dbuf LDS, gemm2 pipeline, mfma_scale_f32_16x16x128_f8f6f4 unity scales.
enum { E8_BF16 = 0, E8_GELU = 1, E8_ATOMIC = 2 };

template <int EPI>
__global__ __launch_bounds__(256, 2) void gemm8(const u8* __restrict__ A, const u8* __restrict__ W,
                                                const float* __restrict__ bias, u16* outb16,
                                                u8* outb8, float* outf, const float* __restrict__ gate,
                                                int M, int N, int K, int kchunks) {
  __shared__ u8 As[2][128 * 128];
  __shared__ u8 Bs[2][128 * 128];

  int nwg = gridDim.x * gridDim.y;
  int bid = blockIdx.y * gridDim.x + blockIdx.x;
  int cpx = nwg >> 3;
  int swz = (bid & 7) * cpx + (bid >> 3);
  int bx = swz % gridDim.x, by = swz / gridDim.x;
  int row0 = by * 128, col0 = bx * 128;

  const int Kc = K / kchunks;
  const int kbase = blockIdx.z * Kc;

  int tid = threadIdx.x;
  int lane = tid & 63, wid = tid >> 6;
  int wr = wid >> 1, wc = wid & 1;      // 2x2 waves, each owns 64x64
  int lr = lane & 15, lg = lane >> 4;

  // staging: tile = 128 rows x 128 B = 1024 chunks of 16 B; 4 per thread per matrix.
  u32 aoff[4], boff[4];
  int ldso[4];
#pragma unroll
  for (int j = 0; j < 4; ++j) {
    int q = tid + j * 256;
    int r = q >> 3, p = q & 7, sp = p ^ (r & 7);
    aoff[j] = (u32)(row0 + r) * (u32)K + sp * 16;
    boff[j] = (u32)(col0 + r) * (u32)K + sp * 16;
    ldso[j] = q * 16;
  }

  f32x4 acc[4][4] = {};
  const int nkt = Kc >> 7;              // BK = 128

  // 16x16x128 fragment: lane (lr,lg) reads row r=base+frag*16+lr,
  // k-bytes lg*32..lg*32+31 = slots lg*2, lg*2+1 (XOR-swizzled).
  auto rdfrag = [&](const u8* base, int r, i32x8& f) {
    const u8* rp = base + r * 128;
    int ck = lg * 2;
    u32x4 lo = *(const u32x4*)(rp + ((ck) ^ (r & 7)) * 16);
    u32x4 hh = *(const u32x4*)(rp + ((ck + 1) ^ (r & 7)) * 16);
    i32x8 v;
    v[0] = (int)lo[0]; v[1] = (int)lo[1]; v[2] = (int)lo[2]; v[3] = (int)lo[3];
    v[4] = (int)hh[0]; v[5] = (int)hh[1]; v[6] = (int)hh[2]; v[7] = (int)hh[3];
    f = v;
  };

  // prologue
#pragma unroll
  for (int j = 0; j < 4; ++j) {
    gload_lds16(&As[0][ldso[j]], A + aoff[j] + kbase);
    gload_lds16(&Bs[0][ldso[j]], W + boff[j] + kbase);
  }
  __syncthreads();

  for (int kt = 0; kt < nkt; ++kt) {
    int cur = kt & 1;
    if (kt + 1 < nkt) {
      int k0 = kbase + ((kt + 1) << 7);
#pragma unroll
      for (int j = 0; j < 4; ++j) {
        gload_lds16(&As[cur ^ 1][ldso[j]], A + aoff[j] + k0);
        gload_lds16(&Bs[cur ^ 1][ldso[j]], W + boff[j] + k0);
      }
    }
    i32x8 a[4], b[4];
#pragma unroll
    for (int m = 0; m < 4; ++m) rdfrag(&As[cur][0], wr * 64 + m * 16 + lr, a[m]);
#pragma unroll
    for (int n = 0; n < 4; ++n) rdfrag(&Bs[cur][0], wc * 64 + n * 16 + lr, b[n]);
    __builtin_amdgcn_s_setprio(1);
#pragma unroll
    for (int m = 0; m < 4; ++m)
#pragma unroll
      for (int n = 0; n < 4; ++n)
        acc[m][n] = __builtin_amdgcn_mfma_scale_f32_16x16x128_f8f6f4(
            a[m], b[n], acc[m][n], 0, 0, 0, 0x7F7F7F7F, 0, 0x7F7F7F7F);
    __builtin_amdgcn_s_setprio(0);
    __syncthreads();
  }

  // epilogue: C layout col=lane&15, row=(lane>>4)*4+i (dtype-independent)
  constexpr float SCL = 1.f / 4096.f;   // undo x16 (act) * x256 (weights)
  if (EPI == E8_BF16) {
    u16* Ct = (u16*)&As[0][0];          // [128][128] u16 = 32 KiB (both As bufs)
#pragma unroll
    for (int n = 0; n < 4; ++n) {
      int cl = wc * 64 + n * 16 + lr;
      float bv = bias[col0 + cl];
#pragma unroll
      for (int m = 0; m < 4; ++m) {
#pragma unroll
        for (int i = 0; i < 4; ++i) {
          int rl = wr * 64 + m * 16 + lg * 4 + i;
          Ct[rl * 128 + cl] = f2bf(acc[m][n][i] * SCL + bv);
        }
      }
    }
    __syncthreads();
#pragma unroll
    for (int j = 0; j < 8; ++j) {
      u32 q = (u32)tid + j * 256;
      u32 r = q >> 4, ck = q & 15;
      short8 v = *(const short8*)(Ct + r * 128 + ck * 8);
      *(short8*)(outb16 + (size_t)(row0 + r) * N + col0 + ck * 8) = v;
    }
  } else if (EPI == E8_GELU) {
    u8* Ct = &As[0][0];                 // [128][128] u8 = 16 KiB
#pragma unroll
    for (int n = 0; n < 4; ++n) {
      int cl = wc * 64 + n * 16 + lr;
      float bv = bias[col0 + cl];
#pragma unroll
      for (int m = 0; m < 4; ++m) {
#pragma unroll
        for (int i = 0; i < 4; ++i) {
          int rl = wr * 64 + m * 16 + lg * 4 + i;
          float v = acc[m][n][i] * SCL + bv;
          Ct[rl * 128 + cl] = fp8b(gelu_tanh(v) * 16.f);
        }
      }
    }
    __syncthreads();
#pragma unroll
    for (int j = 0; j < 4; ++j) {
      int q = tid + j * 256;
      int r = q >> 3, ck = q & 7;
      *(u32x4*)(outb8 + (size_t)(row0 + r) * N + col0 + ck * 16) =
          *(const u32x4*)(Ct + r * 128 + ck * 16);
    }
  } else {  // E8_ATOMIC: bias+gate pre-applied by init_bias_gate
#pragma unroll
    for (int n = 0; n < 4; ++n) {
      int cg = col0 + wc * 64 + n * 16 + lr;
      float gv = gate[cg];
#pragma unroll
      for (int m = 0; m < 4; ++m) {
#pragma unroll
        for (int i = 0; i < 4; ++i) {
          int rg = row0 + wr * 64 + m * 16 + lg * 4 + i;
          atomicAdd(&outf[(size_t)rg * N + cg], gv * (acc[m][n][i] * SCL));
        }
      }
    }
  }
}

// ---------------- flash attention, swapped-QK^T, register-pipelined K/V ----------------
template <int MASKED, int PRE>
static __device__ __forceinline__ void attn_tile3(short8* kf, const u16* KtNext,
                                                  const u16* Vp0, const u16* Vp1,
                                                  const short8* qf, int kb, int q0, int l31, int hi,
                                                  float& m, float& lsum, f32x16& o0, f32x16& o1) {
  // 1) V loads for THIS tile — independent, issue first
  short8 vf0[4], vf1[4];
#pragma unroll
  for (int ks = 0; ks < 4; ++ks) {
    vf0[ks] = *(const short8*)(Vp0 + ks * 16 + hi * 8);
    vf1[ks] = *(const short8*)(Vp1 + ks * 16 + hi * 8);
  }
  // 2) QK^T from pre-loaded K registers
  f32x16 s0 = {}, s1 = {};
  __builtin_amdgcn_s_setprio(1);
#pragma unroll
  for (int s = 0; s < 4; ++s) {
    s0 = mfma32(kf[s], qf[s], s0);       // S^T[k][q]
    s1 = mfma32(kf[4 + s], qf[s], s1);
  }
  __builtin_amdgcn_s_setprio(0);
  // 3) prefetch next tile's K into kf (dead after QK^T)
  if (PRE) {
    const u16* kp0 = KtNext + (size_t)l31 * 64 + hi * 8;
    const u16* kp1 = KtNext + (size_t)(32 + l31) * 64 + hi * 8;
#pragma unroll
    for (int s = 0; s < 4; ++s) {
      kf[s] = *(const short8*)(kp0 + s * 16);
      kf[4 + s] = *(const short8*)(kp1 + s * 16);
    }
  }
  if (MASKED) {
    int qg = q0 + l31;
#pragma unroll
    for (int r = 0; r < 16; ++r) {
      int kk = kb + (r & 3) + 8 * (r >> 2) + 4 * hi;
      if (kk > qg) s0[r] = -INFINITY;
      if (kk + 32 > qg) s1[r] = -INFINITY;
    }
  }
  float pm = -INFINITY;
#pragma unroll
  for (int r = 0; r < 16; ++r) pm = fmaxf(pm, fmaxf(s0[r], s1[r]));
  pm = fmaxf(pm, __shfl_xor(pm, 32));
  if (!__all(pm <= m + DEFER_THR)) {
    float mn = fmaxf(m, pm);
    float al = exp2f(m - mn);
    m = mn;
    lsum *= al;
#pragma unroll
    for (int r = 0; r < 16; ++r) {
      float alr = __shfl(al, (r & 3) + 8 * (r >> 2) + 4 * hi);
      o0[r] *= alr;
      o1[r] *= alr;
    }
  }
  float ts = 0.f;
#pragma unroll
  for (int r = 0; r < 16; ++r) {
    float p0 = exp2f(s0[r] - m);
    float p1 = exp2f(s1[r] - m);
    s0[r] = p0; s1[r] = p1;
    ts += p0 + p1;
  }
  ts += __shfl_xor(ts, 32);
  lsum += ts;
  auto pack8 = [&](float a0, float a1, float a2, float a3,
                   float a4, float a5, float a6, float a7) -> short8 {
    u32 c0 = cvtpk_bf16(a0, a1), c1 = cvtpk_bf16(a2, a3);
    u32 c2 = cvtpk_bf16(a4, a5), c3 = cvtpk_bf16(a6, a7);
    u32x2 r02 = __builtin_amdgcn_permlane32_swap(c0, c2, false, false);
    u32x2 r13 = __builtin_amdgcn_permlane32_swap(c1, c3, false, false);
    u32x4 w;
    w[0] = r02[0]; w[1] = r13[0]; w[2] = r02[1]; w[3] = r13[1];
    return __builtin_bit_cast(short8, w);
  };
  short8 pa0 = pack8(s0[0], s0[1], s0[2], s0[3], s0[4], s0[5], s0[6], s0[7]);
  short8 pa1 = pack8(s0[8], s0[9], s0[10], s0[11], s0[12], s0[13], s0[14], s0[15]);
  short8 pa2 = pack8(s1[0], s1[1], s1[2], s1[3], s1[4], s1[5], s1[6], s1[7]);
  short8 pa3 = pack8(s1[8], s1[9], s1[10], s1[11], s1[12], s1[13], s1[14], s1[15]);
  short8 pa[4] = {pa0, pa1, pa2, pa3};
  __builtin_amdgcn_s_setprio(1);
#pragma unroll
  for (int ks = 0; ks < 4; ++ks) {
    o0 = mfma32(pa[ks], vf0[ks], o0);
    o1 = mfma32(pa[ks], vf1[ks], o1);
  }
  __builtin_amdgcn_s_setprio(0);
}

template <int CAUSAL>
__global__ __launch_bounds__(256) void flash_attn2(const u16* __restrict__ Q, const u16* __restrict__ K,
                                                   const u16* __restrict__ Vt, u16* __restrict__ O,
                                                   int Lq, int Lk) {
  const int wid = threadIdx.x >> 6, lane = threadIdx.x & 63;
  const int l31 = lane & 31, hi = lane >> 5;
  int wg = blockIdx.x * 4 + wid;     // 4 independent waves per block, no barriers
  int bh = wg & 63;
  int qc = wg >> 6;
  if (CAUSAL) qc = (Lq >> 5) - 1 - qc;   // heavy q-chunks dispatch first
  int q0 = qc << 5;

  const u16* Qb = Q + ((size_t)bh * Lq + q0) * 64;
  const u16* Kb = K + (size_t)bh * Lk * 64;
  const u16* Vb = Vt + (size_t)bh * 64 * Lk;

  short8 qf[4];
#pragma unroll
  for (int s = 0; s < 4; ++s) qf[s] = *(const short8*)(Qb + (size_t)l31 * 64 + s * 16 + hi * 8);

  f32x16 o0 = {}, o1 = {};
  float m = -INFINITY, lsum = 0.f;

  const u16* Kt = Kb;
  const u16* Vp0 = Vb + (size_t)l31 * Lk;
  const u16* Vp1 = Vb + (size_t)(32 + l31) * Lk;

  // preload K tile 0 into registers
  short8 kf[8];
  {
    const u16* kp0 = Kt + (size_t)l31 * 64 + hi * 8;
    const u16* kp1 = Kt + (size_t)(32 + l31) * 64 + hi * 8;
#pragma unroll
    for (int s = 0; s < 4; ++s) {
      kf[s] = *(const short8*)(kp0 + s * 16);
      kf[4 + s] = *(const short8*)(kp1 + s * 16);
    }
  }

  int nt = CAUSAL ? ((q0 >> 6) + 1) : (Lk >> 6);
  for (int t = 0; t < nt - 1; ++t) {
    attn_tile3<0, 1>(kf, Kt + 64 * 64, Vp0, Vp1, qf, t * 64, q0, l31, hi, m, lsum, o0, o1);
    Kt += 64 * 64; Vp0 += 64; Vp1 += 64;
  }
  if (CAUSAL)
    attn_tile3<1, 0>(kf, nullptr, Vp0, Vp1, qf, (nt - 1) * 64, q0, l31, hi, m, lsum, o0, o1);
  else
    attn_tile3<0, 0>(kf, nullptr, Vp0, Vp1, qf, (nt - 1) * 64, q0, l31, hi, m, lsum, o0, o1);

  float myinv = 1.f / lsum;
  int b = bh >> 4, h = bh & 15;
#pragma unroll
  for (int r = 0; r < 16; ++r) {
    int cr = (r & 3) + 8 * (r >> 2) + 4 * hi;
    float li = __shfl(myinv, cr);
    u16* op = O + ((size_t)b * Lq + q0 + cr) * 1024 + h * 64;
    op[l31] = f2bf(o0[r] * li);
    op[32 + l31] = f2bf(o1[r] * li);
  }
}

// ---------------- launch ----------------
extern "C" void kernel_launch(void* const* d_in, const int* in_sizes, int n_in,
                              void* d_out, int out_size, void* d_ws, size_t ws_size,
                              hipStream_t stream) {
  (void)in_sizes; (void)n_in; (void)out_size;
  if (ws_size < WS_NEED) return;  // need ~105 MB scratch

  const float* x     = (const float*)d_in[0];
  const float* ctx   = (const float*)d_in[1];
  const float* g_msa = (const float*)d_in[3];
  const float* g_ca  = (const float*)d_in[4];
  const float* g_mlp = (const float*)d_in[5];
  const float* n1w = (const float*)d_in[6],  *n1b = (const float*)d_in[7];
  const float* n2w = (const float*)d_in[8],  *n2b = (const float*)d_in[9];
  const float* n3w = (const float*)d_in[10], *n3b = (const float*)d_in[11];
  const float* sa_qw = (const float*)d_in[12], *sa_kw = (const float*)d_in[14];
  const float* sa_vw = (const float*)d_in[16], *sa_pw = (const float*)d_in[18];
  const float* sa_qb = (const float*)d_in[13], *sa_kb = (const float*)d_in[15];
  const float* sa_vb = (const float*)d_in[17], *sa_pb = (const float*)d_in[19];
  const float* ca_qw = (const float*)d_in[20], *ca_qb = (const float*)d_in[21];
  const float* ca_kw = (const float*)d_in[22], *ca_kb = (const float*)d_in[23];
  const float* ca_vw = (const float*)d_in[24], *ca_vb = (const float*)d_in[25];
  const float* ca_pw = (const float*)d_in[26], *ca_pb = (const float*)d_in[27];
  const float* fc1w = (const float*)d_in[28], *fc1b = (const float*)d_in[29];
  const float* fc2w = (const float*)d_in[30], *fc2b = (const float*)d_in[31];

  char* ws = (char*)d_ws;
  float* out = (float*)d_out;
  float* tcos = (float*)(ws + OFF_TCOS);
  float* tsin = (float*)(ws + OFF_TSIN);
  u16* Hb   = (u16*)(ws + OFF_H);
  u16* QKV  = (u16*)(ws + OFF_QKV);
  u16* QR   = (u16*)(ws + OFF_QR);
  u16* KR   = (u16*)(ws + OFF_KR);
  u16* VT   = (u16*)(ws + OFF_VT);
  u16* AO   = (u16*)(ws + OFF_AO);
  u8*  H8   = (u8*)(ws + OFF_H);        // ln1/ln3 fp8 output
  u8*  U8   = (u8*)(ws + OFF_U);        // fc1 out fp8
  u8*  W8QKV = (u8*)(ws + OFF_W8QKV);
  u8*  W8FC1 = (u8*)(ws + OFF_W8FC1);
  u8*  W8FC2 = (u8*)(ws + OFF_W8FC2);

  // RoPE tables
  build_tab<<<dim3(128), dim3(256), 0, stream>>>(tcos, tsin);

  // weight conversions: bf16 set (sa_p, ca_*, ctx) + fp8 set (sa_q/k/v, fc1, fc2)
  Cvt11 ca;
  ca.s[0] = sa_qw; ca.s[1] = sa_kw; ca.s[2] = sa_vw; ca.s[3] = sa_pw;
  ca.s[4] = ca_qw; ca.s[5] = ca_kw; ca.s[6] = ca_vw; ca.s[7] = ca_pw;
  ca.s[8] = fc1w;  ca.s[9] = fc2w;  ca.s[10] = ctx;
  cvt_all<<<dim3(18432), dim3(256), 0, stream>>>(ca, (u16*)(ws + OFF_WSAQKV));
  cvt_fp8b<<<dim3(11264), dim3(256), 0, stream>>>(sa_qw, sa_kw, sa_vw, fc1w, fc2w,
                                                  W8QKV, W8FC1, W8FC2);
  Cp5 cp;
  cp.s[0] = sa_qb; cp.s[1] = sa_kb; cp.s[2] = sa_vb; cp.s[3] = ca_kb; cp.s[4] = ca_vb;
  copy5<<<dim3(20), dim3(256), 0, stream>>>(cp, (float*)(ws + OFF_BSAQKV));

  // ---- self-attention (QKV in fp8, output bf16) ----
  ln_fp8<<<dim3(NTOK), dim3(256), 0, stream>>>(x, n1w, n1b, H8);
  gemm8<E8_BF16><<<dim3(3072 / 128, NTOK / 128), dim3(256), 0, stream>>>(
      H8, W8QKV, (float*)(ws + OFF_BSAQKV), QKV, nullptr, nullptr, nullptr,
      NTOK, 3072, 1024, 1);
  {
    Rope3 r;
    r.j[0] = {QKV, QR, 3072, 0,    LQ, NTOK, 0, QSCALE};
    r.j[1] = {QKV, KR, 3072, 1024, LQ, NTOK, 0, 1.0f};
    r.j[2] = {QKV, VT, 3072, 2048, LQ, NTOK, 1, 1.0f};
    rope3<<<dim3(NTOK, 3), dim3(128), 0, stream>>>(r, tcos, tsin);
  }
  flash_attn2<1><<<dim3(512), dim3(256), 0, stream>>>(QR, KR, VT, AO, LQ, LQ);
  gemm2<EPI_RESID><<<dim3(1024 / 128, NTOK / 128), dim3(512), 0, stream>>>(
      AO, (u16*)(ws + OFF_WSAP), sa_pb, nullptr, out, x, g_msa, NTOK, 1024, 1024);

  // ---- cross-attention ----
  ln_bf16<<<dim3(NTOK), dim3(256), 0, stream>>>(out, n2w, n2b, Hb);
  gemm2<EPI_BF16><<<dim3(1024 / 128, NTOK / 128), dim3(512), 0, stream>>>(
      Hb, (u16*)(ws + OFF_WCAQ), ca_qb, (u16*)(ws + OFF_CAQ), nullptr, nullptr, nullptr,
      NTOK, 1024, 1024);
  gemm2<EPI_BF16><<<dim3(2048 / 128, NCTX / 128), dim3(512), 0, stream>>>(
      (u16*)(ws + OFF_CTXB), (u16*)(ws + OFF_WCAKV), (float*)(ws + OFF_BCAKV),
      (u16*)(ws + OFF_CAKV), nullptr, nullptr, nullptr, NCTX, 2048, 1024);
  {
    Rope3 r;
    r.j[0] = {(u16*)(ws + OFF_CAQ),  QR, 1024, 0,    LQ, NTOK, 0, QSCALE};
    r.j[1] = {(u16*)(ws + OFF_CAKV), KR, 2048, 0,    LC, NCTX, 0, 1.0f};
    r.j[2] = {(u16*)(ws + OFF_CAKV), VT, 2048, 1024, LC, NCTX, 1, 1.0f};
    rope3<<<dim3(NTOK, 3), dim3(128), 0, stream>>>(r, tcos, tsin);
  }
  flash_attn2<0><<<dim3(512), dim3(256), 0, stream>>>(QR, KR, VT, AO, LQ, LC);
  gemm2<EPI_RESID><<<dim3(1024 / 128, NTOK / 128), dim3(512), 0, stream>>>(
      AO, (u16*)(ws + OFF_WCAP), ca_pb, nullptr, out, out, g_ca, NTOK, 1024, 1024);

  // ---- MLP (fp8 MX path) ----
  ln_fp8<<<dim3(NTOK), dim3(256), 0, stream>>>(out, n3w, n3b, H8);
  gemm8<E8_GELU><<<dim3(4096 / 128, NTOK / 128), dim3(256), 0, stream>>>(
      H8, W8FC1, fc1b, nullptr, U8, nullptr, nullptr, NTOK, 4096, 1024, 1);
  // fc2: split-K x2 atomic (512 blocks = 2/CU, R11-measured best); bias+gate pre-applied
  init_bias_gate<<<dim3(4096), dim3(256), 0, stream>>>(out, fc2b, g_mlp);
  gemm8<E8_ATOMIC><<<dim3(1024 / 128, NTOK / 128, 2), dim3(256), 0, stream>>>(
      U8, W8FC2, nullptr, nullptr, nullptr, out, g_mlp, NTOK, 1024, 4096, 2);
}

// Round 14
// 326.670 us; speedup vs baseline: 1.3731x; 1.1302x over previous
//
#include <hip/hip_runtime.h>
#include <math.h>

#if !__has_builtin(__builtin_amdgcn_cvt_pk_fp8_f32)
#include <hip/hip_fp8.h>
#endif

typedef __attribute__((ext_vector_type(8))) short short8;
typedef __attribute__((ext_vector_type(4))) float f32x4;
typedef __attribute__((ext_vector_type(16))) float f32x16;
typedef unsigned char u8;
typedef unsigned short u16;
typedef unsigned int u32;
typedef __attribute__((ext_vector_type(2))) u32 u32x2;
typedef __attribute__((ext_vector_type(4))) u32 u32x4;
typedef __attribute__((ext_vector_type(8))) int i32x8;
typedef unsigned long long u64;

static constexpr int E = 1024, H = 16, LQ = 1024, LC = 512, Bn = 4, FF = 4096;
static constexpr int NTOK = Bn * LQ;   // 4096
static constexpr int NCTX = Bn * LC;   // 2048

// Q pre-scale: 1/sqrt(64) * log2(e)  (softmax runs in exp2 domain)
#define QSCALE 0.1803368801111244f
#define DEFER_THR 11.5f

// ---------------- workspace layout (bytes) ----------------
static constexpr size_t OFF_TCOS   = 0;                                    // 1024*32 f32
static constexpr size_t OFF_TSIN   = OFF_TCOS + (size_t)LQ*32*4;
static constexpr size_t OFF_BSAQKV = OFF_TSIN + (size_t)LQ*32*4;           // 3072 f32 (+ca_k/v bias after)
static constexpr size_t OFF_BCAKV  = OFF_BSAQKV + 16384;                   // 2048 f32
// contiguous bf16 weight region (order matters for cvt_all):
static constexpr size_t OFF_WSAQKV = OFF_BCAKV + 16384;                    // [3072][1024] bf16 (UNUSED now)
static constexpr size_t OFF_WSAP   = OFF_WSAQKV + (size_t)3072*1024*2;     // [1024][1024]
static constexpr size_t OFF_WCAQ   = OFF_WSAP   + (size_t)1024*1024*2;
static constexpr size_t OFF_WCAKV  = OFF_WCAQ   + (size_t)1024*1024*2;     // [2048][1024]
static constexpr size_t OFF_WCAP   = OFF_WCAKV  + (size_t)2048*1024*2;
static constexpr size_t OFF_WFC1   = OFF_WCAP   + (size_t)1024*1024*2;     // fp8 region: W8QKV(3M)+W8FC1(4M)+W8FC2(4M)
static constexpr size_t OFF_WFC2   = OFF_WFC1   + (size_t)4096*1024*2;
static constexpr size_t OFF_CTXB   = OFF_WFC2   + (size_t)1024*4096*2;     // [2048][1024] bf16
static constexpr size_t OFF_H      = OFF_CTXB   + (size_t)2048*1024*2;     // [4096][1024] bf16 (LN out) / fp8 ln1,ln3
static constexpr size_t OFF_QKV    = OFF_H      + (size_t)4096*1024*2;     // [4096][3072] bf16
static constexpr size_t OFF_CAQ    = OFF_QKV;                              // [4096][1024]
static constexpr size_t OFF_CAKV   = OFF_QKV + (size_t)4096*1024*2;        // [2048][2048]
static constexpr size_t OFF_QR     = OFF_QKV + (size_t)4096*3072*2;        // [B,H,LQ,64]
static constexpr size_t OFF_KR     = OFF_QR  + (size_t)4096*1024*2;        // [B,H,Lk,64]
static constexpr size_t OFF_VT     = OFF_KR  + (size_t)4096*1024*2;        // [B,H,64,Lk]
static constexpr size_t OFF_AO     = OFF_VT  + (size_t)4096*1024*2;        // [4096][1024] bf16
static constexpr size_t OFF_U      = OFF_QKV;                              // fc1 out [4096][4096] fp8 reuses QKV
static constexpr size_t WS_NEED    = OFF_AO + (size_t)4096*1024*2;         // ~105 MB

// fp8 weight sub-layout inside OFF_WFC1 (16 MB region)
static constexpr size_t OFF_W8QKV = OFF_WFC1;                              // [3072][1024] u8
static constexpr size_t OFF_W8FC1 = OFF_W8QKV + (size_t)3072*1024;         // [4096][1024] u8
static constexpr size_t OFF_W8FC2 = OFF_W8FC1 + (size_t)4096*1024;         // [1024][4096] u8

// ---------------- helpers ----------------
static __device__ __forceinline__ float bf2f(u16 u) {
  union { u32 i; float f; } un; un.i = ((u32)u) << 16; return un.f;
}
static __device__ __forceinline__ u16 f2bf(float f) {  // RNE
  union { float f; u32 u; } un; un.f = f;
  u32 u = un.u;
  return (u16)((u + 0x7FFFu + ((u >> 16) & 1u)) >> 16);
}
static __device__ __forceinline__ u64 pack4(u16 a, u16 b, u16 c, u16 d) {
  return (u64)a | ((u64)b << 16) | ((u64)c << 32) | ((u64)d << 48);
}
static __device__ __forceinline__ f32x4 mfma16(short8 a, short8 b, f32x4 c) {
  return __builtin_amdgcn_mfma_f32_16x16x32_bf16(a, b, c, 0, 0, 0);
}
static __device__ __forceinline__ f32x16 mfma32(short8 a, short8 b, f32x16 c) {
  return __builtin_amdgcn_mfma_f32_32x32x16_bf16(a, b, c, 0, 0, 0);
}
static __device__ __forceinline__ void gload_lds16(void* lds, const void* g) {
  __builtin_amdgcn_global_load_lds(
      (const __attribute__((address_space(1))) void*)g,
      (__attribute__((address_space(3))) void*)lds, 16, 0, 0);
}
// gelu(x) = 0.5x(1+tanh(z)) = x*e/(e+1), e=exp(2*0.79788456(x+0.044715x^3)).
static __device__ __forceinline__ float gelu_tanh(float x) {
  float z2 = 1.5957691216057308f * (x + 0.044715f * x * x * x);
  float e = __expf(z2);
  float r = __builtin_amdgcn_rcpf(e + 1.0f);
  return x - x * r;   // x*(1 - 1/(e+1)) = x*e/(e+1)
}
static __device__ __forceinline__ u32 cvtpk_bf16(float lo, float hi) {
  u32 r;
  asm("v_cvt_pk_bf16_f32 %0, %1, %2" : "=v"(r) : "v"(lo), "v"(hi));
  return r;
}
// fp32 -> OCP e4m3 (saturating)
static __device__ __forceinline__ u32 pack_fp8x4(float a, float b, float c, float d) {
#if __has_builtin(__builtin_amdgcn_cvt_pk_fp8_f32)
  u32 r = (u32)__builtin_amdgcn_cvt_pk_fp8_f32(a, b, 0, false);
  r = (u32)__builtin_amdgcn_cvt_pk_fp8_f32(c, d, (int)r, true);
  return r;
#else
  __hip_fp8_e4m3 qa(a), qb(b), qc(c), qd(d);
  return (u32)qa.__x | ((u32)qb.__x << 8) | ((u32)qc.__x << 16) | ((u32)qd.__x << 24);
#endif
}
static __device__ __forceinline__ u8 fp8b(float f) {
#if __has_builtin(__builtin_amdgcn_cvt_pk_fp8_f32)
  return (u8)((u32)__builtin_amdgcn_cvt_pk_fp8_f32(f, f, 0, false) & 0xFFu);
#else
  __hip_fp8_e4m3 t(f); return t.__x;
#endif
}

// ---------------- small kernels ----------------
__global__ __launch_bounds__(256) void build_tab(float* __restrict__ ct, float* __restrict__ st) {
  int idx = blockIdx.x * 256 + threadIdx.x;           // 1024*32 entries
  int pos = idx >> 5, i = idx & 31;
  float inv = powf(10000.f, -(float)i * (1.f / 32.f));
  float a = (float)pos * inv;
  ct[idx] = cosf(a);
  st[idx] = sinf(a);
}

// fused fp32->bf16 conversion of weights + context (segments 0-2 = sa_q/k/v
// and 8,9 = fc1w/fc2w now fp8 -> early-exit).
struct Cvt11 { const float* s[11]; };
__global__ __launch_bounds__(256) void cvt_all(Cvt11 a, u16* __restrict__ dst) {
  u32 gid = blockIdx.x * 256 + threadIdx.x;   // 0 .. 4718591
  u32 s, off;
  if (gid < 2097152u)      { s = gid >> 18; if (s < 3) return;     off = gid & 262143u; }
  else if (gid < 4194304u) { return; }        // fc1w/fc2w handled in fp8
  else                     { s = 10;                               off = gid - 4194304u; }
  float4 v = *(const float4*)(a.s[s] + (size_t)off * 4);
  *(u64*)(dst + (size_t)gid * 4) = pack4(f2bf(v.x), f2bf(v.y), f2bf(v.z), f2bf(v.w));
}

// sa_q/k/v + fc1w + fc2w -> fp8 e4m3 scaled x256. 11 segments of 1M elems.
__global__ __launch_bounds__(256) void cvt_fp8b(const float* __restrict__ qw, const float* __restrict__ kw,
                                                const float* __restrict__ vw, const float* __restrict__ f1,
                                                const float* __restrict__ f2,
                                                u8* __restrict__ d_qkv, u8* __restrict__ d_f1,
                                                u8* __restrict__ d_f2) {
  u32 gid = blockIdx.x * 256 + threadIdx.x;   // 0 .. 2883583 (11 * 262144), 4 elems each
  u32 seg = gid >> 18, off = gid & 262143u;
  const float* s; u8* d;
  if (seg < 3)      { s = seg == 0 ? qw : (seg == 1 ? kw : vw); d = d_qkv + (size_t)seg * 1048576; }
  else if (seg < 7) { s = f1 + (size_t)(seg - 3) * 1048576;     d = d_f1  + (size_t)(seg - 3) * 1048576; }
  else              { s = f2 + (size_t)(seg - 7) * 1048576;     d = d_f2  + (size_t)(seg - 7) * 1048576; }
  float4 v = *(const float4*)(s + (size_t)off * 4);
  *(u32*)(d + (size_t)off * 4) =
      pack_fp8x4(v.x * 256.f, v.y * 256.f, v.z * 256.f, v.w * 256.f);
}

// fused bias copies: sa_q,sa_k,sa_v -> BSAQKV(+0,+1024,+2048); ca_k,ca_v -> BCAKV(+0,+1024)
struct Cp5 { const float* s[5]; };
__global__ __launch_bounds__(256) void copy5(Cp5 a, float* __restrict__ dst) {
  int gid = blockIdx.x * 256 + threadIdx.x;   // 0..5119
  int s = gid >> 10, off = gid & 1023;
  int doff = (s < 3) ? s * 1024 : 4096 + (s - 3) * 1024;
  dst[doff + off] = a.s[s][off];
}

// out[row][c] += gate[c]*bias[c]  (init pass for split-K atomic GEMM)
__global__ __launch_bounds__(256) void init_bias_gate(float* __restrict__ out, const float* __restrict__ bias,
                                                      const float* __restrict__ gate) {
  int i = (blockIdx.x * 256 + threadIdx.x) * 4;
  int c = i & 1023;
  float4 o = *(float4*)(out + i);
  o.x += gate[c] * bias[c];
  o.y += gate[c + 1] * bias[c + 1];
  o.z += gate[c + 2] * bias[c + 2];
  o.w += gate[c + 3] * bias[c + 3];
  *(float4*)(out + i) = o;
}

// LN over last dim 1024, one row per block, bf16 out.
__global__ __launch_bounds__(256) void ln_bf16(const float* __restrict__ x, const float* __restrict__ w,
                                               const float* __restrict__ b, u16* __restrict__ out) {
  __shared__ float red[4];
  int row = blockIdx.x, tid = threadIdx.x;
  const float* xr = x + (size_t)row * 1024;
  float4 v = ((const float4*)xr)[tid];
  float s = v.x + v.y + v.z + v.w;
#pragma unroll
  for (int off = 32; off; off >>= 1) s += __shfl_xor(s, off);
  if ((tid & 63) == 0) red[tid >> 6] = s;
  __syncthreads();
  float mean = (red[0] + red[1] + red[2] + red[3]) * (1.f / 1024.f);
  float dx = v.x - mean, dy = v.y - mean, dz = v.z - mean, dw = v.w - mean;
  float sq = dx * dx + dy * dy + dz * dz + dw * dw;
#pragma unroll
  for (int off = 32; off; off >>= 1) sq += __shfl_xor(sq, off);
  __syncthreads();
  if ((tid & 63) == 0) red[tid >> 6] = sq;
  __syncthreads();
  float var = (red[0] + red[1] + red[2] + red[3]) * (1.f / 1024.f);
  float rstd = rsqrtf(var + 1e-6f);
  float4 wv = ((const float4*)w)[tid];
  float4 bv = ((const float4*)b)[tid];
  u64 o = pack4(f2bf(dx * rstd * wv.x + bv.x), f2bf(dy * rstd * wv.y + bv.y),
                f2bf(dz * rstd * wv.z + bv.z), f2bf(dw * rstd * wv.w + bv.w));
  *(u64*)(out + (size_t)row * 1024 + tid * 4) = o;
}

// LN -> fp8 e4m3 scaled x16 (for fp8 GEMM activations)
__global__ __launch_bounds__(256) void ln_fp8(const float* __restrict__ x, const float* __restrict__ w,
                                              const float* __restrict__ b, u8* __restrict__ out) {
  __shared__ float red[4];
  int row = blockIdx.x, tid = threadIdx.x;
  const float* xr = x + (size_t)row * 1024;
  float4 v = ((const float4*)xr)[tid];
  float s = v.x + v.y + v.z + v.w;
#pragma unroll
  for (int off = 32; off; off >>= 1) s += __shfl_xor(s, off);
  if ((tid & 63) == 0) red[tid >> 6] = s;
  __syncthreads();
  float mean = (red[0] + red[1] + red[2] + red[3]) * (1.f / 1024.f);
  float dx = v.x - mean, dy = v.y - mean, dz = v.z - mean, dw = v.w - mean;
  float sq = dx * dx + dy * dy + dz * dz + dw * dw;
#pragma unroll
  for (int off = 32; off; off >>= 1) sq += __shfl_xor(sq, off);
  __syncthreads();
  if ((tid & 63) == 0) red[tid >> 6] = sq;
  __syncthreads();
  float var = (red[0] + red[1] + red[2] + red[3]) * (1.f / 1024.f);
  float rstd = rsqrtf(var + 1e-6f);
  float4 wv = ((const float4*)w)[tid];
  float4 bv = ((const float4*)b)[tid];
  u32 pk = pack_fp8x4((dx * rstd * wv.x + bv.x) * 16.f, (dy * rstd * wv.y + bv.y) * 16.f,
                      (dz * rstd * wv.z + bv.z) * 16.f, (dw * rstd * wv.w + bv.w) * 16.f);
  *(u32*)(out + (size_t)row * 1024 + tid * 4) = pk;
}

// Fused RoPE (Q,K only): 2 jobs per dispatch, coalesced writes.
struct RopeJob { const u16* src; u16* dst; int ld, col0, Lper, T; float scale; };
struct Rope2 { RopeJob j[2]; };
__global__ __launch_bounds__(128) void rope2(Rope2 a, const float* __restrict__ cosT,
                                             const float* __restrict__ sinT) {
  RopeJob jb = a.j[blockIdx.y];
  int t = blockIdx.x;
  if (t >= jb.T) return;
  int b = t / jb.Lper, l = t - b * jb.Lper;
  int tid = threadIdx.x;
  int e0 = tid * 8;
  int h = e0 >> 6, d0 = e0 & 63;
  short8 vv = *(const short8*)(jb.src + (size_t)t * jb.ld + jb.col0 + e0);
  short8 ov;
#pragma unroll
  for (int j = 0; j < 4; ++j) {
    float x1 = bf2f((u16)vv[2 * j]);
    float x2 = bf2f((u16)vv[2 * j + 1]);
    int i = (d0 >> 1) + j;
    float c = cosT[l * 32 + i], s = sinT[l * 32 + i];
    ov[2 * j]     = (short)f2bf((x1 * c - x2 * s) * jb.scale);
    ov[2 * j + 1] = (short)f2bf((x1 * s + x2 * c) * jb.scale);
  }
  *(short8*)(jb.dst + (((size_t)b * H + h) * jb.Lper + l) * 64 + d0) = ov;
}

// V transpose with COALESCED writes: src [T][ld]+col0 (bf16) -> dst [B,H,64,Lper].
// One block per (64-token tile, b*H+h): 64x64 through padded LDS; every output
// 128-B line written whole by this block (kills the 6.5x scatter amplification).
__global__ __launch_bounds__(256) void vtrans(const u16* __restrict__ src, int ld, int col0,
                                              u16* __restrict__ dst, int Lper) {
  __shared__ u16 tile[64][72];   // +8 pad breaks transpose-read bank conflicts
  int bh = blockIdx.y;           // b*H + h
  int b = bh >> 4, h = bh & 15;
  int l0 = blockIdx.x * 64;
  int tid = threadIdx.x;
#pragma unroll
  for (int j = 0; j < 2; ++j) {  // read: token i = c>>3, d0 = (c&7)*8
    int c = tid + j * 256;
    int i = c >> 3, d0 = (c & 7) * 8;
    short8 v = *(const short8*)(src + (size_t)(b * Lper + l0 + i) * ld + col0 + h * 64 + d0);
    *(short8*)(&tile[i][d0]) = v;
  }
  __syncthreads();
#pragma unroll
  for (int j = 0; j < 2; ++j) {  // write: row d = c>>3, 8 l-values at (c&7)*8
    int c = tid + j * 256;
    int d = c >> 3, lc = (c & 7) * 8;
    short8 v;
#pragma unroll
    for (int k = 0; k < 8; ++k) v[k] = (short)tile[lc + k][d];
    *(short8*)(dst + (((size_t)bh) * 64 + d) * Lper + l0 + lc) = v;
  }
}

// ---------------- bf16 GEMM (proven R8 config): C = A @ W^T + bias ----------------
enum { EPI_BF16 = 0, EPI_GELU = 1, EPI_RESID = 2 };

template <int EPI>
__global__ __launch_bounds__(512, 4) void gemm2(const u16* __restrict__ A, const u16* __restrict__ W,
                                                const float* __restrict__ bias, u16* outb, float* outf,
                                                const float* res, const float* __restrict__ gate,
                                                int M, int N, int K) {
  __shared__ u16 As[2][128 * 64];
  __shared__ u16 Bs[2][128 * 64];

  int nwg = gridDim.x * gridDim.y;
  int bid = blockIdx.y * gridDim.x + blockIdx.x;
  int cpx = nwg >> 3;
  int swz = (bid & 7) * cpx + (bid >> 3);
  int bx = swz % gridDim.x;
  int by = swz / gridDim.x;
  int row0 = by * 128, col0 = bx * 128;

  int tid = threadIdx.x;
  int lane = tid & 63, wid = tid >> 6;
  int wr = wid >> 2, wc = wid & 3;  // 2x4 waves, each owns 64x32
  int lr = lane & 15, lg = lane >> 4;

  size_t a_off0, a_off1, b_off0, b_off1;
  int l_off0 = tid * 8, l_off1 = (512 + tid) * 8;
  {
    int q = tid, r = q >> 3, p = q & 7, sp = p ^ (r & 7);
    a_off0 = (size_t)(row0 + r) * K + sp * 8;
    b_off0 = (size_t)(col0 + r) * K + sp * 8;
    q = 512 + tid; r = q >> 3; p = q & 7; sp = p ^ (r & 7);
    a_off1 = (size_t)(row0 + r) * K + sp * 8;
    b_off1 = (size_t)(col0 + r) * K + sp * 8;
  }

  f32x4 acc[4][2] = {};

  const int nkt = K >> 6;
  {
    gload_lds16(&As[0][l_off0], A + a_off0);
    gload_lds16(&Bs[0][l_off0], W + b_off0);
    gload_lds16(&As[0][l_off1], A + a_off1);
    gload_lds16(&Bs[0][l_off1], W + b_off1);
  }
  __syncthreads();

  for (int kt = 0; kt < nkt; ++kt) {
    int cur = kt & 1;
    if (kt + 1 < nkt) {
      int k0 = (kt + 1) << 6;
      gload_lds16(&As[cur ^ 1][l_off0], A + a_off0 + k0);
      gload_lds16(&Bs[cur ^ 1][l_off0], W + b_off0 + k0);
      gload_lds16(&As[cur ^ 1][l_off1], A + a_off1 + k0);
      gload_lds16(&Bs[cur ^ 1][l_off1], W + b_off1 + k0);
    }
#pragma unroll
    for (int kk = 0; kk < 2; ++kk) {
      short8 af[4], bfr[2];
#pragma unroll
      for (int m = 0; m < 4; ++m) {
        int r = wr * 64 + m * 16 + lr;
        int sc = (kk * 4 + lg) ^ (r & 7);
        af[m] = *(const short8*)(&As[cur][r * 64 + sc * 8]);
      }
#pragma unroll
      for (int n = 0; n < 2; ++n) {
        int r = wc * 32 + n * 16 + lr;
        int sc = (kk * 4 + lg) ^ (r & 7);
        bfr[n] = *(const short8*)(&Bs[cur][r * 64 + sc * 8]);
      }
#pragma unroll
      for (int m = 0; m < 4; ++m)
#pragma unroll
        for (int n = 0; n < 2; ++n)
          acc[m][n] = mfma16(af[m], bfr[n], acc[m][n]);
    }
    __syncthreads();
  }

  if (EPI == EPI_BF16 || EPI == EPI_GELU) {
    u16* Ct = &As[0][0];
#pragma unroll
    for (int n = 0; n < 2; ++n) {
      int c = wc * 32 + n * 16 + lr;
      float bv = bias[col0 + c];
#pragma unroll
      for (int m = 0; m < 4; ++m) {
#pragma unroll
        for (int i = 0; i < 4; ++i) {
          int r = wr * 64 + m * 16 + lg * 4 + i;
          float v = acc[m][n][i] + bv;
          Ct[r * 128 + c] = f2bf(EPI == EPI_GELU ? gelu_tanh(v) : v);
        }
      }
    }
    __syncthreads();
#pragma unroll
    for (int j = 0; j < 4; ++j) {
      u32 q = (u32)tid + j * 512;
      u32 r = q >> 4, ck = q & 15;
      short8 v = *(const short8*)(Ct + r * 128 + ck * 8);
      *(short8*)(outb + (size_t)(row0 + r) * N + col0 + ck * 8) = v;
    }
  } else {
#pragma unroll
    for (int n = 0; n < 2; ++n) {
      int cg = col0 + wc * 32 + n * 16 + lr;
      float bv = bias[cg];
#pragma unroll
      for (int m = 0; m < 4; ++m) {
#pragma unroll
        for (int i = 0; i < 4; ++i) {
          int rg = row0 + wr * 64 + m * 16 + lg * 4 + i;
          float v = acc[m][n][i] + bv;
          float r = res[(size_t)rg * N + cg];
          outf[(size_t)rg * N + cg] = r + gate[cg] * v;
        }
      }
    }
  }
}

// ---------------- fp8 MX GEMM: C = (A/16) @ (W/256)^T -> acc/4096 ----------------
enum { E8_BF16 = 0, E8_GELU = 1, E8_ATOMIC = 2 };

template <int EPI>
__global__ __launch_bounds__(256, 2) void gemm8(const u8* __restrict__ A, const u8* __restrict__ W,
                                                const float* __restrict__ bias, u16* outb16,
                                                u8* outb8, float* outf, const float* __restrict__ gate,
                                                int M, int N, int K, int kchunks) {
  __shared__ u8 As[2][128 * 128];
  __shared__ u8 Bs[2][128 * 128];

  int nwg = gridDim.x * gridDim.y;
  int bid = blockIdx.y * gridDim.x + blockIdx.x;
  int cpx = nwg >> 3;
  int swz = (bid & 7) * cpx + (bid >> 3);
  int bx = swz % gridDim.x, by = swz / gridDim.x;
  int row0 = by * 128, col0 = bx * 128;

  const int Kc = K / kchunks;
  const int kbase = blockIdx.z * Kc;

  int tid = threadIdx.x;
  int lane = tid & 63, wid = tid >> 6;
  int wr = wid >> 1, wc = wid & 1;      // 2x2 waves, each owns 64x64
  int lr = lane & 15, lg = lane >> 4;

  u32 aoff[4], boff[4];
  int ldso[4];
#pragma unroll
  for (int j = 0; j < 4; ++j) {
    int q = tid + j * 256;
    int r = q >> 3, p = q & 7, sp = p ^ (r & 7);
    aoff[j] = (u32)(row0 + r) * (u32)K + sp * 16;
    boff[j] = (u32)(col0 + r) * (u32)K + sp * 16;
    ldso[j] = q * 16;
  }

  f32x4 acc[4][4] = {};
  const int nkt = Kc >> 7;              // BK = 128

  auto rdfrag = [&](const u8* base, int r, i32x8& f) {
    const u8* rp = base + r * 128;
    int ck = lg * 2;
    u32x4 lo = *(const u32x4*)(rp + ((ck) ^ (r & 7)) * 16);
    u32x4 hh = *(const u32x4*)(rp + ((ck + 1) ^ (r & 7)) * 16);
    i32x8 v;
    v[0] = (int)lo[0]; v[1] = (int)lo[1]; v[2] = (int)lo[2]; v[3] = (int)lo[3];
    v[4] = (int)hh[0]; v[5] = (int)hh[1]; v[6] = (int)hh[2]; v[7] = (int)hh[3];
    f = v;
  };

  // prologue
#pragma unroll
  for (int j = 0; j < 4; ++j) {
    gload_lds16(&As[0][ldso[j]], A + aoff[j] + kbase);
    gload_lds16(&Bs[0][ldso[j]], W + boff[j] + kbase);
  }
  __syncthreads();

  for (int kt = 0; kt < nkt; ++kt) {
    int cur = kt & 1;
    if (kt + 1 < nkt) {
      int k0 = kbase + ((kt + 1) << 7);
#pragma unroll
      for (int j = 0; j < 4; ++j) {
        gload_lds16(&As[cur ^ 1][ldso[j]], A + aoff[j] + k0);
        gload_lds16(&Bs[cur ^ 1][ldso[j]], W + boff[j] + k0);
      }
    }
    i32x8 a[4], b[4];
#pragma unroll
    for (int m = 0; m < 4; ++m) rdfrag(&As[cur][0], wr * 64 + m * 16 + lr, a[m]);
#pragma unroll
    for (int n = 0; n < 4; ++n) rdfrag(&Bs[cur][0], wc * 64 + n * 16 + lr, b[n]);
    __builtin_amdgcn_s_setprio(1);
#pragma unroll
    for (int m = 0; m < 4; ++m)
#pragma unroll
      for (int n = 0; n < 4; ++n)
        acc[m][n] = __builtin_amdgcn_mfma_scale_f32_16x16x128_f8f6f4(
            a[m], b[n], acc[m][n], 0, 0, 0, 0x7F7F7F7F, 0, 0x7F7F7F7F);
    __builtin_amdgcn_s_setprio(0);
    __syncthreads();
  }

  // epilogue: C layout col=lane&15, row=(lane>>4)*4+i (dtype-independent)
  constexpr float SCL = 1.f / 4096.f;   // undo x16 (act) * x256 (weights)
  if (EPI == E8_BF16) {
    u16* Ct = (u16*)&As[0][0];          // [128][128] u16 = 32 KiB (both As bufs)
#pragma unroll
    for (int n = 0; n < 4; ++n) {
      int cl = wc * 64 + n * 16 + lr;
      float bv = bias[col0 + cl];
#pragma unroll
      for (int m = 0; m < 4; ++m) {
#pragma unroll
        for (int i = 0; i < 4; ++i) {
          int rl = wr * 64 + m * 16 + lg * 4 + i;
          Ct[rl * 128 + cl] = f2bf(acc[m][n][i] * SCL + bv);
        }
      }
    }
    __syncthreads();
#pragma unroll
    for (int j = 0; j < 8; ++j) {
      u32 q = (u32)tid + j * 256;
      u32 r = q >> 4, ck = q & 15;
      short8 v = *(const short8*)(Ct + r * 128 + ck * 8);
      *(short8*)(outb16 + (size_t)(row0 + r) * N + col0 + ck * 8) = v;
    }
  } else if (EPI == E8_GELU) {
    u8* Ct = &As[0][0];                 // [128][128] u8 = 16 KiB
#pragma unroll
    for (int n = 0; n < 4; ++n) {
      int cl = wc * 64 + n * 16 + lr;
      float bv = bias[col0 + cl];
#pragma unroll
      for (int m = 0; m < 4; ++m) {
#pragma unroll
        for (int i = 0; i < 4; ++i) {
          int rl = wr * 64 + m * 16 + lg * 4 + i;
          float v = acc[m][n][i] * SCL + bv;
          Ct[rl * 128 + cl] = fp8b(gelu_tanh(v) * 16.f);
        }
      }
    }
    __syncthreads();
#pragma unroll
    for (int j = 0; j < 4; ++j) {
      int q = tid + j * 256;
      int r = q >> 3, ck = q & 7;
      *(u32x4*)(outb8 + (size_t)(row0 + r) * N + col0 + ck * 16) =
          *(const u32x4*)(Ct + r * 128 + ck * 16);
    }
  } else {  // E8_ATOMIC: bias+gate pre-applied by init_bias_gate
#pragma unroll
    for (int n = 0; n < 4; ++n) {
      int cg = col0 + wc * 64 + n * 16 + lr;
      float gv = gate[cg];
#pragma unroll
      for (int m = 0; m < 4; ++m) {
#pragma unroll
        for (int i = 0; i < 4; ++i) {
          int rg = row0 + wr * 64 + m * 16 + lg * 4 + i;
          atomicAdd(&outf[(size_t)rg * N + cg], gv * (acc[m][n][i] * SCL));
        }
      }
    }
  }
}

// ---------------- flash attention, swapped-QK^T, register-pipelined K/V ----------------
template <int MASKED, int PRE>
static __device__ __forceinline__ void attn_tile3(short8* kf, const u16* KtNext,
                                                  const u16* Vp0, const u16* Vp1,
                                                  const short8* qf, int kb, int q0, int l31, int hi,
                                                  float& m, float& lsum, f32x16& o0, f32x16& o1) {
  // 1) V loads for THIS tile — independent, issue first
  short8 vf0[4], vf1[4];
#pragma unroll
  for (int ks = 0; ks < 4; ++ks) {
    vf0[ks] = *(const short8*)(Vp0 + ks * 16 + hi * 8);
    vf1[ks] = *(const short8*)(Vp1 + ks * 16 + hi * 8);
  }
  // 2) QK^T from pre-loaded K registers
  f32x16 s0 = {}, s1 = {};
  __builtin_amdgcn_s_setprio(1);
#pragma unroll
  for (int s = 0; s < 4; ++s) {
    s0 = mfma32(kf[s], qf[s], s0);       // S^T[k][q]
    s1 = mfma32(kf[4 + s], qf[s], s1);
  }
  __builtin_amdgcn_s_setprio(0);
  // 3) prefetch next tile's K into kf (dead after QK^T)
  if (PRE) {
    const u16* kp0 = KtNext + (size_t)l31 * 64 + hi * 8;
    const u16* kp1 = KtNext + (size_t)(32 + l31) * 64 + hi * 8;
#pragma unroll
    for (int s = 0; s < 4; ++s) {
      kf[s] = *(const short8*)(kp0 + s * 16);
      kf[4 + s] = *(const short8*)(kp1 + s * 16);
    }
  }
  if (MASKED) {
    int qg = q0 + l31;
#pragma unroll
    for (int r = 0; r < 16; ++r) {
      int kk = kb + (r & 3) + 8 * (r >> 2) + 4 * hi;
      if (kk > qg) s0[r] = -INFINITY;
      if (kk + 32 > qg) s1[r] = -INFINITY;
    }
  }
  float pm = -INFINITY;
#pragma unroll
  for (int r = 0; r < 16; ++r) pm = fmaxf(pm, fmaxf(s0[r], s1[r]));
  pm = fmaxf(pm, __shfl_xor(pm, 32));
  if (!__all(pm <= m + DEFER_THR)) {
    float mn = fmaxf(m, pm);
    float al = exp2f(m - mn);
    m = mn;
    lsum *= al;
#pragma unroll
    for (int r = 0; r < 16; ++r) {
      float alr = __shfl(al, (r & 3) + 8 * (r >> 2) + 4 * hi);
      o0[r] *= alr;
      o1[r] *= alr;
    }
  }
  float ts = 0.f;
#pragma unroll
  for (int r = 0; r < 16; ++r) {
    float p0 = exp2f(s0[r] - m);
    float p1 = exp2f(s1[r] - m);
    s0[r] = p0; s1[r] = p1;
    ts += p0 + p1;
  }
  ts += __shfl_xor(ts, 32);
  lsum += ts;
  auto pack8 = [&](float a0, float a1, float a2, float a3,
                   float a4, float a5, float a6, float a7) -> short8 {
    u32 c0 = cvtpk_bf16(a0, a1), c1 = cvtpk_bf16(a2, a3);
    u32 c2 = cvtpk_bf16(a4, a5), c3 = cvtpk_bf16(a6, a7);
    u32x2 r02 = __builtin_amdgcn_permlane32_swap(c0, c2, false, false);
    u32x2 r13 = __builtin_amdgcn_permlane32_swap(c1, c3, false, false);
    u32x4 w;
    w[0] = r02[0]; w[1] = r13[0]; w[2] = r02[1]; w[3] = r13[1];
    return __builtin_bit_cast(short8, w);
  };
  short8 pa0 = pack8(s0[0], s0[1], s0[2], s0[3], s0[4], s0[5], s0[6], s0[7]);
  short8 pa1 = pack8(s0[8], s0[9], s0[10], s0[11], s0[12], s0[13], s0[14], s0[15]);
  short8 pa2 = pack8(s1[0], s1[1], s1[2], s1[3], s1[4], s1[5], s1[6], s1[7]);
  short8 pa3 = pack8(s1[8], s1[9], s1[10], s1[11], s1[12], s1[13], s1[14], s1[15]);
  short8 pa[4] = {pa0, pa1, pa2, pa3};
  __builtin_amdgcn_s_setprio(1);
#pragma unroll
  for (int ks = 0; ks < 4; ++ks) {
    o0 = mfma32(pa[ks], vf0[ks], o0);
    o1 = mfma32(pa[ks], vf1[ks], o1);
  }
  __builtin_amdgcn_s_setprio(0);
}

template <int CAUSAL>
__global__ __launch_bounds__(256) void flash_attn2(const u16* __restrict__ Q, const u16* __restrict__ K,
                                                   const u16* __restrict__ Vt, u16* __restrict__ O,
                                                   int Lq, int Lk) {
  const int wid = threadIdx.x >> 6, lane = threadIdx.x & 63;
  const int l31 = lane & 31, hi = lane >> 5;
  int wg = blockIdx.x * 4 + wid;     // 4 independent waves per block, no barriers
  int bh = wg & 63;
  int qc = wg >> 6;
  if (CAUSAL) qc = (Lq >> 5) - 1 - qc;   // heavy q-chunks dispatch first
  int q0 = qc << 5;

  const u16* Qb = Q + ((size_t)bh * Lq + q0) * 64;
  const u16* Kb = K + (size_t)bh * Lk * 64;
  const u16* Vb = Vt + (size_t)bh * 64 * Lk;

  short8 qf[4];
#pragma unroll
  for (int s = 0; s < 4; ++s) qf[s] = *(const short8*)(Qb + (size_t)l31 * 64 + s * 16 + hi * 8);

  f32x16 o0 = {}, o1 = {};
  float m = -INFINITY, lsum = 0.f;

  const u16* Kt = Kb;
  const u16* Vp0 = Vb + (size_t)l31 * Lk;
  const u16* Vp1 = Vb + (size_t)(32 + l31) * Lk;

  // preload K tile 0 into registers
  short8 kf[8];
  {
    const u16* kp0 = Kt + (size_t)l31 * 64 + hi * 8;
    const u16* kp1 = Kt + (size_t)(32 + l31) * 64 + hi * 8;
#pragma unroll
    for (int s = 0; s < 4; ++s) {
      kf[s] = *(const short8*)(kp0 + s * 16);
      kf[4 + s] = *(const short8*)(kp1 + s * 16);
    }
  }

  int nt = CAUSAL ? ((q0 >> 6) + 1) : (Lk >> 6);
  for (int t = 0; t < nt - 1; ++t) {
    attn_tile3<0, 1>(kf, Kt + 64 * 64, Vp0, Vp1, qf, t * 64, q0, l31, hi, m, lsum, o0, o1);
    Kt += 64 * 64; Vp0 += 64; Vp1 += 64;
  }
  if (CAUSAL)
    attn_tile3<1, 0>(kf, nullptr, Vp0, Vp1, qf, (nt - 1) * 64, q0, l31, hi, m, lsum, o0, o1);
  else
    attn_tile3<0, 0>(kf, nullptr, Vp0, Vp1, qf, (nt - 1) * 64, q0, l31, hi, m, lsum, o0, o1);

  float myinv = 1.f / lsum;
  int b = bh >> 4, h = bh & 15;
#pragma unroll
  for (int r = 0; r < 16; ++r) {
    int cr = (r & 3) + 8 * (r >> 2) + 4 * hi;
    float li = __shfl(myinv, cr);
    u16* op = O + ((size_t)b * Lq + q0 + cr) * 1024 + h * 64;
    op[l31] = f2bf(o0[r] * li);
    op[32 + l31] = f2bf(o1[r] * li);
  }
}

// ---------------- launch ----------------
extern "C" void kernel_launch(void* const* d_in, const int* in_sizes, int n_in,
                              void* d_out, int out_size, void* d_ws, size_t ws_size,
                              hipStream_t stream) {
  (void)in_sizes; (void)n_in; (void)out_size;
  if (ws_size < WS_NEED) return;  // need ~105 MB scratch

  const float* x     = (const float*)d_in[0];
  const float* ctx   = (const float*)d_in[1];
  const float* g_msa = (const float*)d_in[3];
  const float* g_ca  = (const float*)d_in[4];
  const float* g_mlp = (const float*)d_in[5];
  const float* n1w = (const float*)d_in[6],  *n1b = (const float*)d_in[7];
  const float* n2w = (const float*)d_in[8],  *n2b = (const float*)d_in[9];
  const float* n3w = (const float*)d_in[10], *n3b = (const float*)d_in[11];
  const float* sa_qw = (const float*)d_in[12], *sa_kw = (const float*)d_in[14];
  const float* sa_vw = (const float*)d_in[16], *sa_pw = (const float*)d_in[18];
  const float* sa_qb = (const float*)d_in[13], *sa_kb = (const float*)d_in[15];
  const float* sa_vb = (const float*)d_in[17], *sa_pb = (const float*)d_in[19];
  const float* ca_qw = (const float*)d_in[20], *ca_qb = (const float*)d_in[21];
  const float* ca_kw = (const float*)d_in[22], *ca_kb = (const float*)d_in[23];
  const float* ca_vw = (const float*)d_in[24], *ca_vb = (const float*)d_in[25];
  const float* ca_pw = (const float*)d_in[26], *ca_pb = (const float*)d_in[27];
  const float* fc1w = (const float*)d_in[28], *fc1b = (const float*)d_in[29];
  const float* fc2w = (const float*)d_in[30], *fc2b = (const float*)d_in[31];

  char* ws = (char*)d_ws;
  float* out = (float*)d_out;
  float* tcos = (float*)(ws + OFF_TCOS);
  float* tsin = (float*)(ws + OFF_TSIN);
  u16* Hb   = (u16*)(ws + OFF_H);
  u16* QKV  = (u16*)(ws + OFF_QKV);
  u16* QR   = (u16*)(ws + OFF_QR);
  u16* KR   = (u16*)(ws + OFF_KR);
  u16* VT   = (u16*)(ws + OFF_VT);
  u16* AO   = (u16*)(ws + OFF_AO);
  u8*  H8   = (u8*)(ws + OFF_H);        // ln1/ln3 fp8 output
  u8*  U8   = (u8*)(ws + OFF_U);        // fc1 out fp8
  u8*  W8QKV = (u8*)(ws + OFF_W8QKV);
  u8*  W8FC1 = (u8*)(ws + OFF_W8FC1);
  u8*  W8FC2 = (u8*)(ws + OFF_W8FC2);

  // RoPE tables
  build_tab<<<dim3(128), dim3(256), 0, stream>>>(tcos, tsin);

  // weight conversions: bf16 set (sa_p, ca_*, ctx) + fp8 set (sa_q/k/v, fc1, fc2)
  Cvt11 ca;
  ca.s[0] = sa_qw; ca.s[1] = sa_kw; ca.s[2] = sa_vw; ca.s[3] = sa_pw;
  ca.s[4] = ca_qw; ca.s[5] = ca_kw; ca.s[6] = ca_vw; ca.s[7] = ca_pw;
  ca.s[8] = fc1w;  ca.s[9] = fc2w;  ca.s[10] = ctx;
  cvt_all<<<dim3(18432), dim3(256), 0, stream>>>(ca, (u16*)(ws + OFF_WSAQKV));
  cvt_fp8b<<<dim3(11264), dim3(256), 0, stream>>>(sa_qw, sa_kw, sa_vw, fc1w, fc2w,
                                                  W8QKV, W8FC1, W8FC2);
  Cp5 cp;
  cp.s[0] = sa_qb; cp.s[1] = sa_kb; cp.s[2] = sa_vb; cp.s[3] = ca_kb; cp.s[4] = ca_vb;
  copy5<<<dim3(20), dim3(256), 0, stream>>>(cp, (float*)(ws + OFF_BSAQKV));

  // ---- self-attention (QKV in fp8, output bf16) ----
  ln_fp8<<<dim3(NTOK), dim3(256), 0, stream>>>(x, n1w, n1b, H8);
  gemm8<E8_BF16><<<dim3(3072 / 128, NTOK / 128), dim3(256), 0, stream>>>(
      H8, W8QKV, (float*)(ws + OFF_BSAQKV), QKV, nullptr, nullptr, nullptr,
      NTOK, 3072, 1024, 1);
  {
    Rope2 r;
    r.j[0] = {QKV, QR, 3072, 0,    LQ, NTOK, QSCALE};
    r.j[1] = {QKV, KR, 3072, 1024, LQ, NTOK, 1.0f};
    rope2<<<dim3(NTOK, 2), dim3(128), 0, stream>>>(r, tcos, tsin);
  }
  vtrans<<<dim3(LQ / 64, Bn * H), dim3(256), 0, stream>>>(QKV, 3072, 2048, VT, LQ);
  flash_attn2<1><<<dim3(512), dim3(256), 0, stream>>>(QR, KR, VT, AO, LQ, LQ);
  gemm2<EPI_RESID><<<dim3(1024 / 128, NTOK / 128), dim3(512), 0, stream>>>(
      AO, (u16*)(ws + OFF_WSAP), sa_pb, nullptr, out, x, g_msa, NTOK, 1024, 1024);

  // ---- cross-attention ----
  ln_bf16<<<dim3(NTOK), dim3(256), 0, stream>>>(out, n2w, n2b, Hb);
  gemm2<EPI_BF16><<<dim3(1024 / 128, NTOK / 128), dim3(512), 0, stream>>>(
      Hb, (u16*)(ws + OFF_WCAQ), ca_qb, (u16*)(ws + OFF_CAQ), nullptr, nullptr, nullptr,
      NTOK, 1024, 1024);
  gemm2<EPI_BF16><<<dim3(2048 / 128, NCTX / 128), dim3(512), 0, stream>>>(
      (u16*)(ws + OFF_CTXB), (u16*)(ws + OFF_WCAKV), (float*)(ws + OFF_BCAKV),
      (u16*)(ws + OFF_CAKV), nullptr, nullptr, nullptr, NCTX, 2048, 1024);
  {
    Rope2 r;
    r.j[0] = {(u16*)(ws + OFF_CAQ),  QR, 1024, 0, LQ, NTOK, QSCALE};
    r.j[1] = {(u16*)(ws + OFF_CAKV), KR, 2048, 0, LC, NCTX, 1.0f};
    rope2<<<dim3(NTOK, 2), dim3(128), 0, stream>>>(r, tcos, tsin);
  }
  vtrans<<<dim3(LC / 64, Bn * H), dim3(256), 0, stream>>>(
      (u16*)(ws + OFF_CAKV), 2048, 1024, VT, LC);
  flash_attn2<0><<<dim3(512), dim3(256), 0, stream>>>(QR, KR, VT, AO, LQ, LC);
  gemm2<EPI_RESID><<<dim3(1024 / 128, NTOK / 128), dim3(512), 0, stream>>>(
      AO, (u16*)(ws + OFF_WCAP), ca_pb, nullptr, out, out, g_ca, NTOK, 1024, 1024);

  // ---- MLP (fp8 MX path) ----
  ln_fp8<<<dim3(NTOK), dim3(256), 0, stream>>>(out, n3w, n3b, H8);
  gemm8<E8_GELU><<<dim3(4096 / 128, NTOK / 128), dim3(256), 0, stream>>>(
      H8, W8FC1, fc1b, nullptr, U8, nullptr, nullptr, NTOK, 4096, 1024, 1);
  // fc2: split-K x2 atomic (512 blocks = 2/CU); bias+gate pre-applied
  init_bias_gate<<<dim3(4096), dim3(256), 0, stream>>>(out, fc2b, g_mlp);
  gemm8<E8_ATOMIC><<<dim3(1024 / 128, NTOK / 128, 2), dim3(256), 0, stream>>>(
      U8, W8FC2, nullptr, nullptr, nullptr, out, g_mlp, NTOK, 1024, 4096, 2);
}

// Round 15
// 311.570 us; speedup vs baseline: 1.4396x; 1.0485x over previous
//
#include <hip/hip_runtime.h>
#include <math.h>

#if !__has_builtin(__builtin_amdgcn_cvt_pk_fp8_f32)
#include <hip/hip_fp8.h>
#endif

typedef __attribute__((ext_vector_type(8))) short short8;
typedef __attribute__((ext_vector_type(4))) float f32x4;
typedef __attribute__((ext_vector_type(16))) float f32x16;
typedef unsigned char u8;
typedef unsigned short u16;
typedef unsigned int u32;
typedef __attribute__((ext_vector_type(2))) u32 u32x2;
typedef __attribute__((ext_vector_type(4))) u32 u32x4;
typedef __attribute__((ext_vector_type(8))) int i32x8;
typedef unsigned long long u64;

static constexpr int E = 1024, H = 16, LQ = 1024, LC = 512, Bn = 4, FF = 4096;
static constexpr int NTOK = Bn * LQ;   // 4096
static constexpr int NCTX = Bn * LC;   // 2048

// Q pre-scale: 1/sqrt(64) * log2(e)  (softmax runs in exp2 domain)
#define QSCALE 0.1803368801111244f
#define DEFER_THR 11.5f
#define AOSCL 16.0f   // attention-output fp8 scale

// ---------------- workspace layout (bytes) ----------------
static constexpr size_t OFF_TCOS   = 0;                                    // 1024*32 f32
static constexpr size_t OFF_TSIN   = OFF_TCOS + (size_t)LQ*32*4;
static constexpr size_t OFF_BSAQKV = OFF_TSIN + (size_t)LQ*32*4;           // 3072 f32 (+ca_k/v bias after)
static constexpr size_t OFF_BCAKV  = OFF_BSAQKV + 16384;                   // 2048 f32
// fp8 weight region (contiguous, 18 MB; lives where bf16 weights used to)
static constexpr size_t OFF_W8     = OFF_BCAKV + 16384;
static constexpr size_t OFF_W8QKV  = OFF_W8;                               // [3072][1024]
static constexpr size_t OFF_W8SAP  = OFF_W8QKV  + (size_t)3*1048576;       // [1024][1024]
static constexpr size_t OFF_W8CAQ  = OFF_W8SAP  + (size_t)1*1048576;
static constexpr size_t OFF_W8CAKV = OFF_W8CAQ  + (size_t)1*1048576;       // [2048][1024]
static constexpr size_t OFF_W8CAP  = OFF_W8CAKV + (size_t)2*1048576;
static constexpr size_t OFF_W8FC1  = OFF_W8CAP  + (size_t)1*1048576;       // [4096][1024]
static constexpr size_t OFF_W8FC2  = OFF_W8FC1  + (size_t)4*1048576;       // [1024][4096]
static constexpr size_t OFF_CTX8   = OFF_W8FC2  + (size_t)4*1048576;       // [2048][1024] fp8
// activation region (offsets preserved from R14 layout base)
static constexpr size_t OFF_CTXB   = OFF_W8 + (size_t)30*1048576 + (size_t)2048*1024*2; // (dead)
static constexpr size_t OFF_H      = OFF_CTXB   + (size_t)2048*1024*2;     // [4096][1024] fp8 ln out
static constexpr size_t OFF_QKV    = OFF_H      + (size_t)4096*1024*2;     // [4096][3072] bf16
static constexpr size_t OFF_CAQ    = OFF_QKV;                              // [4096][1024]
static constexpr size_t OFF_CAKV   = OFF_QKV + (size_t)4096*1024*2;        // [2048][2048]
static constexpr size_t OFF_QR     = OFF_QKV + (size_t)4096*3072*2;        // [B,H,LQ,64]
static constexpr size_t OFF_KR     = OFF_QR  + (size_t)4096*1024*2;        // [B,H,Lk,64]
static constexpr size_t OFF_VT     = OFF_KR  + (size_t)4096*1024*2;        // [B,H,64,Lk]
static constexpr size_t OFF_AO     = OFF_VT  + (size_t)4096*1024*2;        // [4096][1024] fp8
static constexpr size_t OFF_U      = OFF_QKV;                              // fc1 out fp8 reuses QKV
static constexpr size_t WS_NEED    = OFF_AO + (size_t)4096*1024*2;         // ~105 MB

// ---------------- helpers ----------------
static __device__ __forceinline__ float bf2f(u16 u) {
  union { u32 i; float f; } un; un.i = ((u32)u) << 16; return un.f;
}
static __device__ __forceinline__ u16 f2bf(float f) {  // RNE
  union { float f; u32 u; } un; un.f = f;
  u32 u = un.u;
  return (u16)((u + 0x7FFFu + ((u >> 16) & 1u)) >> 16);
}
static __device__ __forceinline__ u64 pack4(u16 a, u16 b, u16 c, u16 d) {
  return (u64)a | ((u64)b << 16) | ((u64)c << 32) | ((u64)d << 48);
}
static __device__ __forceinline__ f32x16 mfma32(short8 a, short8 b, f32x16 c) {
  return __builtin_amdgcn_mfma_f32_32x32x16_bf16(a, b, c, 0, 0, 0);
}
static __device__ __forceinline__ void gload_lds16(void* lds, const void* g) {
  __builtin_amdgcn_global_load_lds(
      (const __attribute__((address_space(1))) void*)g,
      (__attribute__((address_space(3))) void*)lds, 16, 0, 0);
}
// gelu(x) = 0.5x(1+tanh(z)) = x*e/(e+1), e=exp(2*0.79788456(x+0.044715x^3)).
static __device__ __forceinline__ float gelu_tanh(float x) {
  float z2 = 1.5957691216057308f * (x + 0.044715f * x * x * x);
  float e = __expf(z2);
  float r = __builtin_amdgcn_rcpf(e + 1.0f);
  return x - x * r;   // x*(1 - 1/(e+1)) = x*e/(e+1)
}
static __device__ __forceinline__ u32 cvtpk_bf16(float lo, float hi) {
  u32 r;
  asm("v_cvt_pk_bf16_f32 %0, %1, %2" : "=v"(r) : "v"(lo), "v"(hi));
  return r;
}
// fp32 -> OCP e4m3 (saturating)
static __device__ __forceinline__ u32 pack_fp8x4(float a, float b, float c, float d) {
#if __has_builtin(__builtin_amdgcn_cvt_pk_fp8_f32)
  u32 r = (u32)__builtin_amdgcn_cvt_pk_fp8_f32(a, b, 0, false);
  r = (u32)__builtin_amdgcn_cvt_pk_fp8_f32(c, d, (int)r, true);
  return r;
#else
  __hip_fp8_e4m3 qa(a), qb(b), qc(c), qd(d);
  return (u32)qa.__x | ((u32)qb.__x << 8) | ((u32)qc.__x << 16) | ((u32)qd.__x << 24);
#endif
}
static __device__ __forceinline__ u8 fp8b(float f) {
#if __has_builtin(__builtin_amdgcn_cvt_pk_fp8_f32)
  return (u8)((u32)__builtin_amdgcn_cvt_pk_fp8_f32(f, f, 0, false) & 0xFFu);
#else
  __hip_fp8_e4m3 t(f); return t.__x;
#endif
}

// ---------------- small kernels ----------------
__global__ __launch_bounds__(256) void build_tab(float* __restrict__ ct, float* __restrict__ st) {
  int idx = blockIdx.x * 256 + threadIdx.x;           // 1024*32 entries
  int pos = idx >> 5, i = idx & 31;
  float inv = powf(10000.f, -(float)i * (1.f / 32.f));
  float a = (float)pos * inv;
  ct[idx] = cosf(a);
  st[idx] = sinf(a);
}

// ALL weights + ctx -> fp8 e4m3 (weights x256, ctx x16), 18 segments of 1M elems
// into the contiguous fp8 region at OFF_W8. seg: 0-2 sa_qkv | 3 sa_p | 4 ca_q |
// 5 ca_k | 6 ca_v | 7 ca_p | 8-11 fc1 | 12-15 fc2 | 16-17 ctx.
struct CvtF8 { const float* s[10]; };  // qw,kw,vw,pw, caq,cak,cav,cap, fc1,fc2 | ctx passed separately
__global__ __launch_bounds__(256) void cvt_fp8c(CvtF8 a, const float* __restrict__ ctx,
                                                u8* __restrict__ dst) {
  u32 gid = blockIdx.x * 256 + threadIdx.x;   // 0 .. 18*262144-1, 4 elems each
  u32 seg = gid >> 18, off = gid & 262143u;
  const float* s;
  float scl = 256.f;
  if (seg < 8)       s = a.s[seg];
  else if (seg < 12) s = a.s[8] + (size_t)(seg - 8) * 1048576;
  else if (seg < 16) s = a.s[9] + (size_t)(seg - 12) * 1048576;
  else             { s = ctx + (size_t)(seg - 16) * 1048576; scl = 16.f; }
  float4 v = *(const float4*)(s + (size_t)off * 4);
  *(u32*)(dst + (size_t)seg * 1048576 + (size_t)off * 4) =
      pack_fp8x4(v.x * scl, v.y * scl, v.z * scl, v.w * scl);
}

// fused bias copies: sa_q,sa_k,sa_v -> BSAQKV(+0,+1024,+2048); ca_k,ca_v -> BCAKV(+0,+1024)
struct Cp5 { const float* s[5]; };
__global__ __launch_bounds__(256) void copy5(Cp5 a, float* __restrict__ dst) {
  int gid = blockIdx.x * 256 + threadIdx.x;   // 0..5119
  int s = gid >> 10, off = gid & 1023;
  int doff = (s < 3) ? s * 1024 : 4096 + (s - 3) * 1024;
  dst[doff + off] = a.s[s][off];
}

// out[row][c] += gate[c]*bias[c]  (init pass for split-K atomic GEMM)
__global__ __launch_bounds__(256) void init_bias_gate(float* __restrict__ out, const float* __restrict__ bias,
                                                      const float* __restrict__ gate) {
  int i = (blockIdx.x * 256 + threadIdx.x) * 4;
  int c = i & 1023;
  float4 o = *(float4*)(out + i);
  o.x += gate[c] * bias[c];
  o.y += gate[c + 1] * bias[c + 1];
  o.z += gate[c + 2] * bias[c + 2];
  o.w += gate[c + 3] * bias[c + 3];
  *(float4*)(out + i) = o;
}

// LN -> fp8 e4m3 scaled x16 (for fp8 GEMM activations)
__global__ __launch_bounds__(256) void ln_fp8(const float* __restrict__ x, const float* __restrict__ w,
                                              const float* __restrict__ b, u8* __restrict__ out) {
  __shared__ float red[4];
  int row = blockIdx.x, tid = threadIdx.x;
  const float* xr = x + (size_t)row * 1024;
  float4 v = ((const float4*)xr)[tid];
  float s = v.x + v.y + v.z + v.w;
#pragma unroll
  for (int off = 32; off; off >>= 1) s += __shfl_xor(s, off);
  if ((tid & 63) == 0) red[tid >> 6] = s;
  __syncthreads();
  float mean = (red[0] + red[1] + red[2] + red[3]) * (1.f / 1024.f);
  float dx = v.x - mean, dy = v.y - mean, dz = v.z - mean, dw = v.w - mean;
  float sq = dx * dx + dy * dy + dz * dz + dw * dw;
#pragma unroll
  for (int off = 32; off; off >>= 1) sq += __shfl_xor(sq, off);
  __syncthreads();
  if ((tid & 63) == 0) red[tid >> 6] = sq;
  __syncthreads();
  float var = (red[0] + red[1] + red[2] + red[3]) * (1.f / 1024.f);
  float rstd = rsqrtf(var + 1e-6f);
  float4 wv = ((const float4*)w)[tid];
  float4 bv = ((const float4*)b)[tid];
  u32 pk = pack_fp8x4((dx * rstd * wv.x + bv.x) * 16.f, (dy * rstd * wv.y + bv.y) * 16.f,
                      (dz * rstd * wv.z + bv.z) * 16.f, (dw * rstd * wv.w + bv.w) * 16.f);
  *(u32*)(out + (size_t)row * 1024 + tid * 4) = pk;
}

// Fused RoPE (Q,K only): 2 jobs per dispatch, coalesced writes.
struct RopeJob { const u16* src; u16* dst; int ld, col0, Lper, T; float scale; };
struct Rope2 { RopeJob j[2]; };
__global__ __launch_bounds__(128) void rope2(Rope2 a, const float* __restrict__ cosT,
                                             const float* __restrict__ sinT) {
  RopeJob jb = a.j[blockIdx.y];
  int t = blockIdx.x;
  if (t >= jb.T) return;
  int b = t / jb.Lper, l = t - b * jb.Lper;
  int tid = threadIdx.x;
  int e0 = tid * 8;
  int h = e0 >> 6, d0 = e0 & 63;
  short8 vv = *(const short8*)(jb.src + (size_t)t * jb.ld + jb.col0 + e0);
  short8 ov;
#pragma unroll
  for (int j = 0; j < 4; ++j) {
    float x1 = bf2f((u16)vv[2 * j]);
    float x2 = bf2f((u16)vv[2 * j + 1]);
    int i = (d0 >> 1) + j;
    float c = cosT[l * 32 + i], s = sinT[l * 32 + i];
    ov[2 * j]     = (short)f2bf((x1 * c - x2 * s) * jb.scale);
    ov[2 * j + 1] = (short)f2bf((x1 * s + x2 * c) * jb.scale);
  }
  *(short8*)(jb.dst + (((size_t)b * H + h) * jb.Lper + l) * 64 + d0) = ov;
}

// V transpose with COALESCED writes: src [T][ld]+col0 (bf16) -> dst [B,H,64,Lper].
__global__ __launch_bounds__(256) void vtrans(const u16* __restrict__ src, int ld, int col0,
                                              u16* __restrict__ dst, int Lper) {
  __shared__ u16 tile[64][72];   // +8 pad breaks transpose-read bank conflicts
  int bh = blockIdx.y;           // b*H + h
  int b = bh >> 4, h = bh & 15;
  int l0 = blockIdx.x * 64;
  int tid = threadIdx.x;
#pragma unroll
  for (int j = 0; j < 2; ++j) {
    int c = tid + j * 256;
    int i = c >> 3, d0 = (c & 7) * 8;
    short8 v = *(const short8*)(src + (size_t)(b * Lper + l0 + i) * ld + col0 + h * 64 + d0);
    *(short8*)(&tile[i][d0]) = v;
  }
  __syncthreads();
#pragma unroll
  for (int j = 0; j < 2; ++j) {
    int c = tid + j * 256;
    int d = c >> 3, lc = (c & 7) * 8;
    short8 v;
#pragma unroll
    for (int k = 0; k < 8; ++k) v[k] = (short)tile[lc + k][d];
    *(short8*)(dst + (((size_t)bh) * 64 + d) * Lper + l0 + lc) = v;
  }
}

// ---------------- fp8 MX GEMM: C = (A/16) @ (W/256)^T -> acc/4096 ----------------
// 128x128 tile, BK=128, 256 threads (2x2 waves of 64x64 = 4x4 16x16-frags),
// dbuf LDS, mfma_scale_f32_16x16x128_f8f6f4 unity scales.
enum { E8_BF16 = 0, E8_GELU = 1, E8_ATOMIC = 2, E8_RESID = 3 };

template <int EPI>
__global__ __launch_bounds__(256, 2) void gemm8(const u8* __restrict__ A, const u8* __restrict__ W,
                                                const float* __restrict__ bias, u16* outb16,
                                                u8* outb8, float* outf, const float* res,
                                                const float* __restrict__ gate,
                                                int M, int N, int K, int kchunks) {
  __shared__ u8 As[2][128 * 128];
  __shared__ u8 Bs[2][128 * 128];

  int nwg = gridDim.x * gridDim.y;
  int bid = blockIdx.y * gridDim.x + blockIdx.x;
  int cpx = nwg >> 3;
  int swz = (bid & 7) * cpx + (bid >> 3);
  int bx = swz % gridDim.x, by = swz / gridDim.x;
  int row0 = by * 128, col0 = bx * 128;

  const int Kc = K / kchunks;
  const int kbase = blockIdx.z * Kc;

  int tid = threadIdx.x;
  int lane = tid & 63, wid = tid >> 6;
  int wr = wid >> 1, wc = wid & 1;      // 2x2 waves, each owns 64x64
  int lr = lane & 15, lg = lane >> 4;

  u32 aoff[4], boff[4];
  int ldso[4];
#pragma unroll
  for (int j = 0; j < 4; ++j) {
    int q = tid + j * 256;
    int r = q >> 3, p = q & 7, sp = p ^ (r & 7);
    aoff[j] = (u32)(row0 + r) * (u32)K + sp * 16;
    boff[j] = (u32)(col0 + r) * (u32)K + sp * 16;
    ldso[j] = q * 16;
  }

  f32x4 acc[4][4] = {};
  const int nkt = Kc >> 7;              // BK = 128

  auto rdfrag = [&](const u8* base, int r, i32x8& f) {
    const u8* rp = base + r * 128;
    int ck = lg * 2;
    u32x4 lo = *(const u32x4*)(rp + ((ck) ^ (r & 7)) * 16);
    u32x4 hh = *(const u32x4*)(rp + ((ck + 1) ^ (r & 7)) * 16);
    i32x8 v;
    v[0] = (int)lo[0]; v[1] = (int)lo[1]; v[2] = (int)lo[2]; v[3] = (int)lo[3];
    v[4] = (int)hh[0]; v[5] = (int)hh[1]; v[6] = (int)hh[2]; v[7] = (int)hh[3];
    f = v;
  };

  // prologue
#pragma unroll
  for (int j = 0; j < 4; ++j) {
    gload_lds16(&As[0][ldso[j]], A + aoff[j] + kbase);
    gload_lds16(&Bs[0][ldso[j]], W + boff[j] + kbase);
  }
  __syncthreads();

  for (int kt = 0; kt < nkt; ++kt) {
    int cur = kt & 1;
    if (kt + 1 < nkt) {
      int k0 = kbase + ((kt + 1) << 7);
#pragma unroll
      for (int j = 0; j < 4; ++j) {
        gload_lds16(&As[cur ^ 1][ldso[j]], A + aoff[j] + k0);
        gload_lds16(&Bs[cur ^ 1][ldso[j]], W + boff[j] + k0);
      }
    }
    i32x8 a[4], b[4];
#pragma unroll
    for (int m = 0; m < 4; ++m) rdfrag(&As[cur][0], wr * 64 + m * 16 + lr, a[m]);
#pragma unroll
    for (int n = 0; n < 4; ++n) rdfrag(&Bs[cur][0], wc * 64 + n * 16 + lr, b[n]);
    __builtin_amdgcn_s_setprio(1);
#pragma unroll
    for (int m = 0; m < 4; ++m)
#pragma unroll
      for (int n = 0; n < 4; ++n)
        acc[m][n] = __builtin_amdgcn_mfma_scale_f32_16x16x128_f8f6f4(
            a[m], b[n], acc[m][n], 0, 0, 0, 0x7F7F7F7F, 0, 0x7F7F7F7F);
    __builtin_amdgcn_s_setprio(0);
    __syncthreads();
  }

  // epilogue: C layout col=lane&15, row=(lane>>4)*4+i (dtype-independent)
  constexpr float SCL = 1.f / 4096.f;   // undo x16 (act) * x256 (weights)
  if (EPI == E8_BF16) {
    u16* Ct = (u16*)&As[0][0];          // [128][128] u16 = 32 KiB
#pragma unroll
    for (int n = 0; n < 4; ++n) {
      int cl = wc * 64 + n * 16 + lr;
      float bv = bias[col0 + cl];
#pragma unroll
      for (int m = 0; m < 4; ++m) {
#pragma unroll
        for (int i = 0; i < 4; ++i) {
          int rl = wr * 64 + m * 16 + lg * 4 + i;
          Ct[rl * 128 + cl] = f2bf(acc[m][n][i] * SCL + bv);
        }
      }
    }
    __syncthreads();
#pragma unroll
    for (int j = 0; j < 8; ++j) {
      u32 q = (u32)tid + j * 256;
      u32 r = q >> 4, ck = q & 15;
      short8 v = *(const short8*)(Ct + r * 128 + ck * 8);
      *(short8*)(outb16 + (size_t)(row0 + r) * N + col0 + ck * 8) = v;
    }
  } else if (EPI == E8_GELU) {
    u8* Ct = &As[0][0];                 // [128][128] u8 = 16 KiB
#pragma unroll
    for (int n = 0; n < 4; ++n) {
      int cl = wc * 64 + n * 16 + lr;
      float bv = bias[col0 + cl];
#pragma unroll
      for (int m = 0; m < 4; ++m) {
#pragma unroll
        for (int i = 0; i < 4; ++i) {
          int rl = wr * 64 + m * 16 + lg * 4 + i;
          float v = acc[m][n][i] * SCL + bv;
          Ct[rl * 128 + cl] = fp8b(gelu_tanh(v) * 16.f);
        }
      }
    }
    __syncthreads();
#pragma unroll
    for (int j = 0; j < 4; ++j) {
      int q = tid + j * 256;
      int r = q >> 3, ck = q & 7;
      *(u32x4*)(outb8 + (size_t)(row0 + r) * N + col0 + ck * 16) =
          *(const u32x4*)(Ct + r * 128 + ck * 16);
    }
  } else if (EPI == E8_RESID) {
#pragma unroll
    for (int n = 0; n < 4; ++n) {
      int cg = col0 + wc * 64 + n * 16 + lr;
      float bv = bias[cg], gv = gate[cg];
#pragma unroll
      for (int m = 0; m < 4; ++m) {
#pragma unroll
        for (int i = 0; i < 4; ++i) {
          int rg = row0 + wr * 64 + m * 16 + lg * 4 + i;
          float v = acc[m][n][i] * SCL + bv;
          float r = res[(size_t)rg * N + cg];
          outf[(size_t)rg * N + cg] = r + gv * v;
        }
      }
    }
  } else {  // E8_ATOMIC: bias+gate pre-applied by init_bias_gate
#pragma unroll
    for (int n = 0; n < 4; ++n) {
      int cg = col0 + wc * 64 + n * 16 + lr;
      float gv = gate[cg];
#pragma unroll
      for (int m = 0; m < 4; ++m) {
#pragma unroll
        for (int i = 0; i < 4; ++i) {
          int rg = row0 + wr * 64 + m * 16 + lg * 4 + i;
          atomicAdd(&outf[(size_t)rg * N + cg], gv * (acc[m][n][i] * SCL));
        }
      }
    }
  }
}

// ---------------- flash attention, swapped-QK^T, register-pipelined K/V ----------------
// Output: fp8 e4m3 x16 token-major [B,Lq,E] (feeds the fp8 projection GEMMs).
template <int MASKED, int PRE>
static __device__ __forceinline__ void attn_tile3(short8* kf, const u16* KtNext,
                                                  const u16* Vp0, const u16* Vp1,
                                                  const short8* qf, int kb, int q0, int l31, int hi,
                                                  float& m, float& lsum, f32x16& o0, f32x16& o1) {
  short8 vf0[4], vf1[4];
#pragma unroll
  for (int ks = 0; ks < 4; ++ks) {
    vf0[ks] = *(const short8*)(Vp0 + ks * 16 + hi * 8);
    vf1[ks] = *(const short8*)(Vp1 + ks * 16 + hi * 8);
  }
  f32x16 s0 = {}, s1 = {};
  __builtin_amdgcn_s_setprio(1);
#pragma unroll
  for (int s = 0; s < 4; ++s) {
    s0 = mfma32(kf[s], qf[s], s0);       // S^T[k][q]
    s1 = mfma32(kf[4 + s], qf[s], s1);
  }
  __builtin_amdgcn_s_setprio(0);
  if (PRE) {
    const u16* kp0 = KtNext + (size_t)l31 * 64 + hi * 8;
    const u16* kp1 = KtNext + (size_t)(32 + l31) * 64 + hi * 8;
#pragma unroll
    for (int s = 0; s < 4; ++s) {
      kf[s] = *(const short8*)(kp0 + s * 16);
      kf[4 + s] = *(const short8*)(kp1 + s * 16);
    }
  }
  if (MASKED) {
    int qg = q0 + l31;
#pragma unroll
    for (int r = 0; r < 16; ++r) {
      int kk = kb + (r & 3) + 8 * (r >> 2) + 4 * hi;
      if (kk > qg) s0[r] = -INFINITY;
      if (kk + 32 > qg) s1[r] = -INFINITY;
    }
  }
  float pm = -INFINITY;
#pragma unroll
  for (int r = 0; r < 16; ++r) pm = fmaxf(pm, fmaxf(s0[r], s1[r]));
  pm = fmaxf(pm, __shfl_xor(pm, 32));
  if (!__all(pm <= m + DEFER_THR)) {
    float mn = fmaxf(m, pm);
    float al = exp2f(m - mn);
    m = mn;
    lsum *= al;
#pragma unroll
    for (int r = 0; r < 16; ++r) {
      float alr = __shfl(al, (r & 3) + 8 * (r >> 2) + 4 * hi);
      o0[r] *= alr;
      o1[r] *= alr;
    }
  }
  float ts = 0.f;
#pragma unroll
  for (int r = 0; r < 16; ++r) {
    float p0 = exp2f(s0[r] - m);
    float p1 = exp2f(s1[r] - m);
    s0[r] = p0; s1[r] = p1;
    ts += p0 + p1;
  }
  ts += __shfl_xor(ts, 32);
  lsum += ts;
  auto pack8 = [&](float a0, float a1, float a2, float a3,
                   float a4, float a5, float a6, float a7) -> short8 {
    u32 c0 = cvtpk_bf16(a0, a1), c1 = cvtpk_bf16(a2, a3);
    u32 c2 = cvtpk_bf16(a4, a5), c3 = cvtpk_bf16(a6, a7);
    u32x2 r02 = __builtin_amdgcn_permlane32_swap(c0, c2, false, false);
    u32x2 r13 = __builtin_amdgcn_permlane32_swap(c1, c3, false, false);
    u32x4 w;
    w[0] = r02[0]; w[1] = r13[0]; w[2] = r02[1]; w[3] = r13[1];
    return __builtin_bit_cast(short8, w);
  };
  short8 pa0 = pack8(s0[0], s0[1], s0[2], s0[3], s0[4], s0[5], s0[6], s0[7]);
  short8 pa1 = pack8(s0[8], s0[9], s0[10], s0[11], s0[12], s0[13], s0[14], s0[15]);
  short8 pa2 = pack8(s1[0], s1[1], s1[2], s1[3], s1[4], s1[5], s1[6], s1[7]);
  short8 pa3 = pack8(s1[8], s1[9], s1[10], s1[11], s1[12], s1[13], s1[14], s1[15]);
  short8 pa[4] = {pa0, pa1, pa2, pa3};
  __builtin_amdgcn_s_setprio(1);
#pragma unroll
  for (int ks = 0; ks < 4; ++ks) {
    o0 = mfma32(pa[ks], vf0[ks], o0);
    o1 = mfma32(pa[ks], vf1[ks], o1);
  }
  __builtin_amdgcn_s_setprio(0);
}

template <int CAUSAL>
__global__ __launch_bounds__(256) void flash_attn2(const u16* __restrict__ Q, const u16* __restrict__ K,
                                                   const u16* __restrict__ Vt, u8* __restrict__ O,
                                                   int Lq, int Lk) {
  const int wid = threadIdx.x >> 6, lane = threadIdx.x & 63;
  const int l31 = lane & 31, hi = lane >> 5;
  int wg = blockIdx.x * 4 + wid;     // 4 independent waves per block, no barriers
  int bh = wg & 63;
  int qc = wg >> 6;
  if (CAUSAL) qc = (Lq >> 5) - 1 - qc;   // heavy q-chunks dispatch first
  int q0 = qc << 5;

  const u16* Qb = Q + ((size_t)bh * Lq + q0) * 64;
  const u16* Kb = K + (size_t)bh * Lk * 64;
  const u16* Vb = Vt + (size_t)bh * 64 * Lk;

  short8 qf[4];
#pragma unroll
  for (int s = 0; s < 4; ++s) qf[s] = *(const short8*)(Qb + (size_t)l31 * 64 + s * 16 + hi * 8);

  f32x16 o0 = {}, o1 = {};
  float m = -INFINITY, lsum = 0.f;

  const u16* Kt = Kb;
  const u16* Vp0 = Vb + (size_t)l31 * Lk;
  const u16* Vp1 = Vb + (size_t)(32 + l31) * Lk;

  short8 kf[8];
  {
    const u16* kp0 = Kt + (size_t)l31 * 64 + hi * 8;
    const u16* kp1 = Kt + (size_t)(32 + l31) * 64 + hi * 8;
#pragma unroll
    for (int s = 0; s < 4; ++s) {
      kf[s] = *(const short8*)(kp0 + s * 16);
      kf[4 + s] = *(const short8*)(kp1 + s * 16);
    }
  }

  int nt = CAUSAL ? ((q0 >> 6) + 1) : (Lk >> 6);
  for (int t = 0; t < nt - 1; ++t) {
    attn_tile3<0, 1>(kf, Kt + 64 * 64, Vp0, Vp1, qf, t * 64, q0, l31, hi, m, lsum, o0, o1);
    Kt += 64 * 64; Vp0 += 64; Vp1 += 64;
  }
  if (CAUSAL)
    attn_tile3<1, 0>(kf, nullptr, Vp0, Vp1, qf, (nt - 1) * 64, q0, l31, hi, m, lsum, o0, o1);
  else
    attn_tile3<0, 0>(kf, nullptr, Vp0, Vp1, qf, (nt - 1) * 64, q0, l31, hi, m, lsum, o0, o1);

  float myinv = AOSCL / lsum;   // fold fp8 x16 scale into the normalizer
  int b = bh >> 4, h = bh & 15;
#pragma unroll
  for (int r = 0; r < 16; ++r) {
    int cr = (r & 3) + 8 * (r >> 2) + 4 * hi;
    float li = __shfl(myinv, cr);
    u8* op = O + ((size_t)b * Lq + q0 + cr) * 1024 + h * 64;
    op[l31] = fp8b(o0[r] * li);
    op[32 + l31] = fp8b(o1[r] * li);
  }
}

// ---------------- launch ----------------
extern "C" void kernel_launch(void* const* d_in, const int* in_sizes, int n_in,
                              void* d_out, int out_size, void* d_ws, size_t ws_size,
                              hipStream_t stream) {
  (void)in_sizes; (void)n_in; (void)out_size;
  if (ws_size < WS_NEED) return;  // need ~105 MB scratch

  const float* x     = (const float*)d_in[0];
  const float* ctx   = (const float*)d_in[1];
  const float* g_msa = (const float*)d_in[3];
  const float* g_ca  = (const float*)d_in[4];
  const float* g_mlp = (const float*)d_in[5];
  const float* n1w = (const float*)d_in[6],  *n1b = (const float*)d_in[7];
  const float* n2w = (const float*)d_in[8],  *n2b = (const float*)d_in[9];
  const float* n3w = (const float*)d_in[10], *n3b = (const float*)d_in[11];
  const float* sa_qw = (const float*)d_in[12], *sa_kw = (const float*)d_in[14];
  const float* sa_vw = (const float*)d_in[16], *sa_pw = (const float*)d_in[18];
  const float* sa_qb = (const float*)d_in[13], *sa_kb = (const float*)d_in[15];
  const float* sa_vb = (const float*)d_in[17], *sa_pb = (const float*)d_in[19];
  const float* ca_qw = (const float*)d_in[20], *ca_qb = (const float*)d_in[21];
  const float* ca_kw = (const float*)d_in[22], *ca_kb = (const float*)d_in[23];
  const float* ca_vw = (const float*)d_in[24], *ca_vb = (const float*)d_in[25];
  const float* ca_pw = (const float*)d_in[26], *ca_pb = (const float*)d_in[27];
  const float* fc1w = (const float*)d_in[28], *fc1b = (const float*)d_in[29];
  const float* fc2w = (const float*)d_in[30], *fc2b = (const float*)d_in[31];

  char* ws = (char*)d_ws;
  float* out = (float*)d_out;
  float* tcos = (float*)(ws + OFF_TCOS);
  float* tsin = (float*)(ws + OFF_TSIN);
  u16* QKV  = (u16*)(ws + OFF_QKV);
  u16* QR   = (u16*)(ws + OFF_QR);
  u16* KR   = (u16*)(ws + OFF_KR);
  u16* VT   = (u16*)(ws + OFF_VT);
  u8*  AO8  = (u8*)(ws + OFF_AO);
  u8*  H8   = (u8*)(ws + OFF_H);
  u8*  U8   = (u8*)(ws + OFF_U);
  u8*  W8QKV  = (u8*)(ws + OFF_W8QKV);
  u8*  W8SAP  = (u8*)(ws + OFF_W8SAP);
  u8*  W8CAQ  = (u8*)(ws + OFF_W8CAQ);
  u8*  W8CAKV = (u8*)(ws + OFF_W8CAKV);
  u8*  W8CAP  = (u8*)(ws + OFF_W8CAP);
  u8*  W8FC1  = (u8*)(ws + OFF_W8FC1);
  u8*  W8FC2  = (u8*)(ws + OFF_W8FC2);
  u8*  CTX8   = (u8*)(ws + OFF_CTX8);

  // RoPE tables + all weight/ctx conversion to fp8 + bias copies
  build_tab<<<dim3(128), dim3(256), 0, stream>>>(tcos, tsin);
  CvtF8 cf;
  cf.s[0] = sa_qw; cf.s[1] = sa_kw; cf.s[2] = sa_vw; cf.s[3] = sa_pw;
  cf.s[4] = ca_qw; cf.s[5] = ca_kw; cf.s[6] = ca_vw; cf.s[7] = ca_pw;
  cf.s[8] = fc1w;  cf.s[9] = fc2w;
  cvt_fp8c<<<dim3(18432), dim3(256), 0, stream>>>(cf, ctx, W8QKV);
  Cp5 cp;
  cp.s[0] = sa_qb; cp.s[1] = sa_kb; cp.s[2] = sa_vb; cp.s[3] = ca_kb; cp.s[4] = ca_vb;
  copy5<<<dim3(20), dim3(256), 0, stream>>>(cp, (float*)(ws + OFF_BSAQKV));

  // ---- self-attention ----
  ln_fp8<<<dim3(NTOK), dim3(256), 0, stream>>>(x, n1w, n1b, H8);
  gemm8<E8_BF16><<<dim3(3072 / 128, NTOK / 128), dim3(256), 0, stream>>>(
      H8, W8QKV, (float*)(ws + OFF_BSAQKV), QKV, nullptr, nullptr, nullptr, nullptr,
      NTOK, 3072, 1024, 1);
  {
    Rope2 r;
    r.j[0] = {QKV, QR, 3072, 0,    LQ, NTOK, QSCALE};
    r.j[1] = {QKV, KR, 3072, 1024, LQ, NTOK, 1.0f};
    rope2<<<dim3(NTOK, 2), dim3(128), 0, stream>>>(r, tcos, tsin);
  }
  vtrans<<<dim3(LQ / 64, Bn * H), dim3(256), 0, stream>>>(QKV, 3072, 2048, VT, LQ);
  flash_attn2<1><<<dim3(512), dim3(256), 0, stream>>>(QR, KR, VT, AO8, LQ, LQ);
  gemm8<E8_RESID><<<dim3(1024 / 128, NTOK / 128), dim3(256), 0, stream>>>(
      AO8, W8SAP, sa_pb, nullptr, nullptr, out, x, g_msa, NTOK, 1024, 1024, 1);

  // ---- cross-attention ----
  ln_fp8<<<dim3(NTOK), dim3(256), 0, stream>>>(out, n2w, n2b, H8);
  gemm8<E8_BF16><<<dim3(1024 / 128, NTOK / 128), dim3(256), 0, stream>>>(
      H8, W8CAQ, ca_qb, (u16*)(ws + OFF_CAQ), nullptr, nullptr, nullptr, nullptr,
      NTOK, 1024, 1024, 1);
  gemm8<E8_BF16><<<dim3(2048 / 128, NCTX / 128), dim3(256), 0, stream>>>(
      CTX8, W8CAKV, (float*)(ws + OFF_BCAKV), (u16*)(ws + OFF_CAKV), nullptr, nullptr,
      nullptr, nullptr, NCTX, 2048, 1024, 1);
  {
    Rope2 r;
    r.j[0] = {(u16*)(ws + OFF_CAQ),  QR, 1024, 0, LQ, NTOK, QSCALE};
    r.j[1] = {(u16*)(ws + OFF_CAKV), KR, 2048, 0, LC, NCTX, 1.0f};
    rope2<<<dim3(NTOK, 2), dim3(128), 0, stream>>>(r, tcos, tsin);
  }
  vtrans<<<dim3(LC / 64, Bn * H), dim3(256), 0, stream>>>(
      (u16*)(ws + OFF_CAKV), 2048, 1024, VT, LC);
  flash_attn2<0><<<dim3(512), dim3(256), 0, stream>>>(QR, KR, VT, AO8, LQ, LC);
  gemm8<E8_RESID><<<dim3(1024 / 128, NTOK / 128), dim3(256), 0, stream>>>(
      AO8, W8CAP, ca_pb, nullptr, nullptr, out, out, g_ca, NTOK, 1024, 1024, 1);

  // ---- MLP (fp8 MX path) ----
  ln_fp8<<<dim3(NTOK), dim3(256), 0, stream>>>(out, n3w, n3b, H8);
  gemm8<E8_GELU><<<dim3(4096 / 128, NTOK / 128), dim3(256), 0, stream>>>(
      H8, W8FC1, fc1b, nullptr, U8, nullptr, nullptr, nullptr, NTOK, 4096, 1024, 1);
  // fc2: split-K x2 atomic (512 blocks = 2/CU); bias+gate pre-applied
  init_bias_gate<<<dim3(4096), dim3(256), 0, stream>>>(out, fc2b, g_mlp);
  gemm8<E8_ATOMIC><<<dim3(1024 / 128, NTOK / 128, 2), dim3(256), 0, stream>>>(
      U8, W8FC2, nullptr, nullptr, nullptr, out, nullptr, g_mlp, NTOK, 1024, 4096, 2);
}